// Round 9
// baseline (662.701 us; speedup 1.0000x reference)
//
#include <hip/hip_runtime.h>

#define DEV static __device__ __forceinline__

constexpr int BATCH = 256;

DEV float leakyf(float x){ return x > 0.f ? x : 0.2f * x; }

typedef short bf16x8 __attribute__((ext_vector_type(8)));
typedef float f32x4 __attribute__((ext_vector_type(4)));

DEV unsigned short f2bf(float v){
  union { float f; unsigned u; } x; x.f = v;
  unsigned r = x.u + 0x7fffu + ((x.u >> 16) & 1u);
  return (unsigned short)(r >> 16);
}
DEV float bf2f(unsigned short b){
  union { unsigned u; float f; } x; x.u = ((unsigned)b) << 16;
  return x.f;
}

// ------- pack OIHW conv weights into MFMA B-fragment order, bf16 hi/lo ------
template<int IC,int OC>
__global__ __launch_bounds__(256) void wpack_k(const float* __restrict__ w,
    unsigned short* __restrict__ hi, unsigned short* __restrict__ lo){
  constexpr int S = IC/32, F = OC/16;
  int i = blockIdx.x*256 + threadIdx.x;
  if (i >= 9*S*F*512) return;
  int j = i & 7, L = (i >> 3) & 63, rest = i >> 9;
  int f = rest % F; int q2 = rest / F; int s = q2 % S; int t = q2 / S;
  int oc = f*16 + (L & 15), ic = s*32 + (L >> 4)*8 + j;
  float v = w[((size_t)oc*IC + ic)*9 + t];
  unsigned short h = f2bf(v);
  hi[i] = h; lo[i] = f2bf(v - bf2f(h));
}

// ------- pack strided-conv weights (IC=16): kstep = (kh, kw-pair) -----------
template<int OC,int K>
__global__ __launch_bounds__(256) void wpackS_k(const float* __restrict__ w,
    unsigned short* __restrict__ hi, unsigned short* __restrict__ lo){
  constexpr int F = OC/16, KWP = (K+1)/2;
  int i = blockIdx.x*256 + threadIdx.x;
  if (i >= K*KWP*F*512) return;
  int j = i & 7, L = (i >> 3) & 63, rest = i >> 9;
  int f = rest % F, s = rest / F;
  int kh = s / KWP, kwp = s % KWP;
  int k = (L >> 4)*8 + j;
  int kw = 2*kwp + (k >> 4), ic = k & 15;
  int oc = f*16 + (L & 15);
  float v = (kw < K) ? w[((size_t)(oc*16 + ic)*K + kh)*K + kw] : 0.f;
  unsigned short h = f2bf(v);
  hi[i] = h; lo[i] = f2bf(v - bf2f(h));
}

// ------- pack scout1(k7) + conv1(k3) weights, space-to-depth frag order -----
// k = tap*48 + c, c = ic*16 + pr*4 + pc ; tap t: dr=(t>>1)-1, dc=(t&1)-1
// nf 0 = scout oc (pad 3), nf 1 = conv1 oc (pad 1)
__global__ __launch_bounds__(256) void wpackF_k(const float* __restrict__ sw1,
    const float* __restrict__ tw1,
    unsigned short* __restrict__ hi, unsigned short* __restrict__ lo){
  int i = blockIdx.x*256 + threadIdx.x;
  if (i >= 6*2*512) return;
  int j = i & 7, L = (i >> 3) & 63, rest = i >> 9;
  int nf = rest & 1, s = rest >> 1;
  int k = s*32 + (L >> 4)*8 + j;
  int oc = L & 15;
  int t = k / 48, c = k % 48;
  int dr = (t >> 1) - 1, dc = (t & 1) - 1;
  int ic = c >> 4, pr = (c >> 2) & 3, pc = c & 3;
  float v = 0.f;
  if (nf == 0){
    int kh = 4*dr + pr + 3, kw = 4*dc + pc + 3;
    if (kh >= 0 && kh < 7 && kw >= 0 && kw < 7) v = sw1[((oc*3 + ic)*7 + kh)*7 + kw];
  } else {
    int kh = 4*dr + pr + 1, kw = 4*dc + pc + 1;
    if (kh >= 0 && kh < 3 && kw >= 0 && kw < 3) v = tw1[((oc*3 + ic)*3 + kh)*3 + kw];
  }
  unsigned short h = f2bf(v);
  hi[i] = h; lo[i] = f2bf(v - bf2f(h));
}

// ------- pack expert GEMM weights W[e][N][K] into frag order, bf16 hi/lo ----
template<int KTOT>
__global__ __launch_bounds__(256) void wpackG_k(const float* __restrict__ w, int N,
    unsigned short* __restrict__ hi, unsigned short* __restrict__ lo){
  const int NF = N >> 4, KT = KTOT >> 5;
  const int total = NF * KT * 512;
  const int e = blockIdx.y;
  w  += (size_t)e * N * KTOT;
  hi += (size_t)e * total; lo += (size_t)e * total;
  int i = blockIdx.x*256 + threadIdx.x;
  if (i >= total) return;
  int j = i & 7, L = (i >> 3) & 63, rest = i >> 9;
  int nf = rest % NF, t = rest / NF;
  int n = nf*16 + (L & 15), k = t*32 + (L >> 4)*8 + j;
  float v = w[(size_t)n*KTOT + k];
  unsigned short h = f2bf(v);
  hi[i] = h; lo[i] = f2bf(v - bf2f(h));
}

// ------- split fp32 array into bf16 hi/lo ----------------------------------
__global__ __launch_bounds__(256) void asplit_k(const float* __restrict__ in,
    unsigned short* __restrict__ hi, unsigned short* __restrict__ lo, int nelem){
  int i = blockIdx.x*256 + threadIdx.x;
  if (i >= nelem) return;
  float v = in[i];
  unsigned short h = f2bf(v);
  hi[i] = h; lo[i] = f2bf(v - bf2f(h));
}

// ---------- fused scout1+conv1 via space-to-depth MFMA (stride4 -> 2x2 s1) --
// LDS: [3 rowgrp][58 col][64ch-pad] bf16 hi/lo, byte-XOR ((col&7)<<4) swizzle.
// Channel slot c = ic*16 + pr*4 + pc -> one staged float4 = 4 contiguous
// ushort = one ds_write_b64 per hi/lo. 4 waves x {2 m-frags, 2 n-frags}.
__global__ __launch_bounds__(256) void fusedM_k(
    const float* __restrict__ x,
    const unsigned short* __restrict__ Wh, const unsigned short* __restrict__ Wl,
    const float* __restrict__ sb, const float* __restrict__ cb_,
    const float* __restrict__ g, const float* __restrict__ bt,
    const float* __restrict__ mn, const float* __restrict__ vr,
    float* __restrict__ s1out, float* __restrict__ c1out){
  __shared__ __align__(16) unsigned short Ah[3*58*64];
  __shared__ __align__(16) unsigned short Al[3*58*64];
  const int tid = threadIdx.x;
  const int n = blockIdx.x / 28, oh0 = (blockIdx.x % 28) * 2;

  { // zero both LDS tiles (covers OOB rows, border cols, pad channels)
    int4* a = (int4*)Ah; int4* b = (int4*)Al;
    for (int i = tid; i < 1392; i += 256){
      a[i] = (int4){0,0,0,0}; b[i] = (int4){0,0,0,0};
    }
  }
  __syncthreads();

  // stage 12 x-rows x 3 ic x 224 cols (coalesced float4), space-to-depth
  for (int i = tid; i < 2016; i += 256){
    int m = i % 56; int rc = i / 56;
    int ic = rc % 3, ridx = rc / 3;
    int ih = 4*oh0 - 4 + ridx;
    if (ih < 0 || ih >= 224) continue;
    float4 v = *(const float4*)(x + ((size_t)(n*3 + ic)*224 + ih)*224 + 4*m);
    int rr = ridx >> 2, pr = ridx & 3, cc = m + 1;
    int boff = (((rr*58 + cc) << 7) + ic*32 + pr*8) ^ ((cc & 7) << 4);
    float vv[4] = {v.x, v.y, v.z, v.w};
    unsigned short h4[4], l4[4];
    #pragma unroll
    for (int q = 0; q < 4; ++q){
      h4[q] = f2bf(vv[q]);
      l4[q] = f2bf(vv[q] - bf2f(h4[q]));
    }
    *(ulong1*)((char*)Ah + boff) = *(ulong1*)h4;
    *(ulong1*)((char*)Al + boff) = *(ulong1*)l4;
  }
  __syncthreads();

  const int wid = tid >> 6, lane = tid & 63;
  const int kg8 = (lane >> 4) * 8;
  f32x4 acc[2][2];
  #pragma unroll
  for (int mi = 0; mi < 2; ++mi)
    #pragma unroll
    for (int nf = 0; nf < 2; ++nf) acc[mi][nf] = (f32x4){0.f,0.f,0.f,0.f};

  #pragma unroll
  for (int s = 0; s < 6; ++s){
    const int kk = s*32 + kg8;
    const int t = kk / 48, c0 = kk - t*48;     // 8-elem group within one tap
    const int ra = t >> 1, ca = t & 1;
    bf16x8 ah[2], al[2];
    #pragma unroll
    for (int mi = 0; mi < 2; ++mi){
      const int m = 2*wid + mi;
      const int rowsel = m >> 2;
      const int ow = (m & 3)*16 + (lane & 15);
      const int owc = ow > 55 ? 55 : ow;
      const int col = owc + ca;
      const int bidx = ((((rowsel + ra)*58 + col) << 7) + c0*2) ^ ((col & 7) << 4);
      ah[mi] = *(const bf16x8*)((const char*)Ah + bidx);
      al[mi] = *(const bf16x8*)((const char*)Al + bidx);
    }
    #pragma unroll
    for (int nf = 0; nf < 2; ++nf){
      const int fb = (s*2 + nf)*512 + lane*8;
      bf16x8 bh = *(const bf16x8*)(Wh + fb);
      bf16x8 bl = *(const bf16x8*)(Wl + fb);
      #pragma unroll
      for (int mi = 0; mi < 2; ++mi){
        acc[mi][nf] = __builtin_amdgcn_mfma_f32_16x16x32_bf16(ah[mi], bh, acc[mi][nf], 0,0,0);
        acc[mi][nf] = __builtin_amdgcn_mfma_f32_16x16x32_bf16(ah[mi], bl, acc[mi][nf], 0,0,0);
        acc[mi][nf] = __builtin_amdgcn_mfma_f32_16x16x32_bf16(al[mi], bh, acc[mi][nf], 0,0,0);
      }
    }
  }

  const int oc = lane & 15;
  const float sbv = sb[oc];
  const float scv = g[oc] * __frsqrt_rn(vr[oc] + 1e-5f);
  const float mnv = mn[oc], btv = bt[oc], cbv = cb_[oc];
  #pragma unroll
  for (int mi = 0; mi < 2; ++mi){
    const int m = 2*wid + mi;
    const int row = oh0 + (m >> 2);
    const int owb = (m & 3)*16 + (lane >> 4)*4;
    #pragma unroll
    for (int r = 0; r < 4; ++r){
      const int ow = owb + r;
      if (ow >= 56) continue;
      float vs = acc[mi][0][r] + sbv;
      vs = fmaxf((vs - mnv)*scv + btv, 0.f);
      s1out[((size_t)(n*16 + oc)*56 + row)*56 + ow] = vs;
      c1out[((size_t)(n*16 + oc)*56 + row)*56 + ow] = leakyf(acc[mi][1][r] + cbv);
    }
  }
}

// ---------------- strided (S=2) MFMA conv, IC=16, out 28x28 NHWC fp32 -------
template<int OC,int K,int P,int IH,int IW,int ACT>
__global__ __launch_bounds__(256) void convS_k(
    const float* __restrict__ in,
    const unsigned short* __restrict__ Wh, const unsigned short* __restrict__ Wl,
    const float* __restrict__ bias,
    const float* __restrict__ bng, const float* __restrict__ bnb,
    const float* __restrict__ bnm, const float* __restrict__ bnv,
    float* __restrict__ outNHWC){
  constexpr int F = OC/16, KWP = (K+1)/2;
  __shared__ __align__(16) unsigned short Ah[K*60*16];
  __shared__ __align__(16) unsigned short Al[K*60*16];

  const int tid = threadIdx.x;
  const int n = blockIdx.x / 28, oh = blockIdx.x % 28;

  for (int i = tid; i < K*16*60; i += 256){
    int c = i % 60; int q = i / 60;
    int ic = q & 15, r = q >> 4;
    int ih = 2*oh - P + r, iw = c - P;
    float v = 0.f;
    if (ih >= 0 && ih < IH && iw >= 0 && iw < IW)
      v = in[((size_t)(n*16 + ic)*IH + ih)*IW + iw];
    unsigned short h = f2bf(v);
    unsigned short l = f2bf(v - bf2f(h));
    int byte = ((r*60 + c)*32 + ic*2) ^ (((c>>1)&7) << 4);
    *(unsigned short*)((char*)Ah + byte) = h;
    *(unsigned short*)((char*)Al + byte) = l;
  }
  __syncthreads();

  const int wid = tid >> 6, lane = tid & 63;
  const int fsel = wid & 1, mb = wid >> 1;
  const int ow_l = min(mb*16 + (lane & 15), 27);
  const int ic0b = ((lane >> 4) & 1) * 16;
  const int kwo  = (lane >> 4) >> 1;

  f32x4 acc = {0.f,0.f,0.f,0.f};
  #pragma unroll
  for (int kh = 0; kh < K; ++kh){
    #pragma unroll
    for (int kwp = 0; kwp < KWP; ++kwp){
      const int kw = 2*kwp + kwo;
      const int c = 2*ow_l + kw;
      int byte = ((kh*60 + c)*32 + ic0b) ^ (((c>>1)&7) << 4);
      bf16x8 ah = *(const bf16x8*)((const char*)Ah + byte);
      bf16x8 al = *(const bf16x8*)((const char*)Al + byte);
      const int s = kh*KWP + kwp;
      const int fb = (s*F + fsel)*512 + lane*8;
      bf16x8 bh = *(const bf16x8*)(Wh + fb);
      bf16x8 bl = *(const bf16x8*)(Wl + fb);
      acc = __builtin_amdgcn_mfma_f32_16x16x32_bf16(ah, bh, acc, 0,0,0);
      acc = __builtin_amdgcn_mfma_f32_16x16x32_bf16(ah, bl, acc, 0,0,0);
      acc = __builtin_amdgcn_mfma_f32_16x16x32_bf16(al, bh, acc, 0,0,0);
    }
  }

  const int oc = fsel*16 + (lane & 15);
  float bv = bias[oc], sc = 1.f, mm = 0.f, bb = 0.f;
  if (ACT == 1){
    sc = bng[oc] * __frsqrt_rn(bnv[oc] + 1e-5f);
    mm = bnm[oc]; bb = bnb[oc];
  }
  #pragma unroll
  for (int r = 0; r < 4; ++r){
    const int ow = mb*16 + (lane >> 4)*4 + r;
    if (ow >= 28) continue;
    float v = acc[r] + bv;
    if (ACT == 1) v = fmaxf((v - mm)*sc + bb, 0.f);
    else          v = leakyf(v);
    outNHWC[(((size_t)n*28 + oh)*28 + ow)*OC + oc] = v;
  }
}

// ---------------- MFMA split-bf16 3x3 s1 p1 conv on 27x27, padded NHWC ------
template<int IC,int OC,int OUTM>
__global__ __launch_bounds__(256) void convM_k(
    const unsigned short* __restrict__ Ahi_g, const unsigned short* __restrict__ Alo_g,
    const unsigned short* __restrict__ Whi, const unsigned short* __restrict__ Wlo,
    const float* __restrict__ bias,
    unsigned short* __restrict__ OutHi, unsigned short* __restrict__ OutLo,
    float* __restrict__ OutF)
{
  constexpr int S = IC/32, FTOT = OC/16, FW = FTOT/2;
  constexpr int ICB = IC*2, ICG = ICB/16;
  __shared__ __align__(16) char Ah[4*34*ICB];
  __shared__ __align__(16) char Al[4*34*ICB];

  const int tid = threadIdx.x;
  const int bx = blockIdx.x;
  const int n = bx / 14, pr = bx % 14;
  const int oh0 = pr * 2;

  const size_t gbase = ((size_t)n*29) * 29 * IC;
  for (int g = tid; g < 4*34*ICG; g += 256){
    int r = g / (34*ICG);
    int rem = g - r*(34*ICG);
    int c = rem / ICG, q = rem - c*ICG;
    int rp = oh0 + r;
    int4 vh = {0,0,0,0}, vl = {0,0,0,0};
    if (rp <= 28 && c < 29){
      size_t e = gbase + ((size_t)rp*29 + c)*IC + q*8;
      vh = *(const int4*)(Ahi_g + e);
      vl = *(const int4*)(Alo_g + e);
    }
    int off = (r*34 + c)*ICB + q*16;
    int swz = off ^ ((c & 7) << 4);
    *(int4*)(Ah + swz) = vh;
    *(int4*)(Al + swz) = vl;
  }
  __syncthreads();

  const int wid = tid >> 6, lane = tid & 63;
  const int rsel = wid & 1, ocq = wid >> 1;
  const int c0 = lane & 15, kg = (lane >> 4) * 16;
  const int colb0 = c0*ICB + kg, colb1 = (16 + c0)*ICB + kg;
  int msk[3];
  #pragma unroll
  for (int kw = 0; kw < 3; ++kw) msk[kw] = ((c0 + kw) & 7) << 4;

  f32x4 acc[2][FW];
  #pragma unroll
  for (int m = 0; m < 2; ++m)
    #pragma unroll
    for (int f = 0; f < FW; ++f) acc[m][f] = (f32x4){0.f,0.f,0.f,0.f};

  #pragma unroll
  for (int kh = 0; kh < 3; ++kh){
    #pragma unroll
    for (int kw = 0; kw < 3; ++kw){
      #pragma unroll
      for (int s = 0; s < S; ++s){
        const int fr0 = (((kh*3 + kw)*S + s)*FTOT + ocq*FW) * 512 + lane*8;
        bf16x8 bh[FW], bl[FW];
        #pragma unroll
        for (int f = 0; f < FW; ++f){
          bh[f] = *(const bf16x8*)(Whi + fr0 + f*512);
          bl[f] = *(const bf16x8*)(Wlo + fr0 + f*512);
        }
        const int base = ((rsel + kh)*34 + kw)*ICB + s*64;
        const int o0 = (base + colb0) ^ msk[kw];
        const int o1 = (base + colb1) ^ msk[kw];
        bf16x8 ah0 = *(const bf16x8*)(Ah + o0);
        bf16x8 al0 = *(const bf16x8*)(Al + o0);
        bf16x8 ah1 = *(const bf16x8*)(Ah + o1);
        bf16x8 al1 = *(const bf16x8*)(Al + o1);
        #pragma unroll
        for (int f = 0; f < FW; ++f){
          acc[0][f] = __builtin_amdgcn_mfma_f32_16x16x32_bf16(ah0, bh[f], acc[0][f], 0,0,0);
          acc[0][f] = __builtin_amdgcn_mfma_f32_16x16x32_bf16(ah0, bl[f], acc[0][f], 0,0,0);
          acc[0][f] = __builtin_amdgcn_mfma_f32_16x16x32_bf16(al0, bh[f], acc[0][f], 0,0,0);
          acc[1][f] = __builtin_amdgcn_mfma_f32_16x16x32_bf16(ah1, bh[f], acc[1][f], 0,0,0);
          acc[1][f] = __builtin_amdgcn_mfma_f32_16x16x32_bf16(ah1, bl[f], acc[1][f], 0,0,0);
          acc[1][f] = __builtin_amdgcn_mfma_f32_16x16x32_bf16(al1, bh[f], acc[1][f], 0,0,0);
        }
      }
    }
  }

  const int orow = oh0 + rsel;
  if (orow >= 27) return;
  #pragma unroll
  for (int f = 0; f < FW; ++f){
    const int oc = (ocq*FW + f)*16 + c0;
    const float bv = bias[oc];
    #pragma unroll
    for (int m = 0; m < 2; ++m){
      #pragma unroll
      for (int r = 0; r < 4; ++r){
        const int ow = m*16 + (lane >> 4)*4 + r;
        if (ow >= 27) continue;
        float v = leakyf(acc[m][f][r] + bv);
        if (OUTM == 0){
          size_t o = (((size_t)n*29 + orow+1)*29 + ow+1)*OC + oc;
          unsigned short h = f2bf(v);
          OutHi[o] = h;
          OutLo[o] = f2bf(v - bf2f(h));
        } else {
          OutF[(((size_t)n*27 + orow)*27 + ow)*OC + oc] = v;
        }
      }
    }
  }
}

// ---------------- split-bf16 MFMA GEMM for MoE head -------------------------
template<int KTOT,int ACT,int OUTM>
__global__ __launch_bounds__(256) void gemmM_k(
    const unsigned short* __restrict__ Ah, const unsigned short* __restrict__ Al,
    long strideA,
    const unsigned short* __restrict__ Wh, const unsigned short* __restrict__ Wl,
    const float* __restrict__ bias, int N,
    unsigned short* __restrict__ OutH, unsigned short* __restrict__ OutL,
    float* __restrict__ OutF){
  const int e = blockIdx.z;
  Ah += (size_t)e * strideA; Al += (size_t)e * strideA;
  const int NF = N >> 4, KT = KTOT >> 5;
  const size_t wb = (size_t)e * NF * KT * 512;
  Wh += wb; Wl += wb;
  const float* bs = bias + (size_t)e * N;
  const size_t ob = (size_t)e * 256 * N;

  const int tid = threadIdx.x, wid = tid >> 6, lane = tid & 63;
  const int mblk = blockIdx.x * 32;
  const int nf = blockIdx.y * 4 + wid;
  const int r0 = mblk + (lane & 15);
  const int kof = (lane >> 4) * 8;

  f32x4 acc0 = {0,0,0,0}, acc1 = {0,0,0,0};
  for (int t = 0; t < KT; ++t){
    const int k = t*32 + kof;
    bf16x8 ah0 = *(const bf16x8*)(Ah + (size_t)r0*KTOT + k);
    bf16x8 al0 = *(const bf16x8*)(Al + (size_t)r0*KTOT + k);
    bf16x8 ah1 = *(const bf16x8*)(Ah + (size_t)(r0+16)*KTOT + k);
    bf16x8 al1 = *(const bf16x8*)(Al + (size_t)(r0+16)*KTOT + k);
    const size_t fb = ((size_t)t*NF + nf)*512 + lane*8;
    bf16x8 bh = *(const bf16x8*)(Wh + fb);
    bf16x8 bl = *(const bf16x8*)(Wl + fb);
    acc0 = __builtin_amdgcn_mfma_f32_16x16x32_bf16(ah0, bh, acc0, 0,0,0);
    acc0 = __builtin_amdgcn_mfma_f32_16x16x32_bf16(ah0, bl, acc0, 0,0,0);
    acc0 = __builtin_amdgcn_mfma_f32_16x16x32_bf16(al0, bh, acc0, 0,0,0);
    acc1 = __builtin_amdgcn_mfma_f32_16x16x32_bf16(ah1, bh, acc1, 0,0,0);
    acc1 = __builtin_amdgcn_mfma_f32_16x16x32_bf16(ah1, bl, acc1, 0,0,0);
    acc1 = __builtin_amdgcn_mfma_f32_16x16x32_bf16(al1, bh, acc1, 0,0,0);
  }
  const int n = nf*16 + (lane & 15);
  const float bv = bs[n];
  #pragma unroll
  for (int mi = 0; mi < 2; ++mi){
    f32x4 a = mi ? acc1 : acc0;
    #pragma unroll
    for (int r = 0; r < 4; ++r){
      const int m = mblk + mi*16 + (lane >> 4)*4 + r;
      float v = a[r] + bv;
      if (ACT == 1) v = leakyf(v);
      const size_t o = ob + (size_t)m*N + n;
      if (OUTM == 0){
        unsigned short h = f2bf(v);
        OutH[o] = h; OutL[o] = f2bf(v - bf2f(h));
      } else {
        OutF[o] = v;
      }
    }
  }
}

// ---------------- 2x2 stride-1 maxpool (NCHW) ----------------
template<int C,int IH,int IW>
__global__ __launch_bounds__(256) void pool_k(const float* __restrict__ in,
                                              float* __restrict__ out){
  constexpr int OH = IH - 1, OW = IW - 1;
  int idx = blockIdx.x * 256 + threadIdx.x;
  if (idx >= BATCH * C * OH * OW) return;
  int ow = idx % OW; int t = idx / OW;
  int oh = t % OH;   t /= OH;
  const float* p = in + ((size_t)t * IH + oh) * IW + ow;
  out[idx] = fmaxf(fmaxf(p[0], p[1]), fmaxf(p[IW], p[IW + 1]));
}

// ------- pool2: NHWC fp32 [B,28,28,32] -> padded NHWC bf16 hi/lo [B,29,29,32]
__global__ __launch_bounds__(256) void pool2n_k(const float* __restrict__ in,
    unsigned short* __restrict__ hi, unsigned short* __restrict__ lo){
  int idx = blockIdx.x*256 + threadIdx.x;
  if (idx >= BATCH*27*27*32) return;
  int ic = idx & 31; int p = idx >> 5;
  int ow = p % 27; int t = p / 27; int oh = t % 27; int n = t / 27;
  const float* b = in + (((size_t)n*28 + oh)*28 + ow)*32 + ic;
  float v = fmaxf(fmaxf(b[0], b[32]), fmaxf(b[28*32], b[29*32]));
  size_t o = (((size_t)n*29 + oh+1)*29 + ow+1)*32 + ic;
  unsigned short h = f2bf(v);
  hi[o] = h; lo[o] = f2bf(v - bf2f(h));
}

// ---------------- scout gate (NHWC input [B,28,28,32]) ----------------
__global__ __launch_bounds__(256) void gate_k(const float* __restrict__ s2,
                                              const float* __restrict__ cw,
                                              const float* __restrict__ cb,
                                              float* __restrict__ comb){
  int n = blockIdx.x;
  int tid = threadIdx.x;
  int c = tid & 31;
  int sub = tid >> 5;
  const float* p = s2 + (size_t)n * 784 * 32 + c;
  float s = 0.f;
  for (int i = sub * 98; i < sub * 98 + 98; ++i) s += p[(size_t)i * 32];
  __shared__ float red[32][8];
  red[c][sub] = s;
  __syncthreads();
  if (tid < 32){
    float tot = 0.f;
    #pragma unroll
    for (int k = 0; k < 8; ++k) tot += red[tid][k];
    red[tid][0] = tot / 784.f;
  }
  __syncthreads();
  if (tid == 0){
    float lg[3];
    for (int e = 0; e < 3; ++e){
      float a = cb[e];
      for (int c2 = 0; c2 < 32; ++c2) a += red[c2][0] * cw[e * 32 + c2];
      lg[e] = a;
    }
    float m = fmaxf(lg[0], fmaxf(lg[1], lg[2]));
    float ex[3], sum = 0.f;
    for (int e = 0; e < 3; ++e){ ex[e] = expf(lg[e] - m); sum += ex[e]; }
    float pr[3];
    for (int e = 0; e < 3; ++e) pr[e] = ex[e] / sum;
    int i1 = 0;
    if (pr[1] > pr[0]) i1 = 1;
    if (pr[2] > pr[i1]) i1 = 2;
    int i2 = -1;
    for (int e = 0; e < 3; ++e){
      if (e == i1) continue;
      if (i2 < 0 || pr[e] > pr[i2]) i2 = e;
    }
    float s12 = pr[i1] + pr[i2] + 1e-6f;
    float cmb[3] = {0.f, 0.f, 0.f};
    cmb[i1] = pr[i1] / s12;
    cmb[i2] = pr[i2] / s12;
    comb[n * 3 + 0] = cmb[0];
    comb[n * 3 + 1] = cmb[1];
    comb[n * 3 + 2] = cmb[2];
  }
}

// ------ fused maxpool2s1(27->26) + adaptive avg(26->3), NHWC input ----------
__global__ __launch_bounds__(256) void papooln_k(const float* __restrict__ in,
                                                 float* __restrict__ flat){
  int idx = blockIdx.x * 256 + threadIdx.x;
  if (idx >= BATCH * 128 * 9) return;
  int j = idx % 3; int t = idx / 3;
  int i = t % 3;   t /= 3;
  int c = t % 128; int n = t / 128;
  int hs = (i * 26) / 3, he = ((i + 1) * 26 + 2) / 3;
  int ws = (j * 26) / 3, we = ((j + 1) * 26 + 2) / 3;
  const float* p = in + (size_t)n * 729 * 128 + c;
  float s = 0.f;
  for (int r = hs; r < he; ++r)
    for (int cc = ws; cc < we; ++cc){
      const float* q0 = p + (r * 27 + cc) * 128;
      const float* q1 = q0 + 27 * 128;
      float m = fmaxf(fmaxf(q0[0], q0[128]), fmaxf(q1[0], q1[128]));
      s += m;
    }
  flat[(size_t)n * 1152 + c * 9 + i * 3 + j] = s / (float)((he - hs) * (we - ws));
}

// ---------------- final gated combine ----------------
__global__ __launch_bounds__(256) void comb_k(const float* __restrict__ h3,
                                              const float* __restrict__ comb,
                                              float* __restrict__ out){
  int idx = blockIdx.x * 256 + threadIdx.x;
  if (idx >= BATCH * 512) return;
  int o = idx % 512, b = idx / 512;
  float s = 0.f;
  #pragma unroll
  for (int e = 0; e < 3; ++e)
    s += comb[b * 3 + e] * h3[((size_t)e * BATCH + b) * 512 + o];
  out[idx] = s;
}

// ============================================================================
extern "C" void kernel_launch(void* const* d_in, const int* in_sizes, int n_in,
                              void* d_out, int out_size, void* d_ws, size_t ws_size,
                              hipStream_t stream){
  const float* x    = (const float*)d_in[0];
  const float* tw1  = (const float*)d_in[1];  const float* tb1 = (const float*)d_in[2];
  const float* tw2  = (const float*)d_in[3];  const float* tb2 = (const float*)d_in[4];
  const float* tw3  = (const float*)d_in[5];  const float* tb3 = (const float*)d_in[6];
  const float* tw4  = (const float*)d_in[7];  const float* tb4 = (const float*)d_in[8];
  const float* sw1  = (const float*)d_in[9];  const float* sb1 = (const float*)d_in[10];
  const float* bn1g = (const float*)d_in[11]; const float* bn1b = (const float*)d_in[12];
  const float* bn1m = (const float*)d_in[13]; const float* bn1v = (const float*)d_in[14];
  const float* sw2  = (const float*)d_in[15]; const float* sb2 = (const float*)d_in[16];
  const float* bn2g = (const float*)d_in[17]; const float* bn2b = (const float*)d_in[18];
  const float* bn2m = (const float*)d_in[19]; const float* bn2v = (const float*)d_in[20];
  const float* cw   = (const float*)d_in[21]; const float* cb  = (const float*)d_in[22];
  const float* ew1  = (const float*)d_in[23]; const float* eb1 = (const float*)d_in[24];
  const float* ew2  = (const float*)d_in[25]; const float* eb2 = (const float*)d_in[26];
  const float* ew3  = (const float*)d_in[27]; const float* eb3 = (const float*)d_in[28];
  float* out = (float*)d_out;

  // ---- workspace layout (floats), ~157 MB ----
  float* ws = (float*)d_ws;
  size_t off = 0;
  float* comb   = ws + off; off += 768;
  float* flat   = ws + off; off += (size_t)BATCH * 1152;
  float* h3     = ws + off; off += (size_t)BATCH * 3 * 512;
  unsigned short* wpk3h = (unsigned short*)(ws + off); off += 9216;
  unsigned short* wpk3l = (unsigned short*)(ws + off); off += 9216;
  unsigned short* wpk4h = (unsigned short*)(ws + off); off += 36864;
  unsigned short* wpk4l = (unsigned short*)(ws + off); off += 36864;
  unsigned short* wp2h  = (unsigned short*)(ws + off); off += 7680;
  unsigned short* wp2l  = (unsigned short*)(ws + off); off += 7680;
  unsigned short* wps2h = (unsigned short*)(ws + off); off += 3072;
  unsigned short* wps2l = (unsigned short*)(ws + off); off += 3072;
  unsigned short* wpfh  = (unsigned short*)(ws + off); off += 3072;
  unsigned short* wpfl  = (unsigned short*)(ws + off); off += 3072;
  off += 16;                                                      // guard pad
  float* bufA   = ws + off; off += 13778944;
  off += 16;                                                      // guard pad
  float* bufB   = ws + off; off += 23887872;
  off += 16;
  (void)ws_size; (void)in_sizes; (void)n_in; (void)out_size;

  // phase aliases (lifetimes disjoint, single-stream ordered)
  float* s1out = bufA;                       // [B,16,56,56] NCHW
  float* c1out = bufB;                       // [B,16,56,56] NCHW
  float* s2out = bufB + 16000000;            // [B,28,28,32] NHWC
  float* p1out = bufA;                       // [B,16,55,55] NCHW
  float* c2out = bufB;                       // [B,28,28,32] NHWC
  unsigned short* P2h = (unsigned short*)(bufB + 8000000);
  unsigned short* P2l = P2h + (size_t)6889472;
  unsigned short* C3h = (unsigned short*)bufA;
  unsigned short* C3l = C3h + (size_t)13778944;
  float* c4out = bufB;                       // [B,27,27,128] NHWC

  // head-phase aliases in bufB (valid after papooln_k)
  unsigned short* ub = (unsigned short*)bufB;
  size_t uo = 0;
  unsigned short* ewp1h = ub + uo; uo += 3538944;
  unsigned short* ewp1l = ub + uo; uo += 3538944;
  unsigned short* ewp2h = ub + uo; uo += 1572864;
  unsigned short* ewp2l = ub + uo; uo += 1572864;
  unsigned short* ewp3h = ub + uo; uo += 786432;
  unsigned short* ewp3l = ub + uo; uo += 786432;
  unsigned short* fh    = ub + uo; uo += 294912;
  unsigned short* fl    = ub + uo; uo += 294912;
  unsigned short* h1h   = ub + uo; uo += 786432;
  unsigned short* h1l   = ub + uo; uo += 786432;
  unsigned short* h2h   = ub + uo; uo += 393216;
  unsigned short* h2l   = ub + uo; uo += 393216;

  dim3 blk(256);

  // ---- weight prep ----
  wpack_k<32,64>  <<<dim3(72),  blk, 0, stream>>>(tw3, wpk3h, wpk3l);
  wpack_k<64,128> <<<dim3(288), blk, 0, stream>>>(tw4, wpk4h, wpk4l);
  wpackS_k<32,5><<<dim3(60), blk, 0, stream>>>(tw2, wp2h, wp2l);
  wpackS_k<32,3><<<dim3(24), blk, 0, stream>>>(sw2, wps2h, wps2l);
  wpackF_k<<<dim3(24), blk, 0, stream>>>(sw1, tw1, wpfh, wpfl);

  // ---- fused scout1 + conv1 (space-to-depth MFMA, one pass over x) ----
  fusedM_k<<<dim3(BATCH*28), blk, 0, stream>>>(
      x, wpfh, wpfl, sb1, tb1, bn1g, bn1b, bn1m, bn1v, s1out, c1out);

  // ---- scout2 (MFMA strided) + gate ----
  convS_k<32,3,1,56,56,1><<<dim3(BATCH*28), blk, 0, stream>>>(
      s1out, wps2h, wps2l, sb2, bn2g, bn2b, bn2m, bn2v, s2out);
  gate_k<<<dim3(256), blk, 0, stream>>>(s2out, cw, cb, comb);

  // ---- pool1 -> conv2 (MFMA strided) ----
  pool_k<16,56,56><<<dim3(48400), blk, 0, stream>>>(c1out, p1out);
  convS_k<32,5,2,55,55,0><<<dim3(BATCH*28), blk, 0, stream>>>(
      p1out, wp2h, wp2l, tb2, nullptr, nullptr, nullptr, nullptr, c2out);

  // ---- pool2 -> padded NHWC bf16 hi/lo ----
  hipMemsetAsync(bufB + 8000000, 0, (size_t)2 * 6889472 * 2, stream);
  pool2n_k<<<dim3((BATCH*27*27*32 + 255)/256), blk, 0, stream>>>(c2out, P2h, P2l);

  // ---- conv3 (MFMA) -> padded NHWC bf16 hi/lo ----
  hipMemsetAsync(bufA, 0, (size_t)2 * 13778944 * 2, stream);
  convM_k<32,64,0><<<dim3(BATCH*14), blk, 0, stream>>>(
      P2h, P2l, wpk3h, wpk3l, tb3, C3h, C3l, nullptr);

  // ---- conv4 (MFMA) -> fp32 NHWC [B,27,27,128] ----
  convM_k<64,128,1><<<dim3(BATCH*14), blk, 0, stream>>>(
      C3h, C3l, wpk4h, wpk4l, tb4, nullptr, nullptr, c4out);

  papooln_k<<<dim3(1152), blk, 0, stream>>>(c4out, flat);

  // ---- MoE head: pack weights + split A, then 3 MFMA GEMMs ----
  wpackG_k<1152><<<dim3(4608,3), blk, 0, stream>>>(ew1, 1024, ewp1h, ewp1l);
  wpackG_k<1024><<<dim3(2048,3), blk, 0, stream>>>(ew2,  512, ewp2h, ewp2l);
  wpackG_k< 512><<<dim3(1024,3), blk, 0, stream>>>(ew3,  512, ewp3h, ewp3l);
  asplit_k<<<dim3(1152), blk, 0, stream>>>(flat, fh, fl, BATCH*1152);

  gemmM_k<1152,1,0><<<dim3(8,16,3), blk, 0, stream>>>(
      fh, fl, 0L, ewp1h, ewp1l, eb1, 1024, h1h, h1l, nullptr);
  gemmM_k<1024,1,0><<<dim3(8,8,3), blk, 0, stream>>>(
      h1h, h1l, 256L*1024, ewp2h, ewp2l, eb2, 512, h2h, h2l, nullptr);
  gemmM_k< 512,0,1><<<dim3(8,8,3), blk, 0, stream>>>(
      h2h, h2l, 256L*512, ewp3h, ewp3l, eb3, 512, nullptr, nullptr, h3);

  comb_k<<<dim3(512), blk, 0, stream>>>(h3, comb, out);
}

// Round 10
// 623.993 us; speedup vs baseline: 1.0620x; 1.0620x over previous
//
#include <hip/hip_runtime.h>

#define DEV static __device__ __forceinline__

constexpr int BATCH = 256;

DEV float leakyf(float x){ return x > 0.f ? x : 0.2f * x; }

typedef short bf16x8 __attribute__((ext_vector_type(8)));
typedef _Float16 f16x8 __attribute__((ext_vector_type(8)));
typedef float f32x4 __attribute__((ext_vector_type(4)));

DEV unsigned short f2bf(float v){
  union { float f; unsigned u; } x; x.f = v;
  unsigned r = x.u + 0x7fffu + ((x.u >> 16) & 1u);
  return (unsigned short)(r >> 16);
}
DEV float bf2f(unsigned short b){
  union { unsigned u; float f; } x; x.u = ((unsigned)b) << 16;
  return x.f;
}

// ------- pack OIHW conv weights into MFMA B-fragment order, bf16 hi/lo ------
template<int IC,int OC>
__global__ __launch_bounds__(256) void wpack_k(const float* __restrict__ w,
    unsigned short* __restrict__ hi, unsigned short* __restrict__ lo){
  constexpr int S = IC/32, F = OC/16;
  int i = blockIdx.x*256 + threadIdx.x;
  if (i >= 9*S*F*512) return;
  int j = i & 7, L = (i >> 3) & 63, rest = i >> 9;
  int f = rest % F; int q2 = rest / F; int s = q2 % S; int t = q2 / S;
  int oc = f*16 + (L & 15), ic = s*32 + (L >> 4)*8 + j;
  float v = w[((size_t)oc*IC + ic)*9 + t];
  unsigned short h = f2bf(v);
  hi[i] = h; lo[i] = f2bf(v - bf2f(h));
}

// ------- pack strided-conv weights (IC=16): kstep = (kh, kw-pair) -----------
template<int OC,int K>
__global__ __launch_bounds__(256) void wpackS_k(const float* __restrict__ w,
    unsigned short* __restrict__ hi, unsigned short* __restrict__ lo){
  constexpr int F = OC/16, KWP = (K+1)/2;
  int i = blockIdx.x*256 + threadIdx.x;
  if (i >= K*KWP*F*512) return;
  int j = i & 7, L = (i >> 3) & 63, rest = i >> 9;
  int f = rest % F, s = rest / F;
  int kh = s / KWP, kwp = s % KWP;
  int k = (L >> 4)*8 + j;
  int kw = 2*kwp + (k >> 4), ic = k & 15;
  int oc = f*16 + (L & 15);
  float v = (kw < K) ? w[((size_t)(oc*16 + ic)*K + kh)*K + kw] : 0.f;
  unsigned short h = f2bf(v);
  hi[i] = h; lo[i] = f2bf(v - bf2f(h));
}

// ------- pack scout1(k7) + conv1(k3) weights, space-to-depth, single fp16 ---
// k = tap*48 + c, c = ic*16 + pr*4 + pc ; tap t: dr=(t>>1)-1, dc=(t&1)-1
// nf 0 = scout oc, nf 1 = conv1 oc
__global__ __launch_bounds__(256) void wpackF_k(const float* __restrict__ sw1,
    const float* __restrict__ tw1, _Float16* __restrict__ wp){
  int i = blockIdx.x*256 + threadIdx.x;
  if (i >= 6*2*512) return;
  int j = i & 7, L = (i >> 3) & 63, rest = i >> 9;
  int nf = rest & 1, s = rest >> 1;
  int k = s*32 + (L >> 4)*8 + j;
  int oc = L & 15;
  int t = k / 48, c = k % 48;
  int dr = (t >> 1) - 1, dc = (t & 1) - 1;
  int ic = c >> 4, pr = (c >> 2) & 3, pc = c & 3;
  float v = 0.f;
  if (nf == 0){
    int kh = 4*dr + pr + 3, kw = 4*dc + pc + 3;
    if (kh >= 0 && kh < 7 && kw >= 0 && kw < 7) v = sw1[((oc*3 + ic)*7 + kh)*7 + kw];
  } else {
    int kh = 4*dr + pr + 1, kw = 4*dc + pc + 1;
    if (kh >= 0 && kh < 3 && kw >= 0 && kw < 3) v = tw1[((oc*3 + ic)*3 + kh)*3 + kw];
  }
  wp[i] = (_Float16)v;
}

// ------- pack expert GEMM weights W[e][N][K] into frag order, bf16 hi/lo ----
template<int KTOT>
__global__ __launch_bounds__(256) void wpackG_k(const float* __restrict__ w, int N,
    unsigned short* __restrict__ hi, unsigned short* __restrict__ lo){
  const int NF = N >> 4, KT = KTOT >> 5;
  const int total = NF * KT * 512;
  const int e = blockIdx.y;
  w  += (size_t)e * N * KTOT;
  hi += (size_t)e * total; lo += (size_t)e * total;
  int i = blockIdx.x*256 + threadIdx.x;
  if (i >= total) return;
  int j = i & 7, L = (i >> 3) & 63, rest = i >> 9;
  int nf = rest % NF, t = rest / NF;
  int n = nf*16 + (L & 15), k = t*32 + (L >> 4)*8 + j;
  float v = w[(size_t)n*KTOT + k];
  unsigned short h = f2bf(v);
  hi[i] = h; lo[i] = f2bf(v - bf2f(h));
}

// ------- split fp32 array into bf16 hi/lo ----------------------------------
__global__ __launch_bounds__(256) void asplit_k(const float* __restrict__ in,
    unsigned short* __restrict__ hi, unsigned short* __restrict__ lo, int nelem){
  int i = blockIdx.x*256 + threadIdx.x;
  if (i >= nelem) return;
  float v = in[i];
  unsigned short h = f2bf(v);
  hi[i] = h; lo[i] = f2bf(v - bf2f(h));
}

// ---------- fused scout1+conv1, space-to-depth MFMA, SINGLE fp16 ------------
// LDS: one tile [3 rowgrp][58 col][64ch-pad] fp16, byte-XOR ((col&7)<<4).
// Channel slot c = ic*16 + pr*4 + pc -> one staged float4 = 4 contiguous fp16
// = one ds_write_b64. 4 waves x {2 m-frags, 2 n-frags}, 1 MFMA per frag-pair.
__global__ __launch_bounds__(256) void fusedM_k(
    const float* __restrict__ x,
    const _Float16* __restrict__ W,
    const float* __restrict__ sb, const float* __restrict__ cb_,
    const float* __restrict__ g, const float* __restrict__ bt,
    const float* __restrict__ mn, const float* __restrict__ vr,
    float* __restrict__ s1out, float* __restrict__ c1out){
  __shared__ __align__(16) _Float16 Ah[3*58*64];
  const int tid = threadIdx.x;
  const int n = blockIdx.x / 28, oh0 = (blockIdx.x % 28) * 2;

  { // zero LDS tile (covers OOB rows, border cols, pad channels)
    int4* a = (int4*)Ah;
    for (int i = tid; i < 1392; i += 256) a[i] = (int4){0,0,0,0};
  }
  __syncthreads();

  // stage 12 x-rows x 3 ic x 224 cols (coalesced float4), space-to-depth
  for (int i = tid; i < 2016; i += 256){
    int m = i % 56; int rc = i / 56;
    int ic = rc % 3, ridx = rc / 3;
    int ih = 4*oh0 - 4 + ridx;
    if (ih < 0 || ih >= 224) continue;
    float4 v = *(const float4*)(x + ((size_t)(n*3 + ic)*224 + ih)*224 + 4*m);
    int rr = ridx >> 2, pr = ridx & 3, cc = m + 1;
    int boff = (((rr*58 + cc) << 7) + ic*32 + pr*8) ^ ((cc & 7) << 4);
    _Float16 h4[4] = {(_Float16)v.x, (_Float16)v.y, (_Float16)v.z, (_Float16)v.w};
    *(unsigned long long*)((char*)Ah + boff) = *(unsigned long long*)h4;
  }
  __syncthreads();

  const int wid = tid >> 6, lane = tid & 63;
  const int kg8 = (lane >> 4) * 8;
  f32x4 acc[2][2];
  #pragma unroll
  for (int mi = 0; mi < 2; ++mi)
    #pragma unroll
    for (int nf = 0; nf < 2; ++nf) acc[mi][nf] = (f32x4){0.f,0.f,0.f,0.f};

  #pragma unroll
  for (int s = 0; s < 6; ++s){
    const int kk = s*32 + kg8;
    const int t = kk / 48, c0 = kk - t*48;     // 8-elem group within one tap
    const int ra = t >> 1, ca = t & 1;
    f16x8 ah[2];
    #pragma unroll
    for (int mi = 0; mi < 2; ++mi){
      const int m = 2*wid + mi;
      const int rowsel = m >> 2;
      const int ow = (m & 3)*16 + (lane & 15);
      const int owc = ow > 55 ? 55 : ow;
      const int col = owc + ca;
      const int bidx = ((((rowsel + ra)*58 + col) << 7) + c0*2) ^ ((col & 7) << 4);
      ah[mi] = *(const f16x8*)((const char*)Ah + bidx);
    }
    #pragma unroll
    for (int nf = 0; nf < 2; ++nf){
      const f16x8 bw = *(const f16x8*)(W + (s*2 + nf)*512 + lane*8);
      #pragma unroll
      for (int mi = 0; mi < 2; ++mi)
        acc[mi][nf] = __builtin_amdgcn_mfma_f32_16x16x32_f16(ah[mi], bw, acc[mi][nf], 0,0,0);
    }
  }

  const int oc = lane & 15;
  const float sbv = sb[oc];
  const float scv = g[oc] * __frsqrt_rn(vr[oc] + 1e-5f);
  const float mnv = mn[oc], btv = bt[oc], cbv = cb_[oc];
  #pragma unroll
  for (int mi = 0; mi < 2; ++mi){
    const int m = 2*wid + mi;
    const int row = oh0 + (m >> 2);
    const int owb = (m & 3)*16 + (lane >> 4)*4;
    #pragma unroll
    for (int r = 0; r < 4; ++r){
      const int ow = owb + r;
      if (ow >= 56) continue;
      float vs = acc[mi][0][r] + sbv;
      vs = fmaxf((vs - mnv)*scv + btv, 0.f);
      s1out[((size_t)(n*16 + oc)*56 + row)*56 + ow] = vs;
      c1out[((size_t)(n*16 + oc)*56 + row)*56 + ow] = leakyf(acc[mi][1][r] + cbv);
    }
  }
}

// ---------------- strided (S=2) MFMA conv, IC=16, out 28x28 NHWC fp32 -------
template<int OC,int K,int P,int IH,int IW,int ACT>
__global__ __launch_bounds__(256) void convS_k(
    const float* __restrict__ in,
    const unsigned short* __restrict__ Wh, const unsigned short* __restrict__ Wl,
    const float* __restrict__ bias,
    const float* __restrict__ bng, const float* __restrict__ bnb,
    const float* __restrict__ bnm, const float* __restrict__ bnv,
    float* __restrict__ outNHWC){
  constexpr int F = OC/16, KWP = (K+1)/2;
  __shared__ __align__(16) unsigned short Ah[K*60*16];
  __shared__ __align__(16) unsigned short Al[K*60*16];

  const int tid = threadIdx.x;
  const int n = blockIdx.x / 28, oh = blockIdx.x % 28;

  for (int i = tid; i < K*16*60; i += 256){
    int c = i % 60; int q = i / 60;
    int ic = q & 15, r = q >> 4;
    int ih = 2*oh - P + r, iw = c - P;
    float v = 0.f;
    if (ih >= 0 && ih < IH && iw >= 0 && iw < IW)
      v = in[((size_t)(n*16 + ic)*IH + ih)*IW + iw];
    unsigned short h = f2bf(v);
    unsigned short l = f2bf(v - bf2f(h));
    int byte = ((r*60 + c)*32 + ic*2) ^ (((c>>1)&7) << 4);
    *(unsigned short*)((char*)Ah + byte) = h;
    *(unsigned short*)((char*)Al + byte) = l;
  }
  __syncthreads();

  const int wid = tid >> 6, lane = tid & 63;
  const int fsel = wid & 1, mb = wid >> 1;
  const int ow_l = min(mb*16 + (lane & 15), 27);
  const int ic0b = ((lane >> 4) & 1) * 16;
  const int kwo  = (lane >> 4) >> 1;

  f32x4 acc = {0.f,0.f,0.f,0.f};
  #pragma unroll
  for (int kh = 0; kh < K; ++kh){
    #pragma unroll
    for (int kwp = 0; kwp < KWP; ++kwp){
      const int kw = 2*kwp + kwo;
      const int c = 2*ow_l + kw;
      int byte = ((kh*60 + c)*32 + ic0b) ^ (((c>>1)&7) << 4);
      bf16x8 ah = *(const bf16x8*)((const char*)Ah + byte);
      bf16x8 al = *(const bf16x8*)((const char*)Al + byte);
      const int s = kh*KWP + kwp;
      const int fb = (s*F + fsel)*512 + lane*8;
      bf16x8 bh = *(const bf16x8*)(Wh + fb);
      bf16x8 bl = *(const bf16x8*)(Wl + fb);
      acc = __builtin_amdgcn_mfma_f32_16x16x32_bf16(ah, bh, acc, 0,0,0);
      acc = __builtin_amdgcn_mfma_f32_16x16x32_bf16(ah, bl, acc, 0,0,0);
      acc = __builtin_amdgcn_mfma_f32_16x16x32_bf16(al, bh, acc, 0,0,0);
    }
  }

  const int oc = fsel*16 + (lane & 15);
  float bv = bias[oc], sc = 1.f, mm = 0.f, bb = 0.f;
  if (ACT == 1){
    sc = bng[oc] * __frsqrt_rn(bnv[oc] + 1e-5f);
    mm = bnm[oc]; bb = bnb[oc];
  }
  #pragma unroll
  for (int r = 0; r < 4; ++r){
    const int ow = mb*16 + (lane >> 4)*4 + r;
    if (ow >= 28) continue;
    float v = acc[r] + bv;
    if (ACT == 1) v = fmaxf((v - mm)*sc + bb, 0.f);
    else          v = leakyf(v);
    outNHWC[(((size_t)n*28 + oh)*28 + ow)*OC + oc] = v;
  }
}

// ---------------- MFMA split-bf16 3x3 s1 p1 conv on 27x27, padded NHWC ------
template<int IC,int OC,int OUTM>
__global__ __launch_bounds__(256) void convM_k(
    const unsigned short* __restrict__ Ahi_g, const unsigned short* __restrict__ Alo_g,
    const unsigned short* __restrict__ Whi, const unsigned short* __restrict__ Wlo,
    const float* __restrict__ bias,
    unsigned short* __restrict__ OutHi, unsigned short* __restrict__ OutLo,
    float* __restrict__ OutF)
{
  constexpr int S = IC/32, FTOT = OC/16, FW = FTOT/2;
  constexpr int ICB = IC*2, ICG = ICB/16;
  __shared__ __align__(16) char Ah[4*34*ICB];
  __shared__ __align__(16) char Al[4*34*ICB];

  const int tid = threadIdx.x;
  const int bx = blockIdx.x;
  const int n = bx / 14, pr = bx % 14;
  const int oh0 = pr * 2;

  const size_t gbase = ((size_t)n*29) * 29 * IC;
  for (int g = tid; g < 4*34*ICG; g += 256){
    int r = g / (34*ICG);
    int rem = g - r*(34*ICG);
    int c = rem / ICG, q = rem - c*ICG;
    int rp = oh0 + r;
    int4 vh = {0,0,0,0}, vl = {0,0,0,0};
    if (rp <= 28 && c < 29){
      size_t e = gbase + ((size_t)rp*29 + c)*IC + q*8;
      vh = *(const int4*)(Ahi_g + e);
      vl = *(const int4*)(Alo_g + e);
    }
    int off = (r*34 + c)*ICB + q*16;
    int swz = off ^ ((c & 7) << 4);
    *(int4*)(Ah + swz) = vh;
    *(int4*)(Al + swz) = vl;
  }
  __syncthreads();

  const int wid = tid >> 6, lane = tid & 63;
  const int rsel = wid & 1, ocq = wid >> 1;
  const int c0 = lane & 15, kg = (lane >> 4) * 16;
  const int colb0 = c0*ICB + kg, colb1 = (16 + c0)*ICB + kg;
  int msk[3];
  #pragma unroll
  for (int kw = 0; kw < 3; ++kw) msk[kw] = ((c0 + kw) & 7) << 4;

  f32x4 acc[2][FW];
  #pragma unroll
  for (int m = 0; m < 2; ++m)
    #pragma unroll
    for (int f = 0; f < FW; ++f) acc[m][f] = (f32x4){0.f,0.f,0.f,0.f};

  #pragma unroll
  for (int kh = 0; kh < 3; ++kh){
    #pragma unroll
    for (int kw = 0; kw < 3; ++kw){
      #pragma unroll
      for (int s = 0; s < S; ++s){
        const int fr0 = (((kh*3 + kw)*S + s)*FTOT + ocq*FW) * 512 + lane*8;
        bf16x8 bh[FW], bl[FW];
        #pragma unroll
        for (int f = 0; f < FW; ++f){
          bh[f] = *(const bf16x8*)(Whi + fr0 + f*512);
          bl[f] = *(const bf16x8*)(Wlo + fr0 + f*512);
        }
        const int base = ((rsel + kh)*34 + kw)*ICB + s*64;
        const int o0 = (base + colb0) ^ msk[kw];
        const int o1 = (base + colb1) ^ msk[kw];
        bf16x8 ah0 = *(const bf16x8*)(Ah + o0);
        bf16x8 al0 = *(const bf16x8*)(Al + o0);
        bf16x8 ah1 = *(const bf16x8*)(Ah + o1);
        bf16x8 al1 = *(const bf16x8*)(Al + o1);
        #pragma unroll
        for (int f = 0; f < FW; ++f){
          acc[0][f] = __builtin_amdgcn_mfma_f32_16x16x32_bf16(ah0, bh[f], acc[0][f], 0,0,0);
          acc[0][f] = __builtin_amdgcn_mfma_f32_16x16x32_bf16(ah0, bl[f], acc[0][f], 0,0,0);
          acc[0][f] = __builtin_amdgcn_mfma_f32_16x16x32_bf16(al0, bh[f], acc[0][f], 0,0,0);
          acc[1][f] = __builtin_amdgcn_mfma_f32_16x16x32_bf16(ah1, bh[f], acc[1][f], 0,0,0);
          acc[1][f] = __builtin_amdgcn_mfma_f32_16x16x32_bf16(ah1, bl[f], acc[1][f], 0,0,0);
          acc[1][f] = __builtin_amdgcn_mfma_f32_16x16x32_bf16(al1, bh[f], acc[1][f], 0,0,0);
        }
      }
    }
  }

  const int orow = oh0 + rsel;
  if (orow >= 27) return;
  #pragma unroll
  for (int f = 0; f < FW; ++f){
    const int oc = (ocq*FW + f)*16 + c0;
    const float bv = bias[oc];
    #pragma unroll
    for (int m = 0; m < 2; ++m){
      #pragma unroll
      for (int r = 0; r < 4; ++r){
        const int ow = m*16 + (lane >> 4)*4 + r;
        if (ow >= 27) continue;
        float v = leakyf(acc[m][f][r] + bv);
        if (OUTM == 0){
          size_t o = (((size_t)n*29 + orow+1)*29 + ow+1)*OC + oc;
          unsigned short h = f2bf(v);
          OutHi[o] = h;
          OutLo[o] = f2bf(v - bf2f(h));
        } else {
          OutF[(((size_t)n*27 + orow)*27 + ow)*OC + oc] = v;
        }
      }
    }
  }
}

// ---------------- split-bf16 MFMA GEMM for MoE head -------------------------
template<int KTOT,int ACT,int OUTM>
__global__ __launch_bounds__(256) void gemmM_k(
    const unsigned short* __restrict__ Ah, const unsigned short* __restrict__ Al,
    long strideA,
    const unsigned short* __restrict__ Wh, const unsigned short* __restrict__ Wl,
    const float* __restrict__ bias, int N,
    unsigned short* __restrict__ OutH, unsigned short* __restrict__ OutL,
    float* __restrict__ OutF){
  const int e = blockIdx.z;
  Ah += (size_t)e * strideA; Al += (size_t)e * strideA;
  const int NF = N >> 4, KT = KTOT >> 5;
  const size_t wb = (size_t)e * NF * KT * 512;
  Wh += wb; Wl += wb;
  const float* bs = bias + (size_t)e * N;
  const size_t ob = (size_t)e * 256 * N;

  const int tid = threadIdx.x, wid = tid >> 6, lane = tid & 63;
  const int mblk = blockIdx.x * 32;
  const int nf = blockIdx.y * 4 + wid;
  const int r0 = mblk + (lane & 15);
  const int kof = (lane >> 4) * 8;

  f32x4 acc0 = {0,0,0,0}, acc1 = {0,0,0,0};
  for (int t = 0; t < KT; ++t){
    const int k = t*32 + kof;
    bf16x8 ah0 = *(const bf16x8*)(Ah + (size_t)r0*KTOT + k);
    bf16x8 al0 = *(const bf16x8*)(Al + (size_t)r0*KTOT + k);
    bf16x8 ah1 = *(const bf16x8*)(Ah + (size_t)(r0+16)*KTOT + k);
    bf16x8 al1 = *(const bf16x8*)(Al + (size_t)(r0+16)*KTOT + k);
    const size_t fb = ((size_t)t*NF + nf)*512 + lane*8;
    bf16x8 bh = *(const bf16x8*)(Wh + fb);
    bf16x8 bl = *(const bf16x8*)(Wl + fb);
    acc0 = __builtin_amdgcn_mfma_f32_16x16x32_bf16(ah0, bh, acc0, 0,0,0);
    acc0 = __builtin_amdgcn_mfma_f32_16x16x32_bf16(ah0, bl, acc0, 0,0,0);
    acc0 = __builtin_amdgcn_mfma_f32_16x16x32_bf16(al0, bh, acc0, 0,0,0);
    acc1 = __builtin_amdgcn_mfma_f32_16x16x32_bf16(ah1, bh, acc1, 0,0,0);
    acc1 = __builtin_amdgcn_mfma_f32_16x16x32_bf16(ah1, bl, acc1, 0,0,0);
    acc1 = __builtin_amdgcn_mfma_f32_16x16x32_bf16(al1, bh, acc1, 0,0,0);
  }
  const int n = nf*16 + (lane & 15);
  const float bv = bs[n];
  #pragma unroll
  for (int mi = 0; mi < 2; ++mi){
    f32x4 a = mi ? acc1 : acc0;
    #pragma unroll
    for (int r = 0; r < 4; ++r){
      const int m = mblk + mi*16 + (lane >> 4)*4 + r;
      float v = a[r] + bv;
      if (ACT == 1) v = leakyf(v);
      const size_t o = ob + (size_t)m*N + n;
      if (OUTM == 0){
        unsigned short h = f2bf(v);
        OutH[o] = h; OutL[o] = f2bf(v - bf2f(h));
      } else {
        OutF[o] = v;
      }
    }
  }
}

// ---------------- 2x2 stride-1 maxpool (NCHW) ----------------
template<int C,int IH,int IW>
__global__ __launch_bounds__(256) void pool_k(const float* __restrict__ in,
                                              float* __restrict__ out){
  constexpr int OH = IH - 1, OW = IW - 1;
  int idx = blockIdx.x * 256 + threadIdx.x;
  if (idx >= BATCH * C * OH * OW) return;
  int ow = idx % OW; int t = idx / OW;
  int oh = t % OH;   t /= OH;
  const float* p = in + ((size_t)t * IH + oh) * IW + ow;
  out[idx] = fmaxf(fmaxf(p[0], p[1]), fmaxf(p[IW], p[IW + 1]));
}

// ------- pool2: NHWC fp32 [B,28,28,32] -> padded NHWC bf16 hi/lo [B,29,29,32]
__global__ __launch_bounds__(256) void pool2n_k(const float* __restrict__ in,
    unsigned short* __restrict__ hi, unsigned short* __restrict__ lo){
  int idx = blockIdx.x*256 + threadIdx.x;
  if (idx >= BATCH*27*27*32) return;
  int ic = idx & 31; int p = idx >> 5;
  int ow = p % 27; int t = p / 27; int oh = t % 27; int n = t / 27;
  const float* b = in + (((size_t)n*28 + oh)*28 + ow)*32 + ic;
  float v = fmaxf(fmaxf(b[0], b[32]), fmaxf(b[28*32], b[29*32]));
  size_t o = (((size_t)n*29 + oh+1)*29 + ow+1)*32 + ic;
  unsigned short h = f2bf(v);
  hi[o] = h; lo[o] = f2bf(v - bf2f(h));
}

// ---------------- scout gate (NHWC input [B,28,28,32]) ----------------
__global__ __launch_bounds__(256) void gate_k(const float* __restrict__ s2,
                                              const float* __restrict__ cw,
                                              const float* __restrict__ cb,
                                              float* __restrict__ comb){
  int n = blockIdx.x;
  int tid = threadIdx.x;
  int c = tid & 31;
  int sub = tid >> 5;
  const float* p = s2 + (size_t)n * 784 * 32 + c;
  float s = 0.f;
  for (int i = sub * 98; i < sub * 98 + 98; ++i) s += p[(size_t)i * 32];
  __shared__ float red[32][8];
  red[c][sub] = s;
  __syncthreads();
  if (tid < 32){
    float tot = 0.f;
    #pragma unroll
    for (int k = 0; k < 8; ++k) tot += red[tid][k];
    red[tid][0] = tot / 784.f;
  }
  __syncthreads();
  if (tid == 0){
    float lg[3];
    for (int e = 0; e < 3; ++e){
      float a = cb[e];
      for (int c2 = 0; c2 < 32; ++c2) a += red[c2][0] * cw[e * 32 + c2];
      lg[e] = a;
    }
    float m = fmaxf(lg[0], fmaxf(lg[1], lg[2]));
    float ex[3], sum = 0.f;
    for (int e = 0; e < 3; ++e){ ex[e] = expf(lg[e] - m); sum += ex[e]; }
    float pr[3];
    for (int e = 0; e < 3; ++e) pr[e] = ex[e] / sum;
    int i1 = 0;
    if (pr[1] > pr[0]) i1 = 1;
    if (pr[2] > pr[i1]) i1 = 2;
    int i2 = -1;
    for (int e = 0; e < 3; ++e){
      if (e == i1) continue;
      if (i2 < 0 || pr[e] > pr[i2]) i2 = e;
    }
    float s12 = pr[i1] + pr[i2] + 1e-6f;
    float cmb[3] = {0.f, 0.f, 0.f};
    cmb[i1] = pr[i1] / s12;
    cmb[i2] = pr[i2] / s12;
    comb[n * 3 + 0] = cmb[0];
    comb[n * 3 + 1] = cmb[1];
    comb[n * 3 + 2] = cmb[2];
  }
}

// ------ fused maxpool2s1(27->26) + adaptive avg(26->3), NHWC input ----------
__global__ __launch_bounds__(256) void papooln_k(const float* __restrict__ in,
                                                 float* __restrict__ flat){
  int idx = blockIdx.x * 256 + threadIdx.x;
  if (idx >= BATCH * 128 * 9) return;
  int j = idx % 3; int t = idx / 3;
  int i = t % 3;   t /= 3;
  int c = t % 128; int n = t / 128;
  int hs = (i * 26) / 3, he = ((i + 1) * 26 + 2) / 3;
  int ws = (j * 26) / 3, we = ((j + 1) * 26 + 2) / 3;
  const float* p = in + (size_t)n * 729 * 128 + c;
  float s = 0.f;
  for (int r = hs; r < he; ++r)
    for (int cc = ws; cc < we; ++cc){
      const float* q0 = p + (r * 27 + cc) * 128;
      const float* q1 = q0 + 27 * 128;
      float m = fmaxf(fmaxf(q0[0], q0[128]), fmaxf(q1[0], q1[128]));
      s += m;
    }
  flat[(size_t)n * 1152 + c * 9 + i * 3 + j] = s / (float)((he - hs) * (we - ws));
}

// ---------------- final gated combine ----------------
__global__ __launch_bounds__(256) void comb_k(const float* __restrict__ h3,
                                              const float* __restrict__ comb,
                                              float* __restrict__ out){
  int idx = blockIdx.x * 256 + threadIdx.x;
  if (idx >= BATCH * 512) return;
  int o = idx % 512, b = idx / 512;
  float s = 0.f;
  #pragma unroll
  for (int e = 0; e < 3; ++e)
    s += comb[b * 3 + e] * h3[((size_t)e * BATCH + b) * 512 + o];
  out[idx] = s;
}

// ============================================================================
extern "C" void kernel_launch(void* const* d_in, const int* in_sizes, int n_in,
                              void* d_out, int out_size, void* d_ws, size_t ws_size,
                              hipStream_t stream){
  const float* x    = (const float*)d_in[0];
  const float* tw1  = (const float*)d_in[1];  const float* tb1 = (const float*)d_in[2];
  const float* tw2  = (const float*)d_in[3];  const float* tb2 = (const float*)d_in[4];
  const float* tw3  = (const float*)d_in[5];  const float* tb3 = (const float*)d_in[6];
  const float* tw4  = (const float*)d_in[7];  const float* tb4 = (const float*)d_in[8];
  const float* sw1  = (const float*)d_in[9];  const float* sb1 = (const float*)d_in[10];
  const float* bn1g = (const float*)d_in[11]; const float* bn1b = (const float*)d_in[12];
  const float* bn1m = (const float*)d_in[13]; const float* bn1v = (const float*)d_in[14];
  const float* sw2  = (const float*)d_in[15]; const float* sb2 = (const float*)d_in[16];
  const float* bn2g = (const float*)d_in[17]; const float* bn2b = (const float*)d_in[18];
  const float* bn2m = (const float*)d_in[19]; const float* bn2v = (const float*)d_in[20];
  const float* cw   = (const float*)d_in[21]; const float* cb  = (const float*)d_in[22];
  const float* ew1  = (const float*)d_in[23]; const float* eb1 = (const float*)d_in[24];
  const float* ew2  = (const float*)d_in[25]; const float* eb2 = (const float*)d_in[26];
  const float* ew3  = (const float*)d_in[27]; const float* eb3 = (const float*)d_in[28];
  float* out = (float*)d_out;

  // ---- workspace layout (floats), ~157 MB ----
  float* ws = (float*)d_ws;
  size_t off = 0;
  float* comb   = ws + off; off += 768;
  float* flat   = ws + off; off += (size_t)BATCH * 1152;
  float* h3     = ws + off; off += (size_t)BATCH * 3 * 512;
  unsigned short* wpk3h = (unsigned short*)(ws + off); off += 9216;
  unsigned short* wpk3l = (unsigned short*)(ws + off); off += 9216;
  unsigned short* wpk4h = (unsigned short*)(ws + off); off += 36864;
  unsigned short* wpk4l = (unsigned short*)(ws + off); off += 36864;
  unsigned short* wp2h  = (unsigned short*)(ws + off); off += 7680;
  unsigned short* wp2l  = (unsigned short*)(ws + off); off += 7680;
  unsigned short* wps2h = (unsigned short*)(ws + off); off += 3072;
  unsigned short* wps2l = (unsigned short*)(ws + off); off += 3072;
  _Float16* wpf = (_Float16*)(ws + off); off += 3072;   // 6144 fp16
  off += 16;                                                      // guard pad
  float* bufA   = ws + off; off += 13778944;
  off += 16;                                                      // guard pad
  float* bufB   = ws + off; off += 23887872;
  off += 16;
  (void)ws_size; (void)in_sizes; (void)n_in; (void)out_size;

  // phase aliases (lifetimes disjoint, single-stream ordered)
  float* s1out = bufA;                       // [B,16,56,56] NCHW
  float* c1out = bufB;                       // [B,16,56,56] NCHW
  float* s2out = bufB + 16000000;            // [B,28,28,32] NHWC
  float* p1out = bufA;                       // [B,16,55,55] NCHW
  float* c2out = bufB;                       // [B,28,28,32] NHWC
  unsigned short* P2h = (unsigned short*)(bufB + 8000000);
  unsigned short* P2l = P2h + (size_t)6889472;
  unsigned short* C3h = (unsigned short*)bufA;
  unsigned short* C3l = C3h + (size_t)13778944;
  float* c4out = bufB;                       // [B,27,27,128] NHWC

  // head-phase aliases in bufB (valid after papooln_k)
  unsigned short* ub = (unsigned short*)bufB;
  size_t uo = 0;
  unsigned short* ewp1h = ub + uo; uo += 3538944;
  unsigned short* ewp1l = ub + uo; uo += 3538944;
  unsigned short* ewp2h = ub + uo; uo += 1572864;
  unsigned short* ewp2l = ub + uo; uo += 1572864;
  unsigned short* ewp3h = ub + uo; uo += 786432;
  unsigned short* ewp3l = ub + uo; uo += 786432;
  unsigned short* fh    = ub + uo; uo += 294912;
  unsigned short* fl    = ub + uo; uo += 294912;
  unsigned short* h1h   = ub + uo; uo += 786432;
  unsigned short* h1l   = ub + uo; uo += 786432;
  unsigned short* h2h   = ub + uo; uo += 393216;
  unsigned short* h2l   = ub + uo; uo += 393216;

  dim3 blk(256);

  // ---- weight prep ----
  wpack_k<32,64>  <<<dim3(72),  blk, 0, stream>>>(tw3, wpk3h, wpk3l);
  wpack_k<64,128> <<<dim3(288), blk, 0, stream>>>(tw4, wpk4h, wpk4l);
  wpackS_k<32,5><<<dim3(60), blk, 0, stream>>>(tw2, wp2h, wp2l);
  wpackS_k<32,3><<<dim3(24), blk, 0, stream>>>(sw2, wps2h, wps2l);
  wpackF_k<<<dim3(24), blk, 0, stream>>>(sw1, tw1, wpf);

  // ---- fused scout1 + conv1 (space-to-depth MFMA fp16, one pass over x) ----
  fusedM_k<<<dim3(BATCH*28), blk, 0, stream>>>(
      x, wpf, sb1, tb1, bn1g, bn1b, bn1m, bn1v, s1out, c1out);

  // ---- scout2 (MFMA strided) + gate ----
  convS_k<32,3,1,56,56,1><<<dim3(BATCH*28), blk, 0, stream>>>(
      s1out, wps2h, wps2l, sb2, bn2g, bn2b, bn2m, bn2v, s2out);
  gate_k<<<dim3(256), blk, 0, stream>>>(s2out, cw, cb, comb);

  // ---- pool1 -> conv2 (MFMA strided) ----
  pool_k<16,56,56><<<dim3(48400), blk, 0, stream>>>(c1out, p1out);
  convS_k<32,5,2,55,55,0><<<dim3(BATCH*28), blk, 0, stream>>>(
      p1out, wp2h, wp2l, tb2, nullptr, nullptr, nullptr, nullptr, c2out);

  // ---- pool2 -> padded NHWC bf16 hi/lo ----
  hipMemsetAsync(bufB + 8000000, 0, (size_t)2 * 6889472 * 2, stream);
  pool2n_k<<<dim3((BATCH*27*27*32 + 255)/256), blk, 0, stream>>>(c2out, P2h, P2l);

  // ---- conv3 (MFMA) -> padded NHWC bf16 hi/lo ----
  hipMemsetAsync(bufA, 0, (size_t)2 * 13778944 * 2, stream);
  convM_k<32,64,0><<<dim3(BATCH*14), blk, 0, stream>>>(
      P2h, P2l, wpk3h, wpk3l, tb3, C3h, C3l, nullptr);

  // ---- conv4 (MFMA) -> fp32 NHWC [B,27,27,128] ----
  convM_k<64,128,1><<<dim3(BATCH*14), blk, 0, stream>>>(
      C3h, C3l, wpk4h, wpk4l, tb4, nullptr, nullptr, c4out);

  papooln_k<<<dim3(1152), blk, 0, stream>>>(c4out, flat);

  // ---- MoE head: pack weights + split A, then 3 MFMA GEMMs ----
  wpackG_k<1152><<<dim3(4608,3), blk, 0, stream>>>(ew1, 1024, ewp1h, ewp1l);
  wpackG_k<1024><<<dim3(2048,3), blk, 0, stream>>>(ew2,  512, ewp2h, ewp2l);
  wpackG_k< 512><<<dim3(1024,3), blk, 0, stream>>>(ew3,  512, ewp3h, ewp3l);
  asplit_k<<<dim3(1152), blk, 0, stream>>>(flat, fh, fl, BATCH*1152);

  gemmM_k<1152,1,0><<<dim3(8,16,3), blk, 0, stream>>>(
      fh, fl, 0L, ewp1h, ewp1l, eb1, 1024, h1h, h1l, nullptr);
  gemmM_k<1024,1,0><<<dim3(8,8,3), blk, 0, stream>>>(
      h1h, h1l, 256L*1024, ewp2h, ewp2l, eb2, 512, h2h, h2l, nullptr);
  gemmM_k< 512,0,1><<<dim3(8,8,3), blk, 0, stream>>>(
      h2h, h2l, 256L*512, ewp3h, ewp3l, eb3, 512, nullptr, nullptr, h3);

  comb_k<<<dim3(512), blk, 0, stream>>>(h3, comb, out);
}

// Round 11
// 529.690 us; speedup vs baseline: 1.2511x; 1.1780x over previous
//
#include <hip/hip_runtime.h>

#define DEV static __device__ __forceinline__

constexpr int BATCH = 256;

DEV float leakyf(float x){ return x > 0.f ? x : 0.2f * x; }

typedef short bf16x8 __attribute__((ext_vector_type(8)));
typedef _Float16 f16x8 __attribute__((ext_vector_type(8)));
typedef float f32x4 __attribute__((ext_vector_type(4)));

DEV unsigned short f2bf(float v){
  union { float f; unsigned u; } x; x.f = v;
  unsigned r = x.u + 0x7fffu + ((x.u >> 16) & 1u);
  return (unsigned short)(r >> 16);
}
DEV float bf2f(unsigned short b){
  union { unsigned u; float f; } x; x.u = ((unsigned)b) << 16;
  return x.f;
}

// ------- pack OIHW conv weights into MFMA B-fragment order, bf16 hi/lo ------
template<int IC,int OC>
__global__ __launch_bounds__(256) void wpack_k(const float* __restrict__ w,
    unsigned short* __restrict__ hi, unsigned short* __restrict__ lo){
  constexpr int S = IC/32, F = OC/16;
  int i = blockIdx.x*256 + threadIdx.x;
  if (i >= 9*S*F*512) return;
  int j = i & 7, L = (i >> 3) & 63, rest = i >> 9;
  int f = rest % F; int q2 = rest / F; int s = q2 % S; int t = q2 / S;
  int oc = f*16 + (L & 15), ic = s*32 + (L >> 4)*8 + j;
  float v = w[((size_t)oc*IC + ic)*9 + t];
  unsigned short h = f2bf(v);
  hi[i] = h; lo[i] = f2bf(v - bf2f(h));
}

// ------- pack strided-conv weights (IC=16): kstep = (kh, kw-pair) -----------
template<int OC,int K>
__global__ __launch_bounds__(256) void wpackS_k(const float* __restrict__ w,
    unsigned short* __restrict__ hi, unsigned short* __restrict__ lo){
  constexpr int F = OC/16, KWP = (K+1)/2;
  int i = blockIdx.x*256 + threadIdx.x;
  if (i >= K*KWP*F*512) return;
  int j = i & 7, L = (i >> 3) & 63, rest = i >> 9;
  int f = rest % F, s = rest / F;
  int kh = s / KWP, kwp = s % KWP;
  int k = (L >> 4)*8 + j;
  int kw = 2*kwp + (k >> 4), ic = k & 15;
  int oc = f*16 + (L & 15);
  float v = (kw < K) ? w[((size_t)(oc*16 + ic)*K + kh)*K + kw] : 0.f;
  unsigned short h = f2bf(v);
  hi[i] = h; lo[i] = f2bf(v - bf2f(h));
}

// ------- pack scout1(k7) + conv1(k3) weights, space-to-depth, single fp16 ---
__global__ __launch_bounds__(256) void wpackF_k(const float* __restrict__ sw1,
    const float* __restrict__ tw1, _Float16* __restrict__ wp){
  int i = blockIdx.x*256 + threadIdx.x;
  if (i >= 6*2*512) return;
  int j = i & 7, L = (i >> 3) & 63, rest = i >> 9;
  int nf = rest & 1, s = rest >> 1;
  int k = s*32 + (L >> 4)*8 + j;
  int oc = L & 15;
  int t = k / 48, c = k % 48;
  int dr = (t >> 1) - 1, dc = (t & 1) - 1;
  int ic = c >> 4, pr = (c >> 2) & 3, pc = c & 3;
  float v = 0.f;
  if (nf == 0){
    int kh = 4*dr + pr + 3, kw = 4*dc + pc + 3;
    if (kh >= 0 && kh < 7 && kw >= 0 && kw < 7) v = sw1[((oc*3 + ic)*7 + kh)*7 + kw];
  } else {
    int kh = 4*dr + pr + 1, kw = 4*dc + pc + 1;
    if (kh >= 0 && kh < 3 && kw >= 0 && kw < 3) v = tw1[((oc*3 + ic)*3 + kh)*3 + kw];
  }
  wp[i] = (_Float16)v;
}

// ------- pack expert GEMM weights W[e][N][K] into frag order, bf16 hi/lo ----
template<int KTOT>
__global__ __launch_bounds__(256) void wpackG_k(const float* __restrict__ w, int N,
    unsigned short* __restrict__ hi, unsigned short* __restrict__ lo){
  const int NF = N >> 4, KT = KTOT >> 5;
  const int total = NF * KT * 512;
  const int e = blockIdx.y;
  w  += (size_t)e * N * KTOT;
  hi += (size_t)e * total; lo += (size_t)e * total;
  int i = blockIdx.x*256 + threadIdx.x;
  if (i >= total) return;
  int j = i & 7, L = (i >> 3) & 63, rest = i >> 9;
  int nf = rest % NF, t = rest / NF;
  int n = nf*16 + (L & 15), k = t*32 + (L >> 4)*8 + j;
  float v = w[(size_t)n*KTOT + k];
  unsigned short h = f2bf(v);
  hi[i] = h; lo[i] = f2bf(v - bf2f(h));
}

// ------- split fp32 array into bf16 hi/lo ----------------------------------
__global__ __launch_bounds__(256) void asplit_k(const float* __restrict__ in,
    unsigned short* __restrict__ hi, unsigned short* __restrict__ lo, int nelem){
  int i = blockIdx.x*256 + threadIdx.x;
  if (i >= nelem) return;
  float v = in[i];
  unsigned short h = f2bf(v);
  hi[i] = h; lo[i] = f2bf(v - bf2f(h));
}

// ---------- fused scout1+conv1, space-to-depth MFMA, SINGLE fp16 ------------
__global__ __launch_bounds__(256) void fusedM_k(
    const float* __restrict__ x,
    const _Float16* __restrict__ W,
    const float* __restrict__ sb, const float* __restrict__ cb_,
    const float* __restrict__ g, const float* __restrict__ bt,
    const float* __restrict__ mn, const float* __restrict__ vr,
    float* __restrict__ s1out, float* __restrict__ c1out){
  __shared__ __align__(16) _Float16 Ah[3*58*64];
  const int tid = threadIdx.x;
  const int n = blockIdx.x / 28, oh0 = (blockIdx.x % 28) * 2;

  { // zero LDS tile (covers OOB rows, border cols, pad channels)
    int4* a = (int4*)Ah;
    for (int i = tid; i < 1392; i += 256) a[i] = (int4){0,0,0,0};
  }
  __syncthreads();

  // stage 12 x-rows x 3 ic x 224 cols (coalesced float4), space-to-depth
  for (int i = tid; i < 2016; i += 256){
    int m = i % 56; int rc = i / 56;
    int ic = rc % 3, ridx = rc / 3;
    int ih = 4*oh0 - 4 + ridx;
    if (ih < 0 || ih >= 224) continue;
    float4 v = *(const float4*)(x + ((size_t)(n*3 + ic)*224 + ih)*224 + 4*m);
    int rr = ridx >> 2, pr = ridx & 3, cc = m + 1;
    int boff = (((rr*58 + cc) << 7) + ic*32 + pr*8) ^ ((cc & 7) << 4);
    _Float16 h4[4] = {(_Float16)v.x, (_Float16)v.y, (_Float16)v.z, (_Float16)v.w};
    *(unsigned long long*)((char*)Ah + boff) = *(unsigned long long*)h4;
  }
  __syncthreads();

  const int wid = tid >> 6, lane = tid & 63;
  const int kg8 = (lane >> 4) * 8;
  f32x4 acc[2][2];
  #pragma unroll
  for (int mi = 0; mi < 2; ++mi)
    #pragma unroll
    for (int nf = 0; nf < 2; ++nf) acc[mi][nf] = (f32x4){0.f,0.f,0.f,0.f};

  #pragma unroll
  for (int s = 0; s < 6; ++s){
    const int kk = s*32 + kg8;
    const int t = kk / 48, c0 = kk - t*48;
    const int ra = t >> 1, ca = t & 1;
    f16x8 ah[2];
    #pragma unroll
    for (int mi = 0; mi < 2; ++mi){
      const int m = 2*wid + mi;
      const int rowsel = m >> 2;
      const int ow = (m & 3)*16 + (lane & 15);
      const int owc = ow > 55 ? 55 : ow;
      const int col = owc + ca;
      const int bidx = ((((rowsel + ra)*58 + col) << 7) + c0*2) ^ ((col & 7) << 4);
      ah[mi] = *(const f16x8*)((const char*)Ah + bidx);
    }
    #pragma unroll
    for (int nf = 0; nf < 2; ++nf){
      const f16x8 bw = *(const f16x8*)(W + (s*2 + nf)*512 + lane*8);
      #pragma unroll
      for (int mi = 0; mi < 2; ++mi)
        acc[mi][nf] = __builtin_amdgcn_mfma_f32_16x16x32_f16(ah[mi], bw, acc[mi][nf], 0,0,0);
    }
  }

  const int oc = lane & 15;
  const float sbv = sb[oc];
  const float scv = g[oc] * __frsqrt_rn(vr[oc] + 1e-5f);
  const float mnv = mn[oc], btv = bt[oc], cbv = cb_[oc];
  #pragma unroll
  for (int mi = 0; mi < 2; ++mi){
    const int m = 2*wid + mi;
    const int row = oh0 + (m >> 2);
    const int owb = (m & 3)*16 + (lane >> 4)*4;
    #pragma unroll
    for (int r = 0; r < 4; ++r){
      const int ow = owb + r;
      if (ow >= 56) continue;
      float vs = acc[mi][0][r] + sbv;
      vs = fmaxf((vs - mnv)*scv + btv, 0.f);
      s1out[((size_t)(n*16 + oc)*56 + row)*56 + ow] = vs;
      c1out[((size_t)(n*16 + oc)*56 + row)*56 + ow] = leakyf(acc[mi][1][r] + cbv);
    }
  }
}

// ---------------- strided (S=2) MFMA conv, IC=16, out 28x28 NHWC fp32 -------
template<int OC,int K,int P,int IH,int IW,int ACT>
__global__ __launch_bounds__(256) void convS_k(
    const float* __restrict__ in,
    const unsigned short* __restrict__ Wh, const unsigned short* __restrict__ Wl,
    const float* __restrict__ bias,
    const float* __restrict__ bng, const float* __restrict__ bnb,
    const float* __restrict__ bnm, const float* __restrict__ bnv,
    float* __restrict__ outNHWC){
  constexpr int F = OC/16, KWP = (K+1)/2;
  __shared__ __align__(16) unsigned short Ah[K*60*16];
  __shared__ __align__(16) unsigned short Al[K*60*16];

  const int tid = threadIdx.x;
  const int n = blockIdx.x / 28, oh = blockIdx.x % 28;

  for (int i = tid; i < K*16*60; i += 256){
    int c = i % 60; int q = i / 60;
    int ic = q & 15, r = q >> 4;
    int ih = 2*oh - P + r, iw = c - P;
    float v = 0.f;
    if (ih >= 0 && ih < IH && iw >= 0 && iw < IW)
      v = in[((size_t)(n*16 + ic)*IH + ih)*IW + iw];
    unsigned short h = f2bf(v);
    unsigned short l = f2bf(v - bf2f(h));
    int byte = ((r*60 + c)*32 + ic*2) ^ (((c>>1)&7) << 4);
    *(unsigned short*)((char*)Ah + byte) = h;
    *(unsigned short*)((char*)Al + byte) = l;
  }
  __syncthreads();

  const int wid = tid >> 6, lane = tid & 63;
  const int fsel = wid & 1, mb = wid >> 1;
  const int ow_l = min(mb*16 + (lane & 15), 27);
  const int ic0b = ((lane >> 4) & 1) * 16;
  const int kwo  = (lane >> 4) >> 1;

  f32x4 acc = {0.f,0.f,0.f,0.f};
  #pragma unroll
  for (int kh = 0; kh < K; ++kh){
    #pragma unroll
    for (int kwp = 0; kwp < KWP; ++kwp){
      const int kw = 2*kwp + kwo;
      const int c = 2*ow_l + kw;
      int byte = ((kh*60 + c)*32 + ic0b) ^ (((c>>1)&7) << 4);
      bf16x8 ah = *(const bf16x8*)((const char*)Ah + byte);
      bf16x8 al = *(const bf16x8*)((const char*)Al + byte);
      const int s = kh*KWP + kwp;
      const int fb = (s*F + fsel)*512 + lane*8;
      bf16x8 bh = *(const bf16x8*)(Wh + fb);
      bf16x8 bl = *(const bf16x8*)(Wl + fb);
      acc = __builtin_amdgcn_mfma_f32_16x16x32_bf16(ah, bh, acc, 0,0,0);
      acc = __builtin_amdgcn_mfma_f32_16x16x32_bf16(ah, bl, acc, 0,0,0);
      acc = __builtin_amdgcn_mfma_f32_16x16x32_bf16(al, bh, acc, 0,0,0);
    }
  }

  const int oc = fsel*16 + (lane & 15);
  float bv = bias[oc], sc = 1.f, mm = 0.f, bb = 0.f;
  if (ACT == 1){
    sc = bng[oc] * __frsqrt_rn(bnv[oc] + 1e-5f);
    mm = bnm[oc]; bb = bnb[oc];
  }
  #pragma unroll
  for (int r = 0; r < 4; ++r){
    const int ow = mb*16 + (lane >> 4)*4 + r;
    if (ow >= 28) continue;
    float v = acc[r] + bv;
    if (ACT == 1) v = fmaxf((v - mm)*sc + bb, 0.f);
    else          v = leakyf(v);
    outNHWC[(((size_t)n*28 + oh)*28 + ow)*OC + oc] = v;
  }
}

// ---------------- MFMA split-bf16 3x3 s1 p1 conv on 27x27, padded NHWC ------
template<int IC,int OC,int OUTM>
__global__ __launch_bounds__(256) void convM_k(
    const unsigned short* __restrict__ Ahi_g, const unsigned short* __restrict__ Alo_g,
    const unsigned short* __restrict__ Whi, const unsigned short* __restrict__ Wlo,
    const float* __restrict__ bias,
    unsigned short* __restrict__ OutHi, unsigned short* __restrict__ OutLo,
    float* __restrict__ OutF)
{
  constexpr int S = IC/32, FTOT = OC/16, FW = FTOT/2;
  constexpr int ICB = IC*2, ICG = ICB/16;
  __shared__ __align__(16) char Ah[4*34*ICB];
  __shared__ __align__(16) char Al[4*34*ICB];

  const int tid = threadIdx.x;
  const int bx = blockIdx.x;
  const int n = bx / 14, pr = bx % 14;
  const int oh0 = pr * 2;

  const size_t gbase = ((size_t)n*29) * 29 * IC;
  for (int g = tid; g < 4*34*ICG; g += 256){
    int r = g / (34*ICG);
    int rem = g - r*(34*ICG);
    int c = rem / ICG, q = rem - c*ICG;
    int rp = oh0 + r;
    int4 vh = {0,0,0,0}, vl = {0,0,0,0};
    if (rp <= 28 && c < 29){
      size_t e = gbase + ((size_t)rp*29 + c)*IC + q*8;
      vh = *(const int4*)(Ahi_g + e);
      vl = *(const int4*)(Alo_g + e);
    }
    int off = (r*34 + c)*ICB + q*16;
    int swz = off ^ ((c & 7) << 4);
    *(int4*)(Ah + swz) = vh;
    *(int4*)(Al + swz) = vl;
  }
  __syncthreads();

  const int wid = tid >> 6, lane = tid & 63;
  const int rsel = wid & 1, ocq = wid >> 1;
  const int c0 = lane & 15, kg = (lane >> 4) * 16;
  const int colb0 = c0*ICB + kg, colb1 = (16 + c0)*ICB + kg;
  int msk[3];
  #pragma unroll
  for (int kw = 0; kw < 3; ++kw) msk[kw] = ((c0 + kw) & 7) << 4;

  f32x4 acc[2][FW];
  #pragma unroll
  for (int m = 0; m < 2; ++m)
    #pragma unroll
    for (int f = 0; f < FW; ++f) acc[m][f] = (f32x4){0.f,0.f,0.f,0.f};

  #pragma unroll
  for (int kh = 0; kh < 3; ++kh){
    #pragma unroll
    for (int kw = 0; kw < 3; ++kw){
      #pragma unroll
      for (int s = 0; s < S; ++s){
        const int fr0 = (((kh*3 + kw)*S + s)*FTOT + ocq*FW) * 512 + lane*8;
        bf16x8 bh[FW], bl[FW];
        #pragma unroll
        for (int f = 0; f < FW; ++f){
          bh[f] = *(const bf16x8*)(Whi + fr0 + f*512);
          bl[f] = *(const bf16x8*)(Wlo + fr0 + f*512);
        }
        const int base = ((rsel + kh)*34 + kw)*ICB + s*64;
        const int o0 = (base + colb0) ^ msk[kw];
        const int o1 = (base + colb1) ^ msk[kw];
        bf16x8 ah0 = *(const bf16x8*)(Ah + o0);
        bf16x8 al0 = *(const bf16x8*)(Al + o0);
        bf16x8 ah1 = *(const bf16x8*)(Ah + o1);
        bf16x8 al1 = *(const bf16x8*)(Al + o1);
        #pragma unroll
        for (int f = 0; f < FW; ++f){
          acc[0][f] = __builtin_amdgcn_mfma_f32_16x16x32_bf16(ah0, bh[f], acc[0][f], 0,0,0);
          acc[0][f] = __builtin_amdgcn_mfma_f32_16x16x32_bf16(ah0, bl[f], acc[0][f], 0,0,0);
          acc[0][f] = __builtin_amdgcn_mfma_f32_16x16x32_bf16(al0, bh[f], acc[0][f], 0,0,0);
          acc[1][f] = __builtin_amdgcn_mfma_f32_16x16x32_bf16(ah1, bh[f], acc[1][f], 0,0,0);
          acc[1][f] = __builtin_amdgcn_mfma_f32_16x16x32_bf16(ah1, bl[f], acc[1][f], 0,0,0);
          acc[1][f] = __builtin_amdgcn_mfma_f32_16x16x32_bf16(al1, bh[f], acc[1][f], 0,0,0);
        }
      }
    }
  }

  const int orow = oh0 + rsel;
  if (orow >= 27) return;
  #pragma unroll
  for (int f = 0; f < FW; ++f){
    const int oc = (ocq*FW + f)*16 + c0;
    const float bv = bias[oc];
    #pragma unroll
    for (int m = 0; m < 2; ++m){
      #pragma unroll
      for (int r = 0; r < 4; ++r){
        const int ow = m*16 + (lane >> 4)*4 + r;
        if (ow >= 27) continue;
        float v = leakyf(acc[m][f][r] + bv);
        if (OUTM == 0){
          size_t o = (((size_t)n*29 + orow+1)*29 + ow+1)*OC + oc;
          unsigned short h = f2bf(v);
          OutHi[o] = h;
          OutLo[o] = f2bf(v - bf2f(h));
        } else {
          OutF[(((size_t)n*27 + orow)*27 + ow)*OC + oc] = v;
        }
      }
    }
  }
}

// ---------------- split-bf16 MFMA GEMM for MoE head -------------------------
template<int KTOT,int ACT,int OUTM>
__global__ __launch_bounds__(256) void gemmM_k(
    const unsigned short* __restrict__ Ah, const unsigned short* __restrict__ Al,
    long strideA,
    const unsigned short* __restrict__ Wh, const unsigned short* __restrict__ Wl,
    const float* __restrict__ bias, int N,
    unsigned short* __restrict__ OutH, unsigned short* __restrict__ OutL,
    float* __restrict__ OutF){
  const int e = blockIdx.z;
  Ah += (size_t)e * strideA; Al += (size_t)e * strideA;
  const int NF = N >> 4, KT = KTOT >> 5;
  const size_t wb = (size_t)e * NF * KT * 512;
  Wh += wb; Wl += wb;
  const float* bs = bias + (size_t)e * N;
  const size_t ob = (size_t)e * 256 * N;

  const int tid = threadIdx.x, wid = tid >> 6, lane = tid & 63;
  const int mblk = blockIdx.x * 32;
  const int nf = blockIdx.y * 4 + wid;
  const int r0 = mblk + (lane & 15);
  const int kof = (lane >> 4) * 8;

  f32x4 acc0 = {0,0,0,0}, acc1 = {0,0,0,0};
  for (int t = 0; t < KT; ++t){
    const int k = t*32 + kof;
    bf16x8 ah0 = *(const bf16x8*)(Ah + (size_t)r0*KTOT + k);
    bf16x8 al0 = *(const bf16x8*)(Al + (size_t)r0*KTOT + k);
    bf16x8 ah1 = *(const bf16x8*)(Ah + (size_t)(r0+16)*KTOT + k);
    bf16x8 al1 = *(const bf16x8*)(Al + (size_t)(r0+16)*KTOT + k);
    const size_t fb = ((size_t)t*NF + nf)*512 + lane*8;
    bf16x8 bh = *(const bf16x8*)(Wh + fb);
    bf16x8 bl = *(const bf16x8*)(Wl + fb);
    acc0 = __builtin_amdgcn_mfma_f32_16x16x32_bf16(ah0, bh, acc0, 0,0,0);
    acc0 = __builtin_amdgcn_mfma_f32_16x16x32_bf16(ah0, bl, acc0, 0,0,0);
    acc0 = __builtin_amdgcn_mfma_f32_16x16x32_bf16(al0, bh, acc0, 0,0,0);
    acc1 = __builtin_amdgcn_mfma_f32_16x16x32_bf16(ah1, bh, acc1, 0,0,0);
    acc1 = __builtin_amdgcn_mfma_f32_16x16x32_bf16(ah1, bl, acc1, 0,0,0);
    acc1 = __builtin_amdgcn_mfma_f32_16x16x32_bf16(al1, bh, acc1, 0,0,0);
  }
  const int n = nf*16 + (lane & 15);
  const float bv = bs[n];
  #pragma unroll
  for (int mi = 0; mi < 2; ++mi){
    f32x4 a = mi ? acc1 : acc0;
    #pragma unroll
    for (int r = 0; r < 4; ++r){
      const int m = mblk + mi*16 + (lane >> 4)*4 + r;
      float v = a[r] + bv;
      if (ACT == 1) v = leakyf(v);
      const size_t o = ob + (size_t)m*N + n;
      if (OUTM == 0){
        unsigned short h = f2bf(v);
        OutH[o] = h; OutL[o] = f2bf(v - bf2f(h));
      } else {
        OutF[o] = v;
      }
    }
  }
}

// ---------------- 2x2 stride-1 maxpool (NCHW) ----------------
template<int C,int IH,int IW>
__global__ __launch_bounds__(256) void pool_k(const float* __restrict__ in,
                                              float* __restrict__ out){
  constexpr int OH = IH - 1, OW = IW - 1;
  int idx = blockIdx.x * 256 + threadIdx.x;
  if (idx >= BATCH * C * OH * OW) return;
  int ow = idx % OW; int t = idx / OW;
  int oh = t % OH;   t /= OH;
  const float* p = in + ((size_t)t * IH + oh) * IW + ow;
  out[idx] = fmaxf(fmaxf(p[0], p[1]), fmaxf(p[IW], p[IW + 1]));
}

// ------- pool2: NHWC fp32 [B,28,28,32] -> padded NHWC bf16 hi/lo [B,29,29,32]
__global__ __launch_bounds__(256) void pool2n_k(const float* __restrict__ in,
    unsigned short* __restrict__ hi, unsigned short* __restrict__ lo){
  int idx = blockIdx.x*256 + threadIdx.x;
  if (idx >= BATCH*27*27*32) return;
  int ic = idx & 31; int p = idx >> 5;
  int ow = p % 27; int t = p / 27; int oh = t % 27; int n = t / 27;
  const float* b = in + (((size_t)n*28 + oh)*28 + ow)*32 + ic;
  float v = fmaxf(fmaxf(b[0], b[32]), fmaxf(b[28*32], b[29*32]));
  size_t o = (((size_t)n*29 + oh+1)*29 + ow+1)*32 + ic;
  unsigned short h = f2bf(v);
  hi[o] = h; lo[o] = f2bf(v - bf2f(h));
}

// ---------------- scout gate (NHWC input [B,28,28,32]) ----------------
__global__ __launch_bounds__(256) void gate_k(const float* __restrict__ s2,
                                              const float* __restrict__ cw,
                                              const float* __restrict__ cb,
                                              float* __restrict__ comb){
  int n = blockIdx.x;
  int tid = threadIdx.x;
  int c = tid & 31;
  int sub = tid >> 5;
  const float* p = s2 + (size_t)n * 784 * 32 + c;
  float s = 0.f;
  for (int i = sub * 98; i < sub * 98 + 98; ++i) s += p[(size_t)i * 32];
  __shared__ float red[32][8];
  red[c][sub] = s;
  __syncthreads();
  if (tid < 32){
    float tot = 0.f;
    #pragma unroll
    for (int k = 0; k < 8; ++k) tot += red[tid][k];
    red[tid][0] = tot / 784.f;
  }
  __syncthreads();
  if (tid == 0){
    float lg[3];
    for (int e = 0; e < 3; ++e){
      float a = cb[e];
      for (int c2 = 0; c2 < 32; ++c2) a += red[c2][0] * cw[e * 32 + c2];
      lg[e] = a;
    }
    float m = fmaxf(lg[0], fmaxf(lg[1], lg[2]));
    float ex[3], sum = 0.f;
    for (int e = 0; e < 3; ++e){ ex[e] = expf(lg[e] - m); sum += ex[e]; }
    float pr[3];
    for (int e = 0; e < 3; ++e) pr[e] = ex[e] / sum;
    int i1 = 0;
    if (pr[1] > pr[0]) i1 = 1;
    if (pr[2] > pr[i1]) i1 = 2;
    int i2 = -1;
    for (int e = 0; e < 3; ++e){
      if (e == i1) continue;
      if (i2 < 0 || pr[e] > pr[i2]) i2 = e;
    }
    float s12 = pr[i1] + pr[i2] + 1e-6f;
    float cmb[3] = {0.f, 0.f, 0.f};
    cmb[i1] = pr[i1] / s12;
    cmb[i2] = pr[i2] / s12;
    comb[n * 3 + 0] = cmb[0];
    comb[n * 3 + 1] = cmb[1];
    comb[n * 3 + 2] = cmb[2];
  }
}

// ------ channel-parallel fused maxpool2s1(27->26) + adaptive avg(26->3) -----
// Block = one image; 256 thr = 2 row-halves x 128 channels. All channel lanes
// read consecutive floats -> coalesced; each pixel read exactly once.
// Overlapping torch-adaptive bands: [0,9) [8,18) [17,26).
__global__ __launch_bounds__(256) void papool2_k(const float* __restrict__ in,
                                                 float* __restrict__ flat){
  __shared__ float red[2][128][9];
  const int n = blockIdx.x;
  const int tid = threadIdx.x;
  const int h = tid >> 7, c = tid & 127;
  const float* p = in + (size_t)n * 729 * 128 + c;

  float sum[9];
  #pragma unroll
  for (int j = 0; j < 9; ++j) sum[j] = 0.f;

  float prev[27], cur[27];
  const int r0 = h * 13;                 // input rows r0 .. r0+13 (14 rows)
  #pragma unroll
  for (int rr = 0; rr < 14; ++rr){
    const int r = r0 + rr;
    #pragma unroll
    for (int cc = 0; cc < 27; ++cc)
      cur[cc] = p[(size_t)(r*27 + cc) * 128];
    if (rr > 0){
      const int pr = r - 1;              // pooled row index
      const bool b0 = (pr < 9), b1 = (pr >= 8) && (pr < 18), b2 = (pr >= 17);
      #pragma unroll
      for (int cc = 0; cc < 26; ++cc){
        float v = fmaxf(fmaxf(prev[cc], prev[cc+1]), fmaxf(cur[cc], cur[cc+1]));
        if (b0){
          if (cc < 9)             sum[0] += v;
          if (cc >= 8 && cc < 18) sum[1] += v;
          if (cc >= 17)           sum[2] += v;
        }
        if (b1){
          if (cc < 9)             sum[3] += v;
          if (cc >= 8 && cc < 18) sum[4] += v;
          if (cc >= 17)           sum[5] += v;
        }
        if (b2){
          if (cc < 9)             sum[6] += v;
          if (cc >= 8 && cc < 18) sum[7] += v;
          if (cc >= 17)           sum[8] += v;
        }
      }
    }
    #pragma unroll
    for (int cc = 0; cc < 27; ++cc) prev[cc] = cur[cc];
  }

  #pragma unroll
  for (int j = 0; j < 9; ++j) red[h][c][j] = sum[j];
  __syncthreads();

  if (tid < 128){
    const float rcp[9] = {1.f/81, 1.f/90, 1.f/81, 1.f/90, 1.f/100, 1.f/90,
                          1.f/81, 1.f/90, 1.f/81};
    float* o = flat + (size_t)n * 1152 + tid * 9;
    #pragma unroll
    for (int j = 0; j < 9; ++j)
      o[j] = (red[0][tid][j] + red[1][tid][j]) * rcp[j];
  }
}

// ---------------- final gated combine ----------------
__global__ __launch_bounds__(256) void comb_k(const float* __restrict__ h3,
                                              const float* __restrict__ comb,
                                              float* __restrict__ out){
  int idx = blockIdx.x * 256 + threadIdx.x;
  if (idx >= BATCH * 512) return;
  int o = idx % 512, b = idx / 512;
  float s = 0.f;
  #pragma unroll
  for (int e = 0; e < 3; ++e)
    s += comb[b * 3 + e] * h3[((size_t)e * BATCH + b) * 512 + o];
  out[idx] = s;
}

// ============================================================================
extern "C" void kernel_launch(void* const* d_in, const int* in_sizes, int n_in,
                              void* d_out, int out_size, void* d_ws, size_t ws_size,
                              hipStream_t stream){
  const float* x    = (const float*)d_in[0];
  const float* tw1  = (const float*)d_in[1];  const float* tb1 = (const float*)d_in[2];
  const float* tw2  = (const float*)d_in[3];  const float* tb2 = (const float*)d_in[4];
  const float* tw3  = (const float*)d_in[5];  const float* tb3 = (const float*)d_in[6];
  const float* tw4  = (const float*)d_in[7];  const float* tb4 = (const float*)d_in[8];
  const float* sw1  = (const float*)d_in[9];  const float* sb1 = (const float*)d_in[10];
  const float* bn1g = (const float*)d_in[11]; const float* bn1b = (const float*)d_in[12];
  const float* bn1m = (const float*)d_in[13]; const float* bn1v = (const float*)d_in[14];
  const float* sw2  = (const float*)d_in[15]; const float* sb2 = (const float*)d_in[16];
  const float* bn2g = (const float*)d_in[17]; const float* bn2b = (const float*)d_in[18];
  const float* bn2m = (const float*)d_in[19]; const float* bn2v = (const float*)d_in[20];
  const float* cw   = (const float*)d_in[21]; const float* cb  = (const float*)d_in[22];
  const float* ew1  = (const float*)d_in[23]; const float* eb1 = (const float*)d_in[24];
  const float* ew2  = (const float*)d_in[25]; const float* eb2 = (const float*)d_in[26];
  const float* ew3  = (const float*)d_in[27]; const float* eb3 = (const float*)d_in[28];
  float* out = (float*)d_out;

  // ---- workspace layout (floats), ~157 MB ----
  float* ws = (float*)d_ws;
  size_t off = 0;
  float* comb   = ws + off; off += 768;
  float* flat   = ws + off; off += (size_t)BATCH * 1152;
  float* h3     = ws + off; off += (size_t)BATCH * 3 * 512;
  unsigned short* wpk3h = (unsigned short*)(ws + off); off += 9216;
  unsigned short* wpk3l = (unsigned short*)(ws + off); off += 9216;
  unsigned short* wpk4h = (unsigned short*)(ws + off); off += 36864;
  unsigned short* wpk4l = (unsigned short*)(ws + off); off += 36864;
  unsigned short* wp2h  = (unsigned short*)(ws + off); off += 7680;
  unsigned short* wp2l  = (unsigned short*)(ws + off); off += 7680;
  unsigned short* wps2h = (unsigned short*)(ws + off); off += 3072;
  unsigned short* wps2l = (unsigned short*)(ws + off); off += 3072;
  _Float16* wpf = (_Float16*)(ws + off); off += 3072;   // 6144 fp16
  off += 16;                                                      // guard pad
  float* bufA   = ws + off; off += 13778944;
  off += 16;                                                      // guard pad
  float* bufB   = ws + off; off += 23887872;
  off += 16;
  (void)ws_size; (void)in_sizes; (void)n_in; (void)out_size;

  // phase aliases (lifetimes disjoint, single-stream ordered)
  float* s1out = bufA;                       // [B,16,56,56] NCHW
  float* c1out = bufB;                       // [B,16,56,56] NCHW
  float* s2out = bufB + 16000000;            // [B,28,28,32] NHWC
  float* p1out = bufA;                       // [B,16,55,55] NCHW
  float* c2out = bufB;                       // [B,28,28,32] NHWC
  unsigned short* P2h = (unsigned short*)(bufB + 8000000);
  unsigned short* P2l = P2h + (size_t)6889472;
  unsigned short* C3h = (unsigned short*)bufA;
  unsigned short* C3l = C3h + (size_t)13778944;
  float* c4out = bufB;                       // [B,27,27,128] NHWC

  // head-phase aliases in bufB (valid after papool2_k)
  unsigned short* ub = (unsigned short*)bufB;
  size_t uo = 0;
  unsigned short* ewp1h = ub + uo; uo += 3538944;
  unsigned short* ewp1l = ub + uo; uo += 3538944;
  unsigned short* ewp2h = ub + uo; uo += 1572864;
  unsigned short* ewp2l = ub + uo; uo += 1572864;
  unsigned short* ewp3h = ub + uo; uo += 786432;
  unsigned short* ewp3l = ub + uo; uo += 786432;
  unsigned short* fh    = ub + uo; uo += 294912;
  unsigned short* fl    = ub + uo; uo += 294912;
  unsigned short* h1h   = ub + uo; uo += 786432;
  unsigned short* h1l   = ub + uo; uo += 786432;
  unsigned short* h2h   = ub + uo; uo += 393216;
  unsigned short* h2l   = ub + uo; uo += 393216;

  dim3 blk(256);

  // ---- weight prep ----
  wpack_k<32,64>  <<<dim3(72),  blk, 0, stream>>>(tw3, wpk3h, wpk3l);
  wpack_k<64,128> <<<dim3(288), blk, 0, stream>>>(tw4, wpk4h, wpk4l);
  wpackS_k<32,5><<<dim3(60), blk, 0, stream>>>(tw2, wp2h, wp2l);
  wpackS_k<32,3><<<dim3(24), blk, 0, stream>>>(sw2, wps2h, wps2l);
  wpackF_k<<<dim3(24), blk, 0, stream>>>(sw1, tw1, wpf);

  // ---- fused scout1 + conv1 (space-to-depth MFMA fp16, one pass over x) ----
  fusedM_k<<<dim3(BATCH*28), blk, 0, stream>>>(
      x, wpf, sb1, tb1, bn1g, bn1b, bn1m, bn1v, s1out, c1out);

  // ---- scout2 (MFMA strided) + gate ----
  convS_k<32,3,1,56,56,1><<<dim3(BATCH*28), blk, 0, stream>>>(
      s1out, wps2h, wps2l, sb2, bn2g, bn2b, bn2m, bn2v, s2out);
  gate_k<<<dim3(256), blk, 0, stream>>>(s2out, cw, cb, comb);

  // ---- pool1 -> conv2 (MFMA strided) ----
  pool_k<16,56,56><<<dim3(48400), blk, 0, stream>>>(c1out, p1out);
  convS_k<32,5,2,55,55,0><<<dim3(BATCH*28), blk, 0, stream>>>(
      p1out, wp2h, wp2l, tb2, nullptr, nullptr, nullptr, nullptr, c2out);

  // ---- pool2 -> padded NHWC bf16 hi/lo ----
  hipMemsetAsync(bufB + 8000000, 0, (size_t)2 * 6889472 * 2, stream);
  pool2n_k<<<dim3((BATCH*27*27*32 + 255)/256), blk, 0, stream>>>(c2out, P2h, P2l);

  // ---- conv3 (MFMA) -> padded NHWC bf16 hi/lo ----
  hipMemsetAsync(bufA, 0, (size_t)2 * 13778944 * 2, stream);
  convM_k<32,64,0><<<dim3(BATCH*14), blk, 0, stream>>>(
      P2h, P2l, wpk3h, wpk3l, tb3, C3h, C3l, nullptr);

  // ---- conv4 (MFMA) -> fp32 NHWC [B,27,27,128] ----
  convM_k<64,128,1><<<dim3(BATCH*14), blk, 0, stream>>>(
      C3h, C3l, wpk4h, wpk4l, tb4, nullptr, nullptr, c4out);

  papool2_k<<<dim3(BATCH), blk, 0, stream>>>(c4out, flat);

  // ---- MoE head: pack weights + split A, then 3 MFMA GEMMs ----
  wpackG_k<1152><<<dim3(4608,3), blk, 0, stream>>>(ew1, 1024, ewp1h, ewp1l);
  wpackG_k<1024><<<dim3(2048,3), blk, 0, stream>>>(ew2,  512, ewp2h, ewp2l);
  wpackG_k< 512><<<dim3(1024,3), blk, 0, stream>>>(ew3,  512, ewp3h, ewp3l);
  asplit_k<<<dim3(1152), blk, 0, stream>>>(flat, fh, fl, BATCH*1152);

  gemmM_k<1152,1,0><<<dim3(8,16,3), blk, 0, stream>>>(
      fh, fl, 0L, ewp1h, ewp1l, eb1, 1024, h1h, h1l, nullptr);
  gemmM_k<1024,1,0><<<dim3(8,8,3), blk, 0, stream>>>(
      h1h, h1l, 256L*1024, ewp2h, ewp2l, eb2, 512, h2h, h2l, nullptr);
  gemmM_k< 512,0,1><<<dim3(8,8,3), blk, 0, stream>>>(
      h2h, h2l, 256L*512, ewp3h, ewp3l, eb3, 512, nullptr, nullptr, h3);

  comb_k<<<dim3(512), blk, 0, stream>>>(h3, comb, out);
}

// Round 12
// 434.507 us; speedup vs baseline: 1.5252x; 1.2191x over previous
//
#include <hip/hip_runtime.h>

#define DEV static __device__ __forceinline__

constexpr int BATCH = 256;

DEV float leakyf(float x){ return x > 0.f ? x : 0.2f * x; }

typedef short bf16x8 __attribute__((ext_vector_type(8)));
typedef _Float16 f16x8 __attribute__((ext_vector_type(8)));
typedef float f32x4 __attribute__((ext_vector_type(4)));

DEV unsigned short f2bf(float v){
  union { float f; unsigned u; } x; x.f = v;
  unsigned r = x.u + 0x7fffu + ((x.u >> 16) & 1u);
  return (unsigned short)(r >> 16);
}
DEV float bf2f(unsigned short b){
  union { unsigned u; float f; } x; x.u = ((unsigned)b) << 16;
  return x.f;
}

// ------- pack OIHW conv weights into MFMA B-fragment order, single fp16 -----
template<int IC,int OC>
__global__ __launch_bounds__(256) void wpackM_k(const float* __restrict__ w,
    _Float16* __restrict__ wp){
  constexpr int S = IC/32, F = OC/16;
  int i = blockIdx.x*256 + threadIdx.x;
  if (i >= 9*S*F*512) return;
  int j = i & 7, L = (i >> 3) & 63, rest = i >> 9;
  int f = rest % F; int q2 = rest / F; int s = q2 % S; int t = q2 / S;
  int oc = f*16 + (L & 15), ic = s*32 + (L >> 4)*8 + j;
  wp[i] = (_Float16)w[((size_t)oc*IC + ic)*9 + t];
}

// ------- pack strided-conv weights (IC=16), single fp16 ---------------------
template<int OC,int K>
__global__ __launch_bounds__(256) void wpackS_k(const float* __restrict__ w,
    _Float16* __restrict__ wp){
  constexpr int F = OC/16, KWP = (K+1)/2;
  int i = blockIdx.x*256 + threadIdx.x;
  if (i >= K*KWP*F*512) return;
  int j = i & 7, L = (i >> 3) & 63, rest = i >> 9;
  int f = rest % F, s = rest / F;
  int kh = s / KWP, kwp = s % KWP;
  int k = (L >> 4)*8 + j;
  int kw = 2*kwp + (k >> 4), ic = k & 15;
  int oc = f*16 + (L & 15);
  float v = (kw < K) ? w[((size_t)(oc*16 + ic)*K + kh)*K + kw] : 0.f;
  wp[i] = (_Float16)v;
}

// ------- pack scout1(k7) + conv1(k3) weights, space-to-depth, single fp16 ---
__global__ __launch_bounds__(256) void wpackF_k(const float* __restrict__ sw1,
    const float* __restrict__ tw1, _Float16* __restrict__ wp){
  int i = blockIdx.x*256 + threadIdx.x;
  if (i >= 6*2*512) return;
  int j = i & 7, L = (i >> 3) & 63, rest = i >> 9;
  int nf = rest & 1, s = rest >> 1;
  int k = s*32 + (L >> 4)*8 + j;
  int oc = L & 15;
  int t = k / 48, c = k % 48;
  int dr = (t >> 1) - 1, dc = (t & 1) - 1;
  int ic = c >> 4, pr = (c >> 2) & 3, pc = c & 3;
  float v = 0.f;
  if (nf == 0){
    int kh = 4*dr + pr + 3, kw = 4*dc + pc + 3;
    if (kh >= 0 && kh < 7 && kw >= 0 && kw < 7) v = sw1[((oc*3 + ic)*7 + kh)*7 + kw];
  } else {
    int kh = 4*dr + pr + 1, kw = 4*dc + pc + 1;
    if (kh >= 0 && kh < 3 && kw >= 0 && kw < 3) v = tw1[((oc*3 + ic)*3 + kh)*3 + kw];
  }
  wp[i] = (_Float16)v;
}

// ------- pack expert GEMM weights W[e][N][K] into frag order, bf16 hi/lo ----
template<int KTOT>
__global__ __launch_bounds__(256) void wpackG_k(const float* __restrict__ w, int N,
    unsigned short* __restrict__ hi, unsigned short* __restrict__ lo){
  const int NF = N >> 4, KT = KTOT >> 5;
  const int total = NF * KT * 512;
  const int e = blockIdx.y;
  w  += (size_t)e * N * KTOT;
  hi += (size_t)e * total; lo += (size_t)e * total;
  int i = blockIdx.x*256 + threadIdx.x;
  if (i >= total) return;
  int j = i & 7, L = (i >> 3) & 63, rest = i >> 9;
  int nf = rest % NF, t = rest / NF;
  int n = nf*16 + (L & 15), k = t*32 + (L >> 4)*8 + j;
  float v = w[(size_t)n*KTOT + k];
  unsigned short h = f2bf(v);
  hi[i] = h; lo[i] = f2bf(v - bf2f(h));
}

// ------- split fp32 array into bf16 hi/lo ----------------------------------
__global__ __launch_bounds__(256) void asplit_k(const float* __restrict__ in,
    unsigned short* __restrict__ hi, unsigned short* __restrict__ lo, int nelem){
  int i = blockIdx.x*256 + threadIdx.x;
  if (i >= nelem) return;
  float v = in[i];
  unsigned short h = f2bf(v);
  hi[i] = h; lo[i] = f2bf(v - bf2f(h));
}

// ---------- fused scout1+conv1, space-to-depth MFMA, SINGLE fp16 ------------
__global__ __launch_bounds__(256) void fusedM_k(
    const float* __restrict__ x,
    const _Float16* __restrict__ W,
    const float* __restrict__ sb, const float* __restrict__ cb_,
    const float* __restrict__ g, const float* __restrict__ bt,
    const float* __restrict__ mn, const float* __restrict__ vr,
    float* __restrict__ s1out, float* __restrict__ c1out){
  __shared__ __align__(16) _Float16 Ah[3*58*64];
  const int tid = threadIdx.x;
  const int n = blockIdx.x / 28, oh0 = (blockIdx.x % 28) * 2;

  { // zero LDS tile
    int4* a = (int4*)Ah;
    for (int i = tid; i < 1392; i += 256) a[i] = (int4){0,0,0,0};
  }
  __syncthreads();

  for (int i = tid; i < 2016; i += 256){
    int m = i % 56; int rc = i / 56;
    int ic = rc % 3, ridx = rc / 3;
    int ih = 4*oh0 - 4 + ridx;
    if (ih < 0 || ih >= 224) continue;
    float4 v = *(const float4*)(x + ((size_t)(n*3 + ic)*224 + ih)*224 + 4*m);
    int rr = ridx >> 2, pr = ridx & 3, cc = m + 1;
    int boff = (((rr*58 + cc) << 7) + ic*32 + pr*8) ^ ((cc & 7) << 4);
    _Float16 h4[4] = {(_Float16)v.x, (_Float16)v.y, (_Float16)v.z, (_Float16)v.w};
    *(unsigned long long*)((char*)Ah + boff) = *(unsigned long long*)h4;
  }
  __syncthreads();

  const int wid = tid >> 6, lane = tid & 63;
  const int kg8 = (lane >> 4) * 8;
  f32x4 acc[2][2];
  #pragma unroll
  for (int mi = 0; mi < 2; ++mi)
    #pragma unroll
    for (int nf = 0; nf < 2; ++nf) acc[mi][nf] = (f32x4){0.f,0.f,0.f,0.f};

  #pragma unroll
  for (int s = 0; s < 6; ++s){
    const int kk = s*32 + kg8;
    const int t = kk / 48, c0 = kk - t*48;
    const int ra = t >> 1, ca = t & 1;
    f16x8 ah[2];
    #pragma unroll
    for (int mi = 0; mi < 2; ++mi){
      const int m = 2*wid + mi;
      const int rowsel = m >> 2;
      const int ow = (m & 3)*16 + (lane & 15);
      const int owc = ow > 55 ? 55 : ow;
      const int col = owc + ca;
      const int bidx = ((((rowsel + ra)*58 + col) << 7) + c0*2) ^ ((col & 7) << 4);
      ah[mi] = *(const f16x8*)((const char*)Ah + bidx);
    }
    #pragma unroll
    for (int nf = 0; nf < 2; ++nf){
      const f16x8 bw = *(const f16x8*)(W + (s*2 + nf)*512 + lane*8);
      #pragma unroll
      for (int mi = 0; mi < 2; ++mi)
        acc[mi][nf] = __builtin_amdgcn_mfma_f32_16x16x32_f16(ah[mi], bw, acc[mi][nf], 0,0,0);
    }
  }

  const int oc = lane & 15;
  const float sbv = sb[oc];
  const float scv = g[oc] * __frsqrt_rn(vr[oc] + 1e-5f);
  const float mnv = mn[oc], btv = bt[oc], cbv = cb_[oc];
  #pragma unroll
  for (int mi = 0; mi < 2; ++mi){
    const int m = 2*wid + mi;
    const int row = oh0 + (m >> 2);
    const int owb = (m & 3)*16 + (lane >> 4)*4;
    #pragma unroll
    for (int r = 0; r < 4; ++r){
      const int ow = owb + r;
      if (ow >= 56) continue;
      float vs = acc[mi][0][r] + sbv;
      vs = fmaxf((vs - mnv)*scv + btv, 0.f);
      s1out[((size_t)(n*16 + oc)*56 + row)*56 + ow] = vs;
      c1out[((size_t)(n*16 + oc)*56 + row)*56 + ow] = leakyf(acc[mi][1][r] + cbv);
    }
  }
}

// ---------------- strided (S=2) MFMA conv, IC=16, single fp16 ---------------
template<int OC,int K,int P,int IH,int IW,int ACT>
__global__ __launch_bounds__(256) void convS_k(
    const float* __restrict__ in,
    const _Float16* __restrict__ W,
    const float* __restrict__ bias,
    const float* __restrict__ bng, const float* __restrict__ bnb,
    const float* __restrict__ bnm, const float* __restrict__ bnv,
    float* __restrict__ outNHWC){
  constexpr int F = OC/16, KWP = (K+1)/2;
  __shared__ __align__(16) _Float16 A[K*60*16];

  const int tid = threadIdx.x;
  const int n = blockIdx.x / 28, oh = blockIdx.x % 28;

  for (int i = tid; i < K*16*60; i += 256){
    int c = i % 60; int q = i / 60;
    int ic = q & 15, r = q >> 4;
    int ih = 2*oh - P + r, iw = c - P;
    float v = 0.f;
    if (ih >= 0 && ih < IH && iw >= 0 && iw < IW)
      v = in[((size_t)(n*16 + ic)*IH + ih)*IW + iw];
    int byte = ((r*60 + c)*32 + ic*2) ^ (((c>>1)&7) << 4);
    *(_Float16*)((char*)A + byte) = (_Float16)v;
  }
  __syncthreads();

  const int wid = tid >> 6, lane = tid & 63;
  const int fsel = wid & 1, mb = wid >> 1;
  const int ow_l = min(mb*16 + (lane & 15), 27);
  const int ic0b = ((lane >> 4) & 1) * 16;
  const int kwo  = (lane >> 4) >> 1;

  f32x4 acc = {0.f,0.f,0.f,0.f};
  #pragma unroll
  for (int kh = 0; kh < K; ++kh){
    #pragma unroll
    for (int kwp = 0; kwp < KWP; ++kwp){
      const int kw = 2*kwp + kwo;
      const int c = 2*ow_l + kw;
      int byte = ((kh*60 + c)*32 + ic0b) ^ (((c>>1)&7) << 4);
      f16x8 a = *(const f16x8*)((const char*)A + byte);
      const int s = kh*KWP + kwp;
      const f16x8 b = *(const f16x8*)(W + (s*F + fsel)*512 + lane*8);
      acc = __builtin_amdgcn_mfma_f32_16x16x32_f16(a, b, acc, 0,0,0);
    }
  }

  const int oc = fsel*16 + (lane & 15);
  float bv = bias[oc], sc = 1.f, mm = 0.f, bb = 0.f;
  if (ACT == 1){
    sc = bng[oc] * __frsqrt_rn(bnv[oc] + 1e-5f);
    mm = bnm[oc]; bb = bnb[oc];
  }
  #pragma unroll
  for (int r = 0; r < 4; ++r){
    const int ow = mb*16 + (lane >> 4)*4 + r;
    if (ow >= 28) continue;
    float v = acc[r] + bv;
    if (ACT == 1) v = fmaxf((v - mm)*sc + bb, 0.f);
    else          v = leakyf(v);
    outNHWC[(((size_t)n*28 + oh)*28 + ow)*OC + oc] = v;
  }
}

// ---------------- MFMA single-fp16 3x3 s1 p1 conv on 27x27, padded NHWC -----
// OUTM 0: write leaky fp16 padded NHWC ; OUTM 1: write leaky fp32 NHWC
template<int IC,int OC,int OUTM>
__global__ __launch_bounds__(256) void convM_k(
    const _Float16* __restrict__ Ag,
    const _Float16* __restrict__ W,
    const float* __restrict__ bias,
    _Float16* __restrict__ OutHf, float* __restrict__ OutF)
{
  constexpr int S = IC/32, FTOT = OC/16, FW = FTOT/2;
  constexpr int ICB = IC*2, ICG = ICB/16;   // bytes per col, 16B chunks per col
  __shared__ __align__(16) char A[4*34*ICB];

  const int tid = threadIdx.x;
  const int bx = blockIdx.x;
  const int n = bx / 14, pr = bx % 14;
  const int oh0 = pr * 2;

  const size_t gbase = ((size_t)n*29) * 29 * IC;
  for (int g = tid; g < 4*34*ICG; g += 256){
    int r = g / (34*ICG);
    int rem = g - r*(34*ICG);
    int c = rem / ICG, q = rem - c*ICG;
    int rp = oh0 + r;
    int4 v = {0,0,0,0};
    if (rp <= 28 && c < 29){
      size_t e = gbase + ((size_t)rp*29 + c)*IC + q*8;
      v = *(const int4*)(Ag + e);
    }
    int off = (r*34 + c)*ICB + q*16;
    int swz = off ^ ((c & 7) << 4);
    *(int4*)(A + swz) = v;
  }
  __syncthreads();

  const int wid = tid >> 6, lane = tid & 63;
  const int rsel = wid & 1, ocq = wid >> 1;
  const int c0 = lane & 15, kg = (lane >> 4) * 16;
  const int colb0 = c0*ICB + kg, colb1 = (16 + c0)*ICB + kg;
  int msk[3];
  #pragma unroll
  for (int kw = 0; kw < 3; ++kw) msk[kw] = ((c0 + kw) & 7) << 4;

  f32x4 acc[2][FW];
  #pragma unroll
  for (int m = 0; m < 2; ++m)
    #pragma unroll
    for (int f = 0; f < FW; ++f) acc[m][f] = (f32x4){0.f,0.f,0.f,0.f};

  #pragma unroll
  for (int kh = 0; kh < 3; ++kh){
    #pragma unroll
    for (int kw = 0; kw < 3; ++kw){
      #pragma unroll
      for (int s = 0; s < S; ++s){
        const int fr0 = (((kh*3 + kw)*S + s)*FTOT + ocq*FW) * 512 + lane*8;
        f16x8 b[FW];
        #pragma unroll
        for (int f = 0; f < FW; ++f)
          b[f] = *(const f16x8*)(W + fr0 + f*512);
        const int base = ((rsel + kh)*34 + kw)*ICB + s*64;
        const int o0 = (base + colb0) ^ msk[kw];
        const int o1 = (base + colb1) ^ msk[kw];
        f16x8 a0 = *(const f16x8*)(A + o0);
        f16x8 a1 = *(const f16x8*)(A + o1);
        #pragma unroll
        for (int f = 0; f < FW; ++f){
          acc[0][f] = __builtin_amdgcn_mfma_f32_16x16x32_f16(a0, b[f], acc[0][f], 0,0,0);
          acc[1][f] = __builtin_amdgcn_mfma_f32_16x16x32_f16(a1, b[f], acc[1][f], 0,0,0);
        }
      }
    }
  }

  const int orow = oh0 + rsel;
  if (orow >= 27) return;
  #pragma unroll
  for (int f = 0; f < FW; ++f){
    const int oc = (ocq*FW + f)*16 + c0;
    const float bv = bias[oc];
    #pragma unroll
    for (int m = 0; m < 2; ++m){
      #pragma unroll
      for (int r = 0; r < 4; ++r){
        const int ow = m*16 + (lane >> 4)*4 + r;
        if (ow >= 27) continue;
        float v = leakyf(acc[m][f][r] + bv);
        if (OUTM == 0){
          size_t o = (((size_t)n*29 + orow+1)*29 + ow+1)*OC + oc;
          OutHf[o] = (_Float16)v;
        } else {
          OutF[(((size_t)n*27 + orow)*27 + ow)*OC + oc] = v;
        }
      }
    }
  }
}

// ---------------- split-bf16 MFMA GEMM for MoE head -------------------------
template<int KTOT,int ACT,int OUTM>
__global__ __launch_bounds__(256) void gemmM_k(
    const unsigned short* __restrict__ Ah, const unsigned short* __restrict__ Al,
    long strideA,
    const unsigned short* __restrict__ Wh, const unsigned short* __restrict__ Wl,
    const float* __restrict__ bias, int N,
    unsigned short* __restrict__ OutH, unsigned short* __restrict__ OutL,
    float* __restrict__ OutF){
  const int e = blockIdx.z;
  Ah += (size_t)e * strideA; Al += (size_t)e * strideA;
  const int NF = N >> 4, KT = KTOT >> 5;
  const size_t wb = (size_t)e * NF * KT * 512;
  Wh += wb; Wl += wb;
  const float* bs = bias + (size_t)e * N;
  const size_t ob = (size_t)e * 256 * N;

  const int tid = threadIdx.x, wid = tid >> 6, lane = tid & 63;
  const int mblk = blockIdx.x * 32;
  const int nf = blockIdx.y * 4 + wid;
  const int r0 = mblk + (lane & 15);
  const int kof = (lane >> 4) * 8;

  f32x4 acc0 = {0,0,0,0}, acc1 = {0,0,0,0};
  for (int t = 0; t < KT; ++t){
    const int k = t*32 + kof;
    bf16x8 ah0 = *(const bf16x8*)(Ah + (size_t)r0*KTOT + k);
    bf16x8 al0 = *(const bf16x8*)(Al + (size_t)r0*KTOT + k);
    bf16x8 ah1 = *(const bf16x8*)(Ah + (size_t)(r0+16)*KTOT + k);
    bf16x8 al1 = *(const bf16x8*)(Al + (size_t)(r0+16)*KTOT + k);
    const size_t fb = ((size_t)t*NF + nf)*512 + lane*8;
    bf16x8 bh = *(const bf16x8*)(Wh + fb);
    bf16x8 bl = *(const bf16x8*)(Wl + fb);
    acc0 = __builtin_amdgcn_mfma_f32_16x16x32_bf16(ah0, bh, acc0, 0,0,0);
    acc0 = __builtin_amdgcn_mfma_f32_16x16x32_bf16(ah0, bl, acc0, 0,0,0);
    acc0 = __builtin_amdgcn_mfma_f32_16x16x32_bf16(al0, bh, acc0, 0,0,0);
    acc1 = __builtin_amdgcn_mfma_f32_16x16x32_bf16(ah1, bh, acc1, 0,0,0);
    acc1 = __builtin_amdgcn_mfma_f32_16x16x32_bf16(ah1, bl, acc1, 0,0,0);
    acc1 = __builtin_amdgcn_mfma_f32_16x16x32_bf16(al1, bh, acc1, 0,0,0);
  }
  const int n = nf*16 + (lane & 15);
  const float bv = bs[n];
  #pragma unroll
  for (int mi = 0; mi < 2; ++mi){
    f32x4 a = mi ? acc1 : acc0;
    #pragma unroll
    for (int r = 0; r < 4; ++r){
      const int m = mblk + mi*16 + (lane >> 4)*4 + r;
      float v = a[r] + bv;
      if (ACT == 1) v = leakyf(v);
      const size_t o = ob + (size_t)m*N + n;
      if (OUTM == 0){
        unsigned short h = f2bf(v);
        OutH[o] = h; OutL[o] = f2bf(v - bf2f(h));
      } else {
        OutF[o] = v;
      }
    }
  }
}

// ---------------- 2x2 stride-1 maxpool (NCHW) ----------------
template<int C,int IH,int IW>
__global__ __launch_bounds__(256) void pool_k(const float* __restrict__ in,
                                              float* __restrict__ out){
  constexpr int OH = IH - 1, OW = IW - 1;
  int idx = blockIdx.x * 256 + threadIdx.x;
  if (idx >= BATCH * C * OH * OW) return;
  int ow = idx % OW; int t = idx / OW;
  int oh = t % OH;   t /= OH;
  const float* p = in + ((size_t)t * IH + oh) * IW + ow;
  out[idx] = fmaxf(fmaxf(p[0], p[1]), fmaxf(p[IW], p[IW + 1]));
}

// ------- pool2: NHWC fp32 [B,28,28,32] -> padded NHWC fp16 [B,29,29,32] -----
__global__ __launch_bounds__(256) void pool2n_k(const float* __restrict__ in,
    _Float16* __restrict__ o16){
  int idx = blockIdx.x*256 + threadIdx.x;
  if (idx >= BATCH*27*27*32) return;
  int ic = idx & 31; int p = idx >> 5;
  int ow = p % 27; int t = p / 27; int oh = t % 27; int n = t / 27;
  const float* b = in + (((size_t)n*28 + oh)*28 + ow)*32 + ic;
  float v = fmaxf(fmaxf(b[0], b[32]), fmaxf(b[28*32], b[29*32]));
  o16[(((size_t)n*29 + oh+1)*29 + ow+1)*32 + ic] = (_Float16)v;
}

// ---------------- scout gate (NHWC input [B,28,28,32]) ----------------
__global__ __launch_bounds__(256) void gate_k(const float* __restrict__ s2,
                                              const float* __restrict__ cw,
                                              const float* __restrict__ cb,
                                              float* __restrict__ comb){
  int n = blockIdx.x;
  int tid = threadIdx.x;
  int c = tid & 31;
  int sub = tid >> 5;
  const float* p = s2 + (size_t)n * 784 * 32 + c;
  float s = 0.f;
  for (int i = sub * 98; i < sub * 98 + 98; ++i) s += p[(size_t)i * 32];
  __shared__ float red[32][8];
  red[c][sub] = s;
  __syncthreads();
  if (tid < 32){
    float tot = 0.f;
    #pragma unroll
    for (int k = 0; k < 8; ++k) tot += red[tid][k];
    red[tid][0] = tot / 784.f;
  }
  __syncthreads();
  if (tid == 0){
    float lg[3];
    for (int e = 0; e < 3; ++e){
      float a = cb[e];
      for (int c2 = 0; c2 < 32; ++c2) a += red[c2][0] * cw[e * 32 + c2];
      lg[e] = a;
    }
    float m = fmaxf(lg[0], fmaxf(lg[1], lg[2]));
    float ex[3], sum = 0.f;
    for (int e = 0; e < 3; ++e){ ex[e] = expf(lg[e] - m); sum += ex[e]; }
    float pr[3];
    for (int e = 0; e < 3; ++e) pr[e] = ex[e] / sum;
    int i1 = 0;
    if (pr[1] > pr[0]) i1 = 1;
    if (pr[2] > pr[i1]) i1 = 2;
    int i2 = -1;
    for (int e = 0; e < 3; ++e){
      if (e == i1) continue;
      if (i2 < 0 || pr[e] > pr[i2]) i2 = e;
    }
    float s12 = pr[i1] + pr[i2] + 1e-6f;
    float cmb[3] = {0.f, 0.f, 0.f};
    cmb[i1] = pr[i1] / s12;
    cmb[i2] = pr[i2] / s12;
    comb[n * 3 + 0] = cmb[0];
    comb[n * 3 + 1] = cmb[1];
    comb[n * 3 + 2] = cmb[2];
  }
}

// ------ channel-parallel fused maxpool2s1(27->26) + adaptive avg(26->3) -----
__global__ __launch_bounds__(256) void papool2_k(const float* __restrict__ in,
                                                 float* __restrict__ flat){
  __shared__ float red[2][128][9];
  const int n = blockIdx.x;
  const int tid = threadIdx.x;
  const int h = tid >> 7, c = tid & 127;
  const float* p = in + (size_t)n * 729 * 128 + c;

  float sum[9];
  #pragma unroll
  for (int j = 0; j < 9; ++j) sum[j] = 0.f;

  float prev[27], cur[27];
  const int r0 = h * 13;
  #pragma unroll
  for (int rr = 0; rr < 14; ++rr){
    const int r = r0 + rr;
    #pragma unroll
    for (int cc = 0; cc < 27; ++cc)
      cur[cc] = p[(size_t)(r*27 + cc) * 128];
    if (rr > 0){
      const int pr = r - 1;
      const bool b0 = (pr < 9), b1 = (pr >= 8) && (pr < 18), b2 = (pr >= 17);
      #pragma unroll
      for (int cc = 0; cc < 26; ++cc){
        float v = fmaxf(fmaxf(prev[cc], prev[cc+1]), fmaxf(cur[cc], cur[cc+1]));
        if (b0){
          if (cc < 9)             sum[0] += v;
          if (cc >= 8 && cc < 18) sum[1] += v;
          if (cc >= 17)           sum[2] += v;
        }
        if (b1){
          if (cc < 9)             sum[3] += v;
          if (cc >= 8 && cc < 18) sum[4] += v;
          if (cc >= 17)           sum[5] += v;
        }
        if (b2){
          if (cc < 9)             sum[6] += v;
          if (cc >= 8 && cc < 18) sum[7] += v;
          if (cc >= 17)           sum[8] += v;
        }
      }
    }
    #pragma unroll
    for (int cc = 0; cc < 27; ++cc) prev[cc] = cur[cc];
  }

  #pragma unroll
  for (int j = 0; j < 9; ++j) red[h][c][j] = sum[j];
  __syncthreads();

  if (tid < 128){
    const float rcp[9] = {1.f/81, 1.f/90, 1.f/81, 1.f/90, 1.f/100, 1.f/90,
                          1.f/81, 1.f/90, 1.f/81};
    float* o = flat + (size_t)n * 1152 + tid * 9;
    #pragma unroll
    for (int j = 0; j < 9; ++j)
      o[j] = (red[0][tid][j] + red[1][tid][j]) * rcp[j];
  }
}

// ---------------- final gated combine ----------------
__global__ __launch_bounds__(256) void comb_k(const float* __restrict__ h3,
                                              const float* __restrict__ comb,
                                              float* __restrict__ out){
  int idx = blockIdx.x * 256 + threadIdx.x;
  if (idx >= BATCH * 512) return;
  int o = idx % 512, b = idx / 512;
  float s = 0.f;
  #pragma unroll
  for (int e = 0; e < 3; ++e)
    s += comb[b * 3 + e] * h3[((size_t)e * BATCH + b) * 512 + o];
  out[idx] = s;
}

// ============================================================================
extern "C" void kernel_launch(void* const* d_in, const int* in_sizes, int n_in,
                              void* d_out, int out_size, void* d_ws, size_t ws_size,
                              hipStream_t stream){
  const float* x    = (const float*)d_in[0];
  const float* tw1  = (const float*)d_in[1];  const float* tb1 = (const float*)d_in[2];
  const float* tw2  = (const float*)d_in[3];  const float* tb2 = (const float*)d_in[4];
  const float* tw3  = (const float*)d_in[5];  const float* tb3 = (const float*)d_in[6];
  const float* tw4  = (const float*)d_in[7];  const float* tb4 = (const float*)d_in[8];
  const float* sw1  = (const float*)d_in[9];  const float* sb1 = (const float*)d_in[10];
  const float* bn1g = (const float*)d_in[11]; const float* bn1b = (const float*)d_in[12];
  const float* bn1m = (const float*)d_in[13]; const float* bn1v = (const float*)d_in[14];
  const float* sw2  = (const float*)d_in[15]; const float* sb2 = (const float*)d_in[16];
  const float* bn2g = (const float*)d_in[17]; const float* bn2b = (const float*)d_in[18];
  const float* bn2m = (const float*)d_in[19]; const float* bn2v = (const float*)d_in[20];
  const float* cw   = (const float*)d_in[21]; const float* cb  = (const float*)d_in[22];
  const float* ew1  = (const float*)d_in[23]; const float* eb1 = (const float*)d_in[24];
  const float* ew2  = (const float*)d_in[25]; const float* eb2 = (const float*)d_in[26];
  const float* ew3  = (const float*)d_in[27]; const float* eb3 = (const float*)d_in[28];
  float* out = (float*)d_out;

  // ---- workspace layout (floats), ~157 MB ----
  float* ws = (float*)d_ws;
  size_t off = 0;
  float* comb   = ws + off; off += 768;
  float* flat   = ws + off; off += (size_t)BATCH * 1152;
  float* h3     = ws + off; off += (size_t)BATCH * 3 * 512;
  _Float16* wpk3 = (_Float16*)(ws + off); off += 9216;   // 18432 fp16
  _Float16* wpk4 = (_Float16*)(ws + off); off += 36864;  // 73728 fp16
  _Float16* wp2  = (_Float16*)(ws + off); off += 7680;   // 15360 fp16
  _Float16* wps2 = (_Float16*)(ws + off); off += 3072;   // 6144 fp16
  _Float16* wpf  = (_Float16*)(ws + off); off += 3072;   // 6144 fp16
  off += 16;                                                      // guard pad
  float* bufA   = ws + off; off += 13778944;
  off += 16;                                                      // guard pad
  float* bufB   = ws + off; off += 23887872;
  off += 16;
  (void)ws_size; (void)in_sizes; (void)n_in; (void)out_size;

  // phase aliases (lifetimes disjoint, single-stream ordered)
  float* s1out = bufA;                       // [B,16,56,56] NCHW
  float* c1out = bufB;                       // [B,16,56,56] NCHW
  float* s2out = bufB + 16000000;            // [B,28,28,32] NHWC
  float* p1out = bufA;                       // [B,16,55,55] NCHW
  float* c2out = bufB;                       // [B,28,28,32] NHWC
  _Float16* P2 = (_Float16*)(bufB + 8000000);          // 6,889,472 fp16
  _Float16* C3 = (_Float16*)bufA;                      // 13,778,944 fp16
  float* c4out = bufB;                       // [B,27,27,128] NHWC

  // head-phase aliases in bufB (valid after papool2_k)
  unsigned short* ub = (unsigned short*)bufB;
  size_t uo = 0;
  unsigned short* ewp1h = ub + uo; uo += 3538944;
  unsigned short* ewp1l = ub + uo; uo += 3538944;
  unsigned short* ewp2h = ub + uo; uo += 1572864;
  unsigned short* ewp2l = ub + uo; uo += 1572864;
  unsigned short* ewp3h = ub + uo; uo += 786432;
  unsigned short* ewp3l = ub + uo; uo += 786432;
  unsigned short* fh    = ub + uo; uo += 294912;
  unsigned short* fl    = ub + uo; uo += 294912;
  unsigned short* h1h   = ub + uo; uo += 786432;
  unsigned short* h1l   = ub + uo; uo += 786432;
  unsigned short* h2h   = ub + uo; uo += 393216;
  unsigned short* h2l   = ub + uo; uo += 393216;

  dim3 blk(256);

  // ---- weight prep (all fp16 single except head) ----
  wpackM_k<32,64>  <<<dim3(72),  blk, 0, stream>>>(tw3, wpk3);
  wpackM_k<64,128> <<<dim3(288), blk, 0, stream>>>(tw4, wpk4);
  wpackS_k<32,5><<<dim3(60), blk, 0, stream>>>(tw2, wp2);
  wpackS_k<32,3><<<dim3(24), blk, 0, stream>>>(sw2, wps2);
  wpackF_k<<<dim3(24), blk, 0, stream>>>(sw1, tw1, wpf);

  // ---- fused scout1 + conv1 (space-to-depth MFMA fp16, one pass over x) ----
  fusedM_k<<<dim3(BATCH*28), blk, 0, stream>>>(
      x, wpf, sb1, tb1, bn1g, bn1b, bn1m, bn1v, s1out, c1out);

  // ---- scout2 (MFMA fp16 strided) + gate ----
  convS_k<32,3,1,56,56,1><<<dim3(BATCH*28), blk, 0, stream>>>(
      s1out, wps2, sb2, bn2g, bn2b, bn2m, bn2v, s2out);
  gate_k<<<dim3(256), blk, 0, stream>>>(s2out, cw, cb, comb);

  // ---- pool1 -> conv2 (MFMA fp16 strided) ----
  pool_k<16,56,56><<<dim3(48400), blk, 0, stream>>>(c1out, p1out);
  convS_k<32,5,2,55,55,0><<<dim3(BATCH*28), blk, 0, stream>>>(
      p1out, wp2, tb2, nullptr, nullptr, nullptr, nullptr, c2out);

  // ---- pool2 -> padded NHWC fp16 ----
  hipMemsetAsync(P2, 0, (size_t)6889472 * 2, stream);
  pool2n_k<<<dim3((BATCH*27*27*32 + 255)/256), blk, 0, stream>>>(c2out, P2);

  // ---- conv3 (MFMA fp16) -> padded NHWC fp16 ----
  hipMemsetAsync(C3, 0, (size_t)13778944 * 2, stream);
  convM_k<32,64,0><<<dim3(BATCH*14), blk, 0, stream>>>(
      P2, wpk3, tb3, C3, nullptr);

  // ---- conv4 (MFMA fp16) -> fp32 NHWC [B,27,27,128] ----
  convM_k<64,128,1><<<dim3(BATCH*14), blk, 0, stream>>>(
      C3, wpk4, tb4, nullptr, c4out);

  papool2_k<<<dim3(BATCH), blk, 0, stream>>>(c4out, flat);

  // ---- MoE head: pack weights + split A, then 3 MFMA GEMMs (split-bf16) ----
  wpackG_k<1152><<<dim3(4608,3), blk, 0, stream>>>(ew1, 1024, ewp1h, ewp1l);
  wpackG_k<1024><<<dim3(2048,3), blk, 0, stream>>>(ew2,  512, ewp2h, ewp2l);
  wpackG_k< 512><<<dim3(1024,3), blk, 0, stream>>>(ew3,  512, ewp3h, ewp3l);
  asplit_k<<<dim3(1152), blk, 0, stream>>>(flat, fh, fl, BATCH*1152);

  gemmM_k<1152,1,0><<<dim3(8,16,3), blk, 0, stream>>>(
      fh, fl, 0L, ewp1h, ewp1l, eb1, 1024, h1h, h1l, nullptr);
  gemmM_k<1024,1,0><<<dim3(8,8,3), blk, 0, stream>>>(
      h1h, h1l, 256L*1024, ewp2h, ewp2l, eb2, 512, h2h, h2l, nullptr);
  gemmM_k< 512,0,1><<<dim3(8,8,3), blk, 0, stream>>>(
      h2h, h2l, 256L*512, ewp3h, ewp3l, eb3, 512, nullptr, nullptr, h3);

  comb_k<<<dim3(512), blk, 0, stream>>>(h3, comb, out);
}

// Round 13
// 356.849 us; speedup vs baseline: 1.8571x; 1.2176x over previous
//
#include <hip/hip_runtime.h>

#define DEV static __device__ __forceinline__

constexpr int BATCH = 256;

DEV float leakyf(float x){ return x > 0.f ? x : 0.2f * x; }

typedef short bf16x8 __attribute__((ext_vector_type(8)));
typedef _Float16 f16x8 __attribute__((ext_vector_type(8)));
typedef float f32x4 __attribute__((ext_vector_type(4)));

DEV unsigned short f2bf(float v){
  union { float f; unsigned u; } x; x.f = v;
  unsigned r = x.u + 0x7fffu + ((x.u >> 16) & 1u);
  return (unsigned short)(r >> 16);
}
DEV float bf2f(unsigned short b){
  union { unsigned u; float f; } x; x.u = ((unsigned)b) << 16;
  return x.f;
}

// ------- pack OIHW conv weights into MFMA B-fragment order, single fp16 -----
template<int IC,int OC>
__global__ __launch_bounds__(256) void wpackM_k(const float* __restrict__ w,
    _Float16* __restrict__ wp){
  constexpr int S = IC/32, F = OC/16;
  int i = blockIdx.x*256 + threadIdx.x;
  if (i >= 9*S*F*512) return;
  int j = i & 7, L = (i >> 3) & 63, rest = i >> 9;
  int f = rest % F; int q2 = rest / F; int s = q2 % S; int t = q2 / S;
  int oc = f*16 + (L & 15), ic = s*32 + (L >> 4)*8 + j;
  wp[i] = (_Float16)w[((size_t)oc*IC + ic)*9 + t];
}

// ------- pack strided-conv weights (IC=16), single fp16 ---------------------
template<int OC,int K>
__global__ __launch_bounds__(256) void wpackS_k(const float* __restrict__ w,
    _Float16* __restrict__ wp){
  constexpr int F = OC/16, KWP = (K+1)/2;
  int i = blockIdx.x*256 + threadIdx.x;
  if (i >= K*KWP*F*512) return;
  int j = i & 7, L = (i >> 3) & 63, rest = i >> 9;
  int f = rest % F, s = rest / F;
  int kh = s / KWP, kwp = s % KWP;
  int k = (L >> 4)*8 + j;
  int kw = 2*kwp + (k >> 4), ic = k & 15;
  int oc = f*16 + (L & 15);
  float v = (kw < K) ? w[((size_t)(oc*16 + ic)*K + kh)*K + kw] : 0.f;
  wp[i] = (_Float16)v;
}

// ------- pack scout1(k7) + conv1(k3) weights, space-to-depth, single fp16 ---
__global__ __launch_bounds__(256) void wpackF_k(const float* __restrict__ sw1,
    const float* __restrict__ tw1, _Float16* __restrict__ wp){
  int i = blockIdx.x*256 + threadIdx.x;
  if (i >= 6*2*512) return;
  int j = i & 7, L = (i >> 3) & 63, rest = i >> 9;
  int nf = rest & 1, s = rest >> 1;
  int k = s*32 + (L >> 4)*8 + j;
  int oc = L & 15;
  int t = k / 48, c = k % 48;
  int dr = (t >> 1) - 1, dc = (t & 1) - 1;
  int ic = c >> 4, pr = (c >> 2) & 3, pc = c & 3;
  float v = 0.f;
  if (nf == 0){
    int kh = 4*dr + pr + 3, kw = 4*dc + pc + 3;
    if (kh >= 0 && kh < 7 && kw >= 0 && kw < 7) v = sw1[((oc*3 + ic)*7 + kh)*7 + kw];
  } else {
    int kh = 4*dr + pr + 1, kw = 4*dc + pc + 1;
    if (kh >= 0 && kh < 3 && kw >= 0 && kw < 3) v = tw1[((oc*3 + ic)*3 + kh)*3 + kw];
  }
  wp[i] = (_Float16)v;
}

// ------- pack expert GEMM weights W[e][N][K] into frag order, bf16 hi/lo ----
template<int KTOT>
__global__ __launch_bounds__(256) void wpackG_k(const float* __restrict__ w, int N,
    unsigned short* __restrict__ hi, unsigned short* __restrict__ lo){
  const int NF = N >> 4, KT = KTOT >> 5;
  const int total = NF * KT * 512;
  const int e = blockIdx.y;
  w  += (size_t)e * N * KTOT;
  hi += (size_t)e * total; lo += (size_t)e * total;
  int i = blockIdx.x*256 + threadIdx.x;
  if (i >= total) return;
  int j = i & 7, L = (i >> 3) & 63, rest = i >> 9;
  int nf = rest % NF, t = rest / NF;
  int n = nf*16 + (L & 15), k = t*32 + (L >> 4)*8 + j;
  float v = w[(size_t)n*KTOT + k];
  unsigned short h = f2bf(v);
  hi[i] = h; lo[i] = f2bf(v - bf2f(h));
}

// ------- split fp32 array into bf16 hi/lo ----------------------------------
__global__ __launch_bounds__(256) void asplit_k(const float* __restrict__ in,
    unsigned short* __restrict__ hi, unsigned short* __restrict__ lo, int nelem){
  int i = blockIdx.x*256 + threadIdx.x;
  if (i >= nelem) return;
  float v = in[i];
  unsigned short h = f2bf(v);
  hi[i] = h; lo[i] = f2bf(v - bf2f(h));
}

// ---------- fused scout1+conv1, space-to-depth MFMA, fp16 NHWC outputs ------
__global__ __launch_bounds__(256) void fusedM_k(
    const float* __restrict__ x,
    const _Float16* __restrict__ W,
    const float* __restrict__ sb, const float* __restrict__ cb_,
    const float* __restrict__ g, const float* __restrict__ bt,
    const float* __restrict__ mn, const float* __restrict__ vr,
    _Float16* __restrict__ s1out, _Float16* __restrict__ c1out){
  __shared__ __align__(16) _Float16 Ah[3*58*64];
  const int tid = threadIdx.x;
  const int n = blockIdx.x / 28, oh0 = (blockIdx.x % 28) * 2;

  { // zero LDS tile
    int4* a = (int4*)Ah;
    for (int i = tid; i < 1392; i += 256) a[i] = (int4){0,0,0,0};
  }
  __syncthreads();

  for (int i = tid; i < 2016; i += 256){
    int m = i % 56; int rc = i / 56;
    int ic = rc % 3, ridx = rc / 3;
    int ih = 4*oh0 - 4 + ridx;
    if (ih < 0 || ih >= 224) continue;
    float4 v = *(const float4*)(x + ((size_t)(n*3 + ic)*224 + ih)*224 + 4*m);
    int rr = ridx >> 2, pr = ridx & 3, cc = m + 1;
    int boff = (((rr*58 + cc) << 7) + ic*32 + pr*8) ^ ((cc & 7) << 4);
    _Float16 h4[4] = {(_Float16)v.x, (_Float16)v.y, (_Float16)v.z, (_Float16)v.w};
    *(unsigned long long*)((char*)Ah + boff) = *(unsigned long long*)h4;
  }
  __syncthreads();

  const int wid = tid >> 6, lane = tid & 63;
  const int kg8 = (lane >> 4) * 8;
  f32x4 acc[2][2];
  #pragma unroll
  for (int mi = 0; mi < 2; ++mi)
    #pragma unroll
    for (int nf = 0; nf < 2; ++nf) acc[mi][nf] = (f32x4){0.f,0.f,0.f,0.f};

  #pragma unroll
  for (int s = 0; s < 6; ++s){
    const int kk = s*32 + kg8;
    const int t = kk / 48, c0 = kk - t*48;
    const int ra = t >> 1, ca = t & 1;
    f16x8 ah[2];
    #pragma unroll
    for (int mi = 0; mi < 2; ++mi){
      const int m = 2*wid + mi;
      const int rowsel = m >> 2;
      const int ow = (m & 3)*16 + (lane & 15);
      const int owc = ow > 55 ? 55 : ow;
      const int col = owc + ca;
      const int bidx = ((((rowsel + ra)*58 + col) << 7) + c0*2) ^ ((col & 7) << 4);
      ah[mi] = *(const f16x8*)((const char*)Ah + bidx);
    }
    #pragma unroll
    for (int nf = 0; nf < 2; ++nf){
      const f16x8 bw = *(const f16x8*)(W + (s*2 + nf)*512 + lane*8);
      #pragma unroll
      for (int mi = 0; mi < 2; ++mi)
        acc[mi][nf] = __builtin_amdgcn_mfma_f32_16x16x32_f16(ah[mi], bw, acc[mi][nf], 0,0,0);
    }
  }

  const int oc = lane & 15;
  const float sbv = sb[oc];
  const float scv = g[oc] * __frsqrt_rn(vr[oc] + 1e-5f);
  const float mnv = mn[oc], btv = bt[oc], cbv = cb_[oc];
  #pragma unroll
  for (int mi = 0; mi < 2; ++mi){
    const int m = 2*wid + mi;
    const int row = oh0 + (m >> 2);
    const int owb = (m & 3)*16 + (lane >> 4)*4;
    #pragma unroll
    for (int r = 0; r < 4; ++r){
      const int ow = owb + r;
      if (ow >= 56) continue;
      float vs = acc[mi][0][r] + sbv;
      vs = fmaxf((vs - mnv)*scv + btv, 0.f);
      const size_t o = (((size_t)n*56 + row)*56 + ow)*16 + oc;
      s1out[o] = (_Float16)vs;
      c1out[o] = (_Float16)leakyf(acc[mi][1][r] + cbv);
    }
  }
}

// ---------------- strided (S=2) MFMA conv, fp16 NHWC input [B,IH,IW,16] -----
template<int OC,int K,int P,int IH,int IW,int ACT>
__global__ __launch_bounds__(256) void convS_k(
    const _Float16* __restrict__ in,
    const _Float16* __restrict__ W,
    const float* __restrict__ bias,
    const float* __restrict__ bng, const float* __restrict__ bnb,
    const float* __restrict__ bnm, const float* __restrict__ bnv,
    float* __restrict__ outNHWC){
  constexpr int F = OC/16, KWP = (K+1)/2;
  __shared__ __align__(16) _Float16 A[K*60*16];

  const int tid = threadIdx.x;
  const int n = blockIdx.x / 28, oh = blockIdx.x % 28;

  // stage: 16B chunks (8 ch); fully coalesced NHWC reads, no cvt
  for (int i = tid; i < K*60*2; i += 256){
    int half = i & 1; int p = i >> 1;
    int c = p % 60; int r = p / 60;
    int ih = 2*oh - P + r, iw = c - P;
    int4 v = {0,0,0,0};
    if (ih >= 0 && ih < IH && iw >= 0 && iw < IW)
      v = *(const int4*)(in + (((size_t)n*IH + ih)*IW + iw)*16 + half*8);
    int byte = ((r*60 + c)*32 + half*16) ^ (((c>>1)&7) << 4);
    *(int4*)((char*)A + byte) = v;
  }
  __syncthreads();

  const int wid = tid >> 6, lane = tid & 63;
  const int fsel = wid & 1, mb = wid >> 1;
  const int ow_l = min(mb*16 + (lane & 15), 27);
  const int ic0b = ((lane >> 4) & 1) * 16;
  const int kwo  = (lane >> 4) >> 1;

  f32x4 acc = {0.f,0.f,0.f,0.f};
  #pragma unroll
  for (int kh = 0; kh < K; ++kh){
    #pragma unroll
    for (int kwp = 0; kwp < KWP; ++kwp){
      const int kw = 2*kwp + kwo;
      const int c = 2*ow_l + kw;
      int byte = ((kh*60 + c)*32 + ic0b) ^ (((c>>1)&7) << 4);
      f16x8 a = *(const f16x8*)((const char*)A + byte);
      const int s = kh*KWP + kwp;
      const f16x8 b = *(const f16x8*)(W + (s*F + fsel)*512 + lane*8);
      acc = __builtin_amdgcn_mfma_f32_16x16x32_f16(a, b, acc, 0,0,0);
    }
  }

  const int oc = fsel*16 + (lane & 15);
  float bv = bias[oc], sc = 1.f, mm = 0.f, bb = 0.f;
  if (ACT == 1){
    sc = bng[oc] * __frsqrt_rn(bnv[oc] + 1e-5f);
    mm = bnm[oc]; bb = bnb[oc];
  }
  #pragma unroll
  for (int r = 0; r < 4; ++r){
    const int ow = mb*16 + (lane >> 4)*4 + r;
    if (ow >= 28) continue;
    float v = acc[r] + bv;
    if (ACT == 1) v = fmaxf((v - mm)*sc + bb, 0.f);
    else          v = leakyf(v);
    outNHWC[(((size_t)n*28 + oh)*28 + ow)*OC + oc] = v;
  }
}

// ---------------- MFMA single-fp16 3x3 s1 p1 conv on 27x27, padded NHWC -----
template<int IC,int OC,int OUTM>
__global__ __launch_bounds__(256) void convM_k(
    const _Float16* __restrict__ Ag,
    const _Float16* __restrict__ W,
    const float* __restrict__ bias,
    _Float16* __restrict__ OutHf, float* __restrict__ OutF)
{
  constexpr int S = IC/32, FTOT = OC/16, FW = FTOT/2;
  constexpr int ICB = IC*2, ICG = ICB/16;
  __shared__ __align__(16) char A[4*34*ICB];

  const int tid = threadIdx.x;
  const int bx = blockIdx.x;
  const int n = bx / 14, pr = bx % 14;
  const int oh0 = pr * 2;

  const size_t gbase = ((size_t)n*29) * 29 * IC;
  for (int g = tid; g < 4*34*ICG; g += 256){
    int r = g / (34*ICG);
    int rem = g - r*(34*ICG);
    int c = rem / ICG, q = rem - c*ICG;
    int rp = oh0 + r;
    int4 v = {0,0,0,0};
    if (rp <= 28 && c < 29){
      size_t e = gbase + ((size_t)rp*29 + c)*IC + q*8;
      v = *(const int4*)(Ag + e);
    }
    int off = (r*34 + c)*ICB + q*16;
    int swz = off ^ ((c & 7) << 4);
    *(int4*)(A + swz) = v;
  }
  __syncthreads();

  const int wid = tid >> 6, lane = tid & 63;
  const int rsel = wid & 1, ocq = wid >> 1;
  const int c0 = lane & 15, kg = (lane >> 4) * 16;
  const int colb0 = c0*ICB + kg, colb1 = (16 + c0)*ICB + kg;
  int msk[3];
  #pragma unroll
  for (int kw = 0; kw < 3; ++kw) msk[kw] = ((c0 + kw) & 7) << 4;

  f32x4 acc[2][FW];
  #pragma unroll
  for (int m = 0; m < 2; ++m)
    #pragma unroll
    for (int f = 0; f < FW; ++f) acc[m][f] = (f32x4){0.f,0.f,0.f,0.f};

  #pragma unroll
  for (int kh = 0; kh < 3; ++kh){
    #pragma unroll
    for (int kw = 0; kw < 3; ++kw){
      #pragma unroll
      for (int s = 0; s < S; ++s){
        const int fr0 = (((kh*3 + kw)*S + s)*FTOT + ocq*FW) * 512 + lane*8;
        f16x8 b[FW];
        #pragma unroll
        for (int f = 0; f < FW; ++f)
          b[f] = *(const f16x8*)(W + fr0 + f*512);
        const int base = ((rsel + kh)*34 + kw)*ICB + s*64;
        const int o0 = (base + colb0) ^ msk[kw];
        const int o1 = (base + colb1) ^ msk[kw];
        f16x8 a0 = *(const f16x8*)(A + o0);
        f16x8 a1 = *(const f16x8*)(A + o1);
        #pragma unroll
        for (int f = 0; f < FW; ++f){
          acc[0][f] = __builtin_amdgcn_mfma_f32_16x16x32_f16(a0, b[f], acc[0][f], 0,0,0);
          acc[1][f] = __builtin_amdgcn_mfma_f32_16x16x32_f16(a1, b[f], acc[1][f], 0,0,0);
        }
      }
    }
  }

  const int orow = oh0 + rsel;
  if (orow >= 27) return;
  #pragma unroll
  for (int f = 0; f < FW; ++f){
    const int oc = (ocq*FW + f)*16 + c0;
    const float bv = bias[oc];
    #pragma unroll
    for (int m = 0; m < 2; ++m){
      #pragma unroll
      for (int r = 0; r < 4; ++r){
        const int ow = m*16 + (lane >> 4)*4 + r;
        if (ow >= 27) continue;
        float v = leakyf(acc[m][f][r] + bv);
        if (OUTM == 0){
          size_t o = (((size_t)n*29 + orow+1)*29 + ow+1)*OC + oc;
          OutHf[o] = (_Float16)v;
        } else {
          OutF[(((size_t)n*27 + orow)*27 + ow)*OC + oc] = v;
        }
      }
    }
  }
}

// ---------------- split-bf16 MFMA GEMM for MoE head -------------------------
template<int KTOT,int ACT,int OUTM>
__global__ __launch_bounds__(256) void gemmM_k(
    const unsigned short* __restrict__ Ah, const unsigned short* __restrict__ Al,
    long strideA,
    const unsigned short* __restrict__ Wh, const unsigned short* __restrict__ Wl,
    const float* __restrict__ bias, int N,
    unsigned short* __restrict__ OutH, unsigned short* __restrict__ OutL,
    float* __restrict__ OutF){
  const int e = blockIdx.z;
  Ah += (size_t)e * strideA; Al += (size_t)e * strideA;
  const int NF = N >> 4, KT = KTOT >> 5;
  const size_t wb = (size_t)e * NF * KT * 512;
  Wh += wb; Wl += wb;
  const float* bs = bias + (size_t)e * N;
  const size_t ob = (size_t)e * 256 * N;

  const int tid = threadIdx.x, wid = tid >> 6, lane = tid & 63;
  const int mblk = blockIdx.x * 32;
  const int nf = blockIdx.y * 4 + wid;
  const int r0 = mblk + (lane & 15);
  const int kof = (lane >> 4) * 8;

  f32x4 acc0 = {0,0,0,0}, acc1 = {0,0,0,0};
  for (int t = 0; t < KT; ++t){
    const int k = t*32 + kof;
    bf16x8 ah0 = *(const bf16x8*)(Ah + (size_t)r0*KTOT + k);
    bf16x8 al0 = *(const bf16x8*)(Al + (size_t)r0*KTOT + k);
    bf16x8 ah1 = *(const bf16x8*)(Ah + (size_t)(r0+16)*KTOT + k);
    bf16x8 al1 = *(const bf16x8*)(Al + (size_t)(r0+16)*KTOT + k);
    const size_t fb = ((size_t)t*NF + nf)*512 + lane*8;
    bf16x8 bh = *(const bf16x8*)(Wh + fb);
    bf16x8 bl = *(const bf16x8*)(Wl + fb);
    acc0 = __builtin_amdgcn_mfma_f32_16x16x32_bf16(ah0, bh, acc0, 0,0,0);
    acc0 = __builtin_amdgcn_mfma_f32_16x16x32_bf16(ah0, bl, acc0, 0,0,0);
    acc0 = __builtin_amdgcn_mfma_f32_16x16x32_bf16(al0, bh, acc0, 0,0,0);
    acc1 = __builtin_amdgcn_mfma_f32_16x16x32_bf16(ah1, bh, acc1, 0,0,0);
    acc1 = __builtin_amdgcn_mfma_f32_16x16x32_bf16(ah1, bl, acc1, 0,0,0);
    acc1 = __builtin_amdgcn_mfma_f32_16x16x32_bf16(al1, bh, acc1, 0,0,0);
  }
  const int n = nf*16 + (lane & 15);
  const float bv = bs[n];
  #pragma unroll
  for (int mi = 0; mi < 2; ++mi){
    f32x4 a = mi ? acc1 : acc0;
    #pragma unroll
    for (int r = 0; r < 4; ++r){
      const int m = mblk + mi*16 + (lane >> 4)*4 + r;
      float v = a[r] + bv;
      if (ACT == 1) v = leakyf(v);
      const size_t o = ob + (size_t)m*N + n;
      if (OUTM == 0){
        unsigned short h = f2bf(v);
        OutH[o] = h; OutL[o] = f2bf(v - bf2f(h));
      } else {
        OutF[o] = v;
      }
    }
  }
}

// ------ fp16 NHWC 2x2 s1 maxpool: [B,56,56,16] -> [B,55,55,16] --------------
__global__ __launch_bounds__(256) void poolh_k(const _Float16* __restrict__ in,
                                               _Float16* __restrict__ out){
  int idx = blockIdx.x * 256 + threadIdx.x;
  if (idx >= BATCH * 55 * 55 * 2) return;
  int half = idx & 1; int p = idx >> 1;
  int ow = p % 55; int t = p / 55; int oh = t % 55; int n = t / 55;
  const _Float16* q = in + (((size_t)n*56 + oh)*56 + ow)*16 + half*8;
  f16x8 a = *(const f16x8*)q;
  f16x8 b = *(const f16x8*)(q + 16);
  f16x8 c = *(const f16x8*)(q + 56*16);
  f16x8 d = *(const f16x8*)(q + 57*16);
  f16x8 r;
  #pragma unroll
  for (int j = 0; j < 8; ++j){
    float m = fmaxf(fmaxf((float)a[j], (float)b[j]), fmaxf((float)c[j], (float)d[j]));
    r[j] = (_Float16)m;
  }
  *(f16x8*)(out + (size_t)p*16 + half*8) = r;
}

// ------- pool2: NHWC fp32 [B,28,28,32] -> padded NHWC fp16 [B,29,29,32] -----
__global__ __launch_bounds__(256) void pool2n_k(const float* __restrict__ in,
    _Float16* __restrict__ o16){
  int idx = blockIdx.x*256 + threadIdx.x;
  if (idx >= BATCH*27*27*32) return;
  int ic = idx & 31; int p = idx >> 5;
  int ow = p % 27; int t = p / 27; int oh = t % 27; int n = t / 27;
  const float* b = in + (((size_t)n*28 + oh)*28 + ow)*32 + ic;
  float v = fmaxf(fmaxf(b[0], b[32]), fmaxf(b[28*32], b[29*32]));
  o16[(((size_t)n*29 + oh+1)*29 + ow+1)*32 + ic] = (_Float16)v;
}

// ---------------- scout gate (NHWC input [B,28,28,32]) ----------------
__global__ __launch_bounds__(256) void gate_k(const float* __restrict__ s2,
                                              const float* __restrict__ cw,
                                              const float* __restrict__ cb,
                                              float* __restrict__ comb){
  int n = blockIdx.x;
  int tid = threadIdx.x;
  int c = tid & 31;
  int sub = tid >> 5;
  const float* p = s2 + (size_t)n * 784 * 32 + c;
  float s = 0.f;
  for (int i = sub * 98; i < sub * 98 + 98; ++i) s += p[(size_t)i * 32];
  __shared__ float red[32][8];
  red[c][sub] = s;
  __syncthreads();
  if (tid < 32){
    float tot = 0.f;
    #pragma unroll
    for (int k = 0; k < 8; ++k) tot += red[tid][k];
    red[tid][0] = tot / 784.f;
  }
  __syncthreads();
  if (tid == 0){
    float lg[3];
    for (int e = 0; e < 3; ++e){
      float a = cb[e];
      for (int c2 = 0; c2 < 32; ++c2) a += red[c2][0] * cw[e * 32 + c2];
      lg[e] = a;
    }
    float m = fmaxf(lg[0], fmaxf(lg[1], lg[2]));
    float ex[3], sum = 0.f;
    for (int e = 0; e < 3; ++e){ ex[e] = expf(lg[e] - m); sum += ex[e]; }
    float pr[3];
    for (int e = 0; e < 3; ++e) pr[e] = ex[e] / sum;
    int i1 = 0;
    if (pr[1] > pr[0]) i1 = 1;
    if (pr[2] > pr[i1]) i1 = 2;
    int i2 = -1;
    for (int e = 0; e < 3; ++e){
      if (e == i1) continue;
      if (i2 < 0 || pr[e] > pr[i2]) i2 = e;
    }
    float s12 = pr[i1] + pr[i2] + 1e-6f;
    float cmb[3] = {0.f, 0.f, 0.f};
    cmb[i1] = pr[i1] / s12;
    cmb[i2] = pr[i2] / s12;
    comb[n * 3 + 0] = cmb[0];
    comb[n * 3 + 1] = cmb[1];
    comb[n * 3 + 2] = cmb[2];
  }
}

// ------ channel-parallel fused maxpool2s1(27->26) + adaptive avg(26->3) -----
__global__ __launch_bounds__(256) void papool2_k(const float* __restrict__ in,
                                                 float* __restrict__ flat){
  __shared__ float red[2][128][9];
  const int n = blockIdx.x;
  const int tid = threadIdx.x;
  const int h = tid >> 7, c = tid & 127;
  const float* p = in + (size_t)n * 729 * 128 + c;

  float sum[9];
  #pragma unroll
  for (int j = 0; j < 9; ++j) sum[j] = 0.f;

  float prev[27], cur[27];
  const int r0 = h * 13;
  #pragma unroll
  for (int rr = 0; rr < 14; ++rr){
    const int r = r0 + rr;
    #pragma unroll
    for (int cc = 0; cc < 27; ++cc)
      cur[cc] = p[(size_t)(r*27 + cc) * 128];
    if (rr > 0){
      const int pr = r - 1;
      const bool b0 = (pr < 9), b1 = (pr >= 8) && (pr < 18), b2 = (pr >= 17);
      #pragma unroll
      for (int cc = 0; cc < 26; ++cc){
        float v = fmaxf(fmaxf(prev[cc], prev[cc+1]), fmaxf(cur[cc], cur[cc+1]));
        if (b0){
          if (cc < 9)             sum[0] += v;
          if (cc >= 8 && cc < 18) sum[1] += v;
          if (cc >= 17)           sum[2] += v;
        }
        if (b1){
          if (cc < 9)             sum[3] += v;
          if (cc >= 8 && cc < 18) sum[4] += v;
          if (cc >= 17)           sum[5] += v;
        }
        if (b2){
          if (cc < 9)             sum[6] += v;
          if (cc >= 8 && cc < 18) sum[7] += v;
          if (cc >= 17)           sum[8] += v;
        }
      }
    }
    #pragma unroll
    for (int cc = 0; cc < 27; ++cc) prev[cc] = cur[cc];
  }

  #pragma unroll
  for (int j = 0; j < 9; ++j) red[h][c][j] = sum[j];
  __syncthreads();

  if (tid < 128){
    const float rcp[9] = {1.f/81, 1.f/90, 1.f/81, 1.f/90, 1.f/100, 1.f/90,
                          1.f/81, 1.f/90, 1.f/81};
    float* o = flat + (size_t)n * 1152 + tid * 9;
    #pragma unroll
    for (int j = 0; j < 9; ++j)
      o[j] = (red[0][tid][j] + red[1][tid][j]) * rcp[j];
  }
}

// ---------------- final gated combine ----------------
__global__ __launch_bounds__(256) void comb_k(const float* __restrict__ h3,
                                              const float* __restrict__ comb,
                                              float* __restrict__ out){
  int idx = blockIdx.x * 256 + threadIdx.x;
  if (idx >= BATCH * 512) return;
  int o = idx % 512, b = idx / 512;
  float s = 0.f;
  #pragma unroll
  for (int e = 0; e < 3; ++e)
    s += comb[b * 3 + e] * h3[((size_t)e * BATCH + b) * 512 + o];
  out[idx] = s;
}

// ============================================================================
extern "C" void kernel_launch(void* const* d_in, const int* in_sizes, int n_in,
                              void* d_out, int out_size, void* d_ws, size_t ws_size,
                              hipStream_t stream){
  const float* x    = (const float*)d_in[0];
  const float* tw1  = (const float*)d_in[1];  const float* tb1 = (const float*)d_in[2];
  const float* tw2  = (const float*)d_in[3];  const float* tb2 = (const float*)d_in[4];
  const float* tw3  = (const float*)d_in[5];  const float* tb3 = (const float*)d_in[6];
  const float* tw4  = (const float*)d_in[7];  const float* tb4 = (const float*)d_in[8];
  const float* sw1  = (const float*)d_in[9];  const float* sb1 = (const float*)d_in[10];
  const float* bn1g = (const float*)d_in[11]; const float* bn1b = (const float*)d_in[12];
  const float* bn1m = (const float*)d_in[13]; const float* bn1v = (const float*)d_in[14];
  const float* sw2  = (const float*)d_in[15]; const float* sb2 = (const float*)d_in[16];
  const float* bn2g = (const float*)d_in[17]; const float* bn2b = (const float*)d_in[18];
  const float* bn2m = (const float*)d_in[19]; const float* bn2v = (const float*)d_in[20];
  const float* cw   = (const float*)d_in[21]; const float* cb  = (const float*)d_in[22];
  const float* ew1  = (const float*)d_in[23]; const float* eb1 = (const float*)d_in[24];
  const float* ew2  = (const float*)d_in[25]; const float* eb2 = (const float*)d_in[26];
  const float* ew3  = (const float*)d_in[27]; const float* eb3 = (const float*)d_in[28];
  float* out = (float*)d_out;

  // ---- workspace layout (floats), ~157 MB ----
  float* ws = (float*)d_ws;
  size_t off = 0;
  float* comb   = ws + off; off += 768;
  float* flat   = ws + off; off += (size_t)BATCH * 1152;
  float* h3     = ws + off; off += (size_t)BATCH * 3 * 512;
  _Float16* wpk3 = (_Float16*)(ws + off); off += 9216;
  _Float16* wpk4 = (_Float16*)(ws + off); off += 36864;
  _Float16* wp2  = (_Float16*)(ws + off); off += 7680;
  _Float16* wps2 = (_Float16*)(ws + off); off += 3072;
  _Float16* wpf  = (_Float16*)(ws + off); off += 3072;
  off += 16;                                                      // guard pad
  float* bufA   = ws + off; off += 13778944;
  off += 16;                                                      // guard pad
  float* bufB   = ws + off; off += 23887872;
  off += 16;
  (void)ws_size; (void)in_sizes; (void)n_in; (void)out_size;

  // phase aliases (lifetimes disjoint, single-stream ordered)
  _Float16* s1h = (_Float16*)bufA;           // [B,56,56,16] fp16 NHWC
  _Float16* c1h = (_Float16*)bufB;           // [B,56,56,16] fp16 NHWC
  float* s2out  = bufB + 16000000;           // [B,28,28,32] fp32 NHWC
  _Float16* p1h = (_Float16*)bufA;           // [B,55,55,16] fp16 NHWC (after scout2)
  float* c2out  = bufB;                      // [B,28,28,32] fp32 NHWC
  _Float16* P2 = (_Float16*)(bufB + 8000000);
  _Float16* C3 = (_Float16*)bufA;
  float* c4out = bufB;                       // [B,27,27,128] fp32 NHWC

  // head-phase aliases in bufB (valid after papool2_k)
  unsigned short* ub = (unsigned short*)bufB;
  size_t uo = 0;
  unsigned short* ewp1h = ub + uo; uo += 3538944;
  unsigned short* ewp1l = ub + uo; uo += 3538944;
  unsigned short* ewp2h = ub + uo; uo += 1572864;
  unsigned short* ewp2l = ub + uo; uo += 1572864;
  unsigned short* ewp3h = ub + uo; uo += 786432;
  unsigned short* ewp3l = ub + uo; uo += 786432;
  unsigned short* fh    = ub + uo; uo += 294912;
  unsigned short* fl    = ub + uo; uo += 294912;
  unsigned short* h1h   = ub + uo; uo += 786432;
  unsigned short* h1l   = ub + uo; uo += 786432;
  unsigned short* h2h   = ub + uo; uo += 393216;
  unsigned short* h2l   = ub + uo; uo += 393216;

  dim3 blk(256);

  // ---- weight prep ----
  wpackM_k<32,64>  <<<dim3(72),  blk, 0, stream>>>(tw3, wpk3);
  wpackM_k<64,128> <<<dim3(288), blk, 0, stream>>>(tw4, wpk4);
  wpackS_k<32,5><<<dim3(60), blk, 0, stream>>>(tw2, wp2);
  wpackS_k<32,3><<<dim3(24), blk, 0, stream>>>(sw2, wps2);
  wpackF_k<<<dim3(24), blk, 0, stream>>>(sw1, tw1, wpf);

  // ---- fused scout1 + conv1 -> fp16 NHWC ----
  fusedM_k<<<dim3(BATCH*28), blk, 0, stream>>>(
      x, wpf, sb1, tb1, bn1g, bn1b, bn1m, bn1v, s1h, c1h);

  // ---- scout2 (fp16 NHWC in) + gate ----
  convS_k<32,3,1,56,56,1><<<dim3(BATCH*28), blk, 0, stream>>>(
      s1h, wps2, sb2, bn2g, bn2b, bn2m, bn2v, s2out);
  gate_k<<<dim3(256), blk, 0, stream>>>(s2out, cw, cb, comb);

  // ---- pool1 (fp16 NHWC) -> conv2 ----
  poolh_k<<<dim3((BATCH*55*55*2 + 255)/256), blk, 0, stream>>>(c1h, p1h);
  convS_k<32,5,2,55,55,0><<<dim3(BATCH*28), blk, 0, stream>>>(
      p1h, wp2, tb2, nullptr, nullptr, nullptr, nullptr, c2out);

  // ---- pool2 -> padded NHWC fp16 ----
  hipMemsetAsync(P2, 0, (size_t)6889472 * 2, stream);
  pool2n_k<<<dim3((BATCH*27*27*32 + 255)/256), blk, 0, stream>>>(c2out, P2);

  // ---- conv3 (MFMA fp16) -> padded NHWC fp16 ----
  hipMemsetAsync(C3, 0, (size_t)13778944 * 2, stream);
  convM_k<32,64,0><<<dim3(BATCH*14), blk, 0, stream>>>(
      P2, wpk3, tb3, C3, nullptr);

  // ---- conv4 (MFMA fp16) -> fp32 NHWC [B,27,27,128] ----
  convM_k<64,128,1><<<dim3(BATCH*14), blk, 0, stream>>>(
      C3, wpk4, tb4, nullptr, c4out);

  papool2_k<<<dim3(BATCH), blk, 0, stream>>>(c4out, flat);

  // ---- MoE head: pack weights + split A, then 3 MFMA GEMMs (split-bf16) ----
  wpackG_k<1152><<<dim3(4608,3), blk, 0, stream>>>(ew1, 1024, ewp1h, ewp1l);
  wpackG_k<1024><<<dim3(2048,3), blk, 0, stream>>>(ew2,  512, ewp2h, ewp2l);
  wpackG_k< 512><<<dim3(1024,3), blk, 0, stream>>>(ew3,  512, ewp3h, ewp3l);
  asplit_k<<<dim3(1152), blk, 0, stream>>>(flat, fh, fl, BATCH*1152);

  gemmM_k<1152,1,0><<<dim3(8,16,3), blk, 0, stream>>>(
      fh, fl, 0L, ewp1h, ewp1l, eb1, 1024, h1h, h1l, nullptr);
  gemmM_k<1024,1,0><<<dim3(8,8,3), blk, 0, stream>>>(
      h1h, h1l, 256L*1024, ewp2h, ewp2l, eb2, 512, h2h, h2l, nullptr);
  gemmM_k< 512,0,1><<<dim3(8,8,3), blk, 0, stream>>>(
      h2h, h2l, 256L*512, ewp3h, ewp3l, eb3, 512, nullptr, nullptr, h3);

  comb_k<<<dim3(512), blk, 0, stream>>>(h3, comb, out);
}

// Round 14
// 343.972 us; speedup vs baseline: 1.9266x; 1.0374x over previous
//
#include <hip/hip_runtime.h>

#define DEV static __device__ __forceinline__

constexpr int BATCH = 256;

DEV float leakyf(float x){ return x > 0.f ? x : 0.2f * x; }

typedef short bf16x8 __attribute__((ext_vector_type(8)));
typedef _Float16 f16x8 __attribute__((ext_vector_type(8)));
typedef float f32x4 __attribute__((ext_vector_type(4)));

DEV unsigned short f2bf(float v){
  union { float f; unsigned u; } x; x.f = v;
  unsigned r = x.u + 0x7fffu + ((x.u >> 16) & 1u);
  return (unsigned short)(r >> 16);
}
DEV float bf2f(unsigned short b){
  union { unsigned u; float f; } x; x.u = ((unsigned)b) << 16;
  return x.f;
}

// ------- pack OIHW conv weights into MFMA B-fragment order, single fp16 -----
template<int IC,int OC>
__global__ __launch_bounds__(256) void wpackM_k(const float* __restrict__ w,
    _Float16* __restrict__ wp){
  constexpr int S = IC/32, F = OC/16;
  int i = blockIdx.x*256 + threadIdx.x;
  if (i >= 9*S*F*512) return;
  int j = i & 7, L = (i >> 3) & 63, rest = i >> 9;
  int f = rest % F; int q2 = rest / F; int s = q2 % S; int t = q2 / S;
  int oc = f*16 + (L & 15), ic = s*32 + (L >> 4)*8 + j;
  wp[i] = (_Float16)w[((size_t)oc*IC + ic)*9 + t];
}

// ------- pack strided-conv weights (IC=16), single fp16 ---------------------
template<int OC,int K>
__global__ __launch_bounds__(256) void wpackS_k(const float* __restrict__ w,
    _Float16* __restrict__ wp){
  constexpr int F = OC/16, KWP = (K+1)/2;
  int i = blockIdx.x*256 + threadIdx.x;
  if (i >= K*KWP*F*512) return;
  int j = i & 7, L = (i >> 3) & 63, rest = i >> 9;
  int f = rest % F, s = rest / F;
  int kh = s / KWP, kwp = s % KWP;
  int k = (L >> 4)*8 + j;
  int kw = 2*kwp + (k >> 4), ic = k & 15;
  int oc = f*16 + (L & 15);
  float v = (kw < K) ? w[((size_t)(oc*16 + ic)*K + kh)*K + kw] : 0.f;
  wp[i] = (_Float16)v;
}

// ------- pack scout1(k7) + conv1(k3) weights, space-to-depth, single fp16 ---
__global__ __launch_bounds__(256) void wpackF_k(const float* __restrict__ sw1,
    const float* __restrict__ tw1, _Float16* __restrict__ wp){
  int i = blockIdx.x*256 + threadIdx.x;
  if (i >= 6*2*512) return;
  int j = i & 7, L = (i >> 3) & 63, rest = i >> 9;
  int nf = rest & 1, s = rest >> 1;
  int k = s*32 + (L >> 4)*8 + j;
  int oc = L & 15;
  int t = k / 48, c = k % 48;
  int dr = (t >> 1) - 1, dc = (t & 1) - 1;
  int ic = c >> 4, pr = (c >> 2) & 3, pc = c & 3;
  float v = 0.f;
  if (nf == 0){
    int kh = 4*dr + pr + 3, kw = 4*dc + pc + 3;
    if (kh >= 0 && kh < 7 && kw >= 0 && kw < 7) v = sw1[((oc*3 + ic)*7 + kh)*7 + kw];
  } else {
    int kh = 4*dr + pr + 1, kw = 4*dc + pc + 1;
    if (kh >= 0 && kh < 3 && kw >= 0 && kw < 3) v = tw1[((oc*3 + ic)*3 + kh)*3 + kw];
  }
  wp[i] = (_Float16)v;
}

// ------- pack expert GEMM weights W[e][N][K] into frag order, bf16 hi/lo ----
template<int KTOT>
__global__ __launch_bounds__(256) void wpackG_k(const float* __restrict__ w, int N,
    unsigned short* __restrict__ hi, unsigned short* __restrict__ lo){
  const int NF = N >> 4, KT = KTOT >> 5;
  const int total = NF * KT * 512;
  const int e = blockIdx.y;
  w  += (size_t)e * N * KTOT;
  hi += (size_t)e * total; lo += (size_t)e * total;
  int i = blockIdx.x*256 + threadIdx.x;
  if (i >= total) return;
  int j = i & 7, L = (i >> 3) & 63, rest = i >> 9;
  int nf = rest % NF, t = rest / NF;
  int n = nf*16 + (L & 15), k = t*32 + (L >> 4)*8 + j;
  float v = w[(size_t)n*KTOT + k];
  unsigned short h = f2bf(v);
  hi[i] = h; lo[i] = f2bf(v - bf2f(h));
}

// ------- split fp32 array into bf16 hi/lo ----------------------------------
__global__ __launch_bounds__(256) void asplit_k(const float* __restrict__ in,
    unsigned short* __restrict__ hi, unsigned short* __restrict__ lo, int nelem){
  int i = blockIdx.x*256 + threadIdx.x;
  if (i >= nelem) return;
  float v = in[i];
  unsigned short h = f2bf(v);
  hi[i] = h; lo[i] = f2bf(v - bf2f(h));
}

// ---------- fused scout1+conv1, space-to-depth MFMA fp16, 4 rows/block ------
// LDS: [5 rowgrp][58 col][64ch-pad] fp16, XOR ((col&7)<<4). One barrier:
// zero writes (col0 + OOB rowgrp0) are disjoint from stage writes.
__global__ __launch_bounds__(256) void fusedM_k(
    const float* __restrict__ x,
    const _Float16* __restrict__ W,
    const float* __restrict__ sb, const float* __restrict__ cb_,
    const float* __restrict__ g, const float* __restrict__ bt,
    const float* __restrict__ mn, const float* __restrict__ vr,
    _Float16* __restrict__ s1out, _Float16* __restrict__ c1out){
  __shared__ __align__(16) _Float16 Ah[5*58*64];
  const int tid = threadIdx.x;
  const int n = blockIdx.x / 14, oh0 = (blockIdx.x % 14) * 4;

  // zero col0 slots (left pad) for all 5 rowgrps: 40 x 16B
  if (tid < 40){
    int rr = tid >> 3, q = tid & 7;
    *(int4*)((char*)Ah + ((rr*58) << 7) + q*16) = (int4){0,0,0,0};
  }
  // first row-quad of each image: rowgrp 0 has no valid input rows
  if (oh0 == 0){
    for (int i = tid; i < 464; i += 256)
      ((int4*)Ah)[i] = (int4){0,0,0,0};
  }

  // stage 20 x-rows x 3 ic x 224 cols (coalesced float4), space-to-depth
  for (int i = tid; i < 3360; i += 256){
    int m = i % 56; int rc = i / 56;
    int ic = rc % 3, ridx = rc / 3;
    int ih = 4*oh0 - 4 + ridx;
    if (ih < 0) continue;              // ih <= 223 always (oh0 <= 52)
    float4 v = *(const float4*)(x + ((size_t)(n*3 + ic)*224 + ih)*224 + 4*m);
    int rr = ridx >> 2, pr = ridx & 3, cc = m + 1;
    int boff = (((rr*58 + cc) << 7) + ic*32 + pr*8) ^ ((cc & 7) << 4);
    _Float16 h4[4] = {(_Float16)v.x, (_Float16)v.y, (_Float16)v.z, (_Float16)v.w};
    *(unsigned long long*)((char*)Ah + boff) = *(unsigned long long*)h4;
  }
  __syncthreads();

  const int wid = tid >> 6, lane = tid & 63;   // wid = output row offset
  const int kg8 = (lane >> 4) * 8;
  f32x4 acc[4][2];
  #pragma unroll
  for (int mi = 0; mi < 4; ++mi)
    #pragma unroll
    for (int nf = 0; nf < 2; ++nf) acc[mi][nf] = (f32x4){0.f,0.f,0.f,0.f};

  #pragma unroll
  for (int s = 0; s < 6; ++s){
    const int kk = s*32 + kg8;
    const int t = kk / 48, c0 = kk - t*48;
    const int ra = t >> 1, ca = t & 1;
    const int trow = wid + ra;                 // tile rowgrp
    f16x8 ah[4];
    #pragma unroll
    for (int mi = 0; mi < 4; ++mi){
      const int ow = mi*16 + (lane & 15);
      const int owc = ow > 55 ? 55 : ow;
      const int col = owc + ca;
      const int bidx = (((trow*58 + col) << 7) + c0*2) ^ ((col & 7) << 4);
      ah[mi] = *(const f16x8*)((const char*)Ah + bidx);
    }
    #pragma unroll
    for (int nf = 0; nf < 2; ++nf){
      const f16x8 bw = *(const f16x8*)(W + (s*2 + nf)*512 + lane*8);
      #pragma unroll
      for (int mi = 0; mi < 4; ++mi)
        acc[mi][nf] = __builtin_amdgcn_mfma_f32_16x16x32_f16(ah[mi], bw, acc[mi][nf], 0,0,0);
    }
  }

  const int oc = lane & 15;
  const float sbv = sb[oc];
  const float scv = g[oc] * __frsqrt_rn(vr[oc] + 1e-5f);
  const float mnv = mn[oc], btv = bt[oc], cbv = cb_[oc];
  const int row = oh0 + wid;
  #pragma unroll
  for (int mi = 0; mi < 4; ++mi){
    const int owb = mi*16 + (lane >> 4)*4;
    #pragma unroll
    for (int r = 0; r < 4; ++r){
      const int ow = owb + r;
      if (ow >= 56) continue;
      float vs = acc[mi][0][r] + sbv;
      vs = fmaxf((vs - mnv)*scv + btv, 0.f);
      const size_t o = (((size_t)n*56 + row)*56 + ow)*16 + oc;
      s1out[o] = (_Float16)vs;
      c1out[o] = (_Float16)leakyf(acc[mi][1][r] + cbv);
    }
  }
}

// ---------------- strided (S=2) MFMA conv, fp16 NHWC input [B,IH,IW,16] -----
// OUT16: write fp16 NHWC (safe pre-maxpool); else fp32 NHWC
template<int OC,int K,int P,int IH,int IW,int ACT,bool OUT16>
__global__ __launch_bounds__(256) void convS_k(
    const _Float16* __restrict__ in,
    const _Float16* __restrict__ W,
    const float* __restrict__ bias,
    const float* __restrict__ bng, const float* __restrict__ bnb,
    const float* __restrict__ bnm, const float* __restrict__ bnv,
    float* __restrict__ outF, _Float16* __restrict__ outH){
  constexpr int F = OC/16, KWP = (K+1)/2;
  __shared__ __align__(16) _Float16 A[K*60*16];

  const int tid = threadIdx.x;
  const int n = blockIdx.x / 28, oh = blockIdx.x % 28;

  for (int i = tid; i < K*60*2; i += 256){
    int half = i & 1; int p = i >> 1;
    int c = p % 60; int r = p / 60;
    int ih = 2*oh - P + r, iw = c - P;
    int4 v = {0,0,0,0};
    if (ih >= 0 && ih < IH && iw >= 0 && iw < IW)
      v = *(const int4*)(in + (((size_t)n*IH + ih)*IW + iw)*16 + half*8);
    int byte = ((r*60 + c)*32 + half*16) ^ (((c>>1)&7) << 4);
    *(int4*)((char*)A + byte) = v;
  }
  __syncthreads();

  const int wid = tid >> 6, lane = tid & 63;
  const int fsel = wid & 1, mb = wid >> 1;
  const int ow_l = min(mb*16 + (lane & 15), 27);
  const int ic0b = ((lane >> 4) & 1) * 16;
  const int kwo  = (lane >> 4) >> 1;

  f32x4 acc = {0.f,0.f,0.f,0.f};
  #pragma unroll
  for (int kh = 0; kh < K; ++kh){
    #pragma unroll
    for (int kwp = 0; kwp < KWP; ++kwp){
      const int kw = 2*kwp + kwo;
      const int c = 2*ow_l + kw;
      int byte = ((kh*60 + c)*32 + ic0b) ^ (((c>>1)&7) << 4);
      f16x8 a = *(const f16x8*)((const char*)A + byte);
      const int s = kh*KWP + kwp;
      const f16x8 b = *(const f16x8*)(W + (s*F + fsel)*512 + lane*8);
      acc = __builtin_amdgcn_mfma_f32_16x16x32_f16(a, b, acc, 0,0,0);
    }
  }

  const int oc = fsel*16 + (lane & 15);
  float bv = bias[oc], sc = 1.f, mm = 0.f, bb = 0.f;
  if (ACT == 1){
    sc = bng[oc] * __frsqrt_rn(bnv[oc] + 1e-5f);
    mm = bnm[oc]; bb = bnb[oc];
  }
  #pragma unroll
  for (int r = 0; r < 4; ++r){
    const int ow = mb*16 + (lane >> 4)*4 + r;
    if (ow >= 28) continue;
    float v = acc[r] + bv;
    if (ACT == 1) v = fmaxf((v - mm)*sc + bb, 0.f);
    else          v = leakyf(v);
    const size_t o = (((size_t)n*28 + oh)*28 + ow)*OC + oc;
    if (OUT16) outH[o] = (_Float16)v;
    else       outF[o] = v;
  }
}

// ---------------- MFMA single-fp16 3x3 s1 p1 conv on 27x27, padded NHWC -----
// OUTM 0: leaky fp16 padded NHWC [29,29] ; OUTM 1: leaky fp16 NHWC [27,27]
template<int IC,int OC,int OUTM>
__global__ __launch_bounds__(256) void convM_k(
    const _Float16* __restrict__ Ag,
    const _Float16* __restrict__ W,
    const float* __restrict__ bias,
    _Float16* __restrict__ OutPad, _Float16* __restrict__ OutNP)
{
  constexpr int S = IC/32, FTOT = OC/16, FW = FTOT/2;
  constexpr int ICB = IC*2, ICG = ICB/16;
  __shared__ __align__(16) char A[4*34*ICB];

  const int tid = threadIdx.x;
  const int bx = blockIdx.x;
  const int n = bx / 14, pr = bx % 14;
  const int oh0 = pr * 2;

  const size_t gbase = ((size_t)n*29) * 29 * IC;
  for (int g = tid; g < 4*34*ICG; g += 256){
    int r = g / (34*ICG);
    int rem = g - r*(34*ICG);
    int c = rem / ICG, q = rem - c*ICG;
    int rp = oh0 + r;
    int4 v = {0,0,0,0};
    if (rp <= 28 && c < 29){
      size_t e = gbase + ((size_t)rp*29 + c)*IC + q*8;
      v = *(const int4*)(Ag + e);
    }
    int off = (r*34 + c)*ICB + q*16;
    int swz = off ^ ((c & 7) << 4);
    *(int4*)(A + swz) = v;
  }
  __syncthreads();

  const int wid = tid >> 6, lane = tid & 63;
  const int rsel = wid & 1, ocq = wid >> 1;
  const int c0 = lane & 15, kg = (lane >> 4) * 16;
  const int colb0 = c0*ICB + kg, colb1 = (16 + c0)*ICB + kg;
  int msk[3];
  #pragma unroll
  for (int kw = 0; kw < 3; ++kw) msk[kw] = ((c0 + kw) & 7) << 4;

  f32x4 acc[2][FW];
  #pragma unroll
  for (int m = 0; m < 2; ++m)
    #pragma unroll
    for (int f = 0; f < FW; ++f) acc[m][f] = (f32x4){0.f,0.f,0.f,0.f};

  #pragma unroll
  for (int kh = 0; kh < 3; ++kh){
    #pragma unroll
    for (int kw = 0; kw < 3; ++kw){
      #pragma unroll
      for (int s = 0; s < S; ++s){
        const int fr0 = (((kh*3 + kw)*S + s)*FTOT + ocq*FW) * 512 + lane*8;
        f16x8 b[FW];
        #pragma unroll
        for (int f = 0; f < FW; ++f)
          b[f] = *(const f16x8*)(W + fr0 + f*512);
        const int base = ((rsel + kh)*34 + kw)*ICB + s*64;
        const int o0 = (base + colb0) ^ msk[kw];
        const int o1 = (base + colb1) ^ msk[kw];
        f16x8 a0 = *(const f16x8*)(A + o0);
        f16x8 a1 = *(const f16x8*)(A + o1);
        #pragma unroll
        for (int f = 0; f < FW; ++f){
          acc[0][f] = __builtin_amdgcn_mfma_f32_16x16x32_f16(a0, b[f], acc[0][f], 0,0,0);
          acc[1][f] = __builtin_amdgcn_mfma_f32_16x16x32_f16(a1, b[f], acc[1][f], 0,0,0);
        }
      }
    }
  }

  const int orow = oh0 + rsel;
  if (orow >= 27) return;
  #pragma unroll
  for (int f = 0; f < FW; ++f){
    const int oc = (ocq*FW + f)*16 + c0;
    const float bv = bias[oc];
    #pragma unroll
    for (int m = 0; m < 2; ++m){
      #pragma unroll
      for (int r = 0; r < 4; ++r){
        const int ow = m*16 + (lane >> 4)*4 + r;
        if (ow >= 27) continue;
        float v = leakyf(acc[m][f][r] + bv);
        if (OUTM == 0){
          OutPad[(((size_t)n*29 + orow+1)*29 + ow+1)*OC + oc] = (_Float16)v;
        } else {
          OutNP[(((size_t)n*27 + orow)*27 + ow)*OC + oc] = (_Float16)v;
        }
      }
    }
  }
}

// ---------------- split-bf16 MFMA GEMM for MoE head -------------------------
template<int KTOT,int ACT,int OUTM>
__global__ __launch_bounds__(256) void gemmM_k(
    const unsigned short* __restrict__ Ah, const unsigned short* __restrict__ Al,
    long strideA,
    const unsigned short* __restrict__ Wh, const unsigned short* __restrict__ Wl,
    const float* __restrict__ bias, int N,
    unsigned short* __restrict__ OutH, unsigned short* __restrict__ OutL,
    float* __restrict__ OutF){
  const int e = blockIdx.z;
  Ah += (size_t)e * strideA; Al += (size_t)e * strideA;
  const int NF = N >> 4, KT = KTOT >> 5;
  const size_t wb = (size_t)e * NF * KT * 512;
  Wh += wb; Wl += wb;
  const float* bs = bias + (size_t)e * N;
  const size_t ob = (size_t)e * 256 * N;

  const int tid = threadIdx.x, wid = tid >> 6, lane = tid & 63;
  const int mblk = blockIdx.x * 32;
  const int nf = blockIdx.y * 4 + wid;
  const int r0 = mblk + (lane & 15);
  const int kof = (lane >> 4) * 8;

  f32x4 acc0 = {0,0,0,0}, acc1 = {0,0,0,0};
  for (int t = 0; t < KT; ++t){
    const int k = t*32 + kof;
    bf16x8 ah0 = *(const bf16x8*)(Ah + (size_t)r0*KTOT + k);
    bf16x8 al0 = *(const bf16x8*)(Al + (size_t)r0*KTOT + k);
    bf16x8 ah1 = *(const bf16x8*)(Ah + (size_t)(r0+16)*KTOT + k);
    bf16x8 al1 = *(const bf16x8*)(Al + (size_t)(r0+16)*KTOT + k);
    const size_t fb = ((size_t)t*NF + nf)*512 + lane*8;
    bf16x8 bh = *(const bf16x8*)(Wh + fb);
    bf16x8 bl = *(const bf16x8*)(Wl + fb);
    acc0 = __builtin_amdgcn_mfma_f32_16x16x32_bf16(ah0, bh, acc0, 0,0,0);
    acc0 = __builtin_amdgcn_mfma_f32_16x16x32_bf16(ah0, bl, acc0, 0,0,0);
    acc0 = __builtin_amdgcn_mfma_f32_16x16x32_bf16(al0, bh, acc0, 0,0,0);
    acc1 = __builtin_amdgcn_mfma_f32_16x16x32_bf16(ah1, bh, acc1, 0,0,0);
    acc1 = __builtin_amdgcn_mfma_f32_16x16x32_bf16(ah1, bl, acc1, 0,0,0);
    acc1 = __builtin_amdgcn_mfma_f32_16x16x32_bf16(al1, bh, acc1, 0,0,0);
  }
  const int n = nf*16 + (lane & 15);
  const float bv = bs[n];
  #pragma unroll
  for (int mi = 0; mi < 2; ++mi){
    f32x4 a = mi ? acc1 : acc0;
    #pragma unroll
    for (int r = 0; r < 4; ++r){
      const int m = mblk + mi*16 + (lane >> 4)*4 + r;
      float v = a[r] + bv;
      if (ACT == 1) v = leakyf(v);
      const size_t o = ob + (size_t)m*N + n;
      if (OUTM == 0){
        unsigned short h = f2bf(v);
        OutH[o] = h; OutL[o] = f2bf(v - bf2f(h));
      } else {
        OutF[o] = v;
      }
    }
  }
}

// ------ fp16 NHWC 2x2 s1 maxpool: [B,56,56,16] -> [B,55,55,16] --------------
__global__ __launch_bounds__(256) void poolh_k(const _Float16* __restrict__ in,
                                               _Float16* __restrict__ out){
  int idx = blockIdx.x * 256 + threadIdx.x;
  if (idx >= BATCH * 55 * 55 * 2) return;
  int half = idx & 1; int p = idx >> 1;
  int ow = p % 55; int t = p / 55; int oh = t % 55; int n = t / 55;
  const _Float16* q = in + (((size_t)n*56 + oh)*56 + ow)*16 + half*8;
  f16x8 a = *(const f16x8*)q;
  f16x8 b = *(const f16x8*)(q + 16);
  f16x8 c = *(const f16x8*)(q + 56*16);
  f16x8 d = *(const f16x8*)(q + 57*16);
  f16x8 r;
  #pragma unroll
  for (int j = 0; j < 8; ++j){
    float m = fmaxf(fmaxf((float)a[j], (float)b[j]), fmaxf((float)c[j], (float)d[j]));
    r[j] = (_Float16)m;
  }
  *(f16x8*)(out + (size_t)p*16 + half*8) = r;
}

// ------- pool2: fp16 NHWC [B,28,28,32] -> padded NHWC fp16 [B,29,29,32] -----
__global__ __launch_bounds__(256) void pool2n_k(const _Float16* __restrict__ in,
    _Float16* __restrict__ o16){
  int idx = blockIdx.x*256 + threadIdx.x;
  if (idx >= BATCH*27*27*32) return;
  int ic = idx & 31; int p = idx >> 5;
  int ow = p % 27; int t = p / 27; int oh = t % 27; int n = t / 27;
  const _Float16* b = in + (((size_t)n*28 + oh)*28 + ow)*32 + ic;
  float v = fmaxf(fmaxf((float)b[0], (float)b[32]),
                  fmaxf((float)b[28*32], (float)b[29*32]));
  o16[(((size_t)n*29 + oh+1)*29 + ow+1)*32 + ic] = (_Float16)v;
}

// ---------------- scout gate (fp32 NHWC input [B,28,28,32]) ----------------
__global__ __launch_bounds__(256) void gate_k(const float* __restrict__ s2,
                                              const float* __restrict__ cw,
                                              const float* __restrict__ cb,
                                              float* __restrict__ comb){
  int n = blockIdx.x;
  int tid = threadIdx.x;
  int c = tid & 31;
  int sub = tid >> 5;
  const float* p = s2 + (size_t)n * 784 * 32 + c;
  float s = 0.f;
  for (int i = sub * 98; i < sub * 98 + 98; ++i) s += p[(size_t)i * 32];
  __shared__ float red[32][8];
  red[c][sub] = s;
  __syncthreads();
  if (tid < 32){
    float tot = 0.f;
    #pragma unroll
    for (int k = 0; k < 8; ++k) tot += red[tid][k];
    red[tid][0] = tot / 784.f;
  }
  __syncthreads();
  if (tid == 0){
    float lg[3];
    for (int e = 0; e < 3; ++e){
      float a = cb[e];
      for (int c2 = 0; c2 < 32; ++c2) a += red[c2][0] * cw[e * 32 + c2];
      lg[e] = a;
    }
    float m = fmaxf(lg[0], fmaxf(lg[1], lg[2]));
    float ex[3], sum = 0.f;
    for (int e = 0; e < 3; ++e){ ex[e] = expf(lg[e] - m); sum += ex[e]; }
    float pr[3];
    for (int e = 0; e < 3; ++e) pr[e] = ex[e] / sum;
    int i1 = 0;
    if (pr[1] > pr[0]) i1 = 1;
    if (pr[2] > pr[i1]) i1 = 2;
    int i2 = -1;
    for (int e = 0; e < 3; ++e){
      if (e == i1) continue;
      if (i2 < 0 || pr[e] > pr[i2]) i2 = e;
    }
    float s12 = pr[i1] + pr[i2] + 1e-6f;
    float cmb[3] = {0.f, 0.f, 0.f};
    cmb[i1] = pr[i1] / s12;
    cmb[i2] = pr[i2] / s12;
    comb[n * 3 + 0] = cmb[0];
    comb[n * 3 + 1] = cmb[1];
    comb[n * 3 + 2] = cmb[2];
  }
}

// ------ channel-parallel fused maxpool2s1(27->26) + adaptive avg(26->3) -----
// fp16 NHWC input [B,27,27,128]; fp32 accumulation
__global__ __launch_bounds__(256) void papool2_k(const _Float16* __restrict__ in,
                                                 float* __restrict__ flat){
  __shared__ float red[2][128][9];
  const int n = blockIdx.x;
  const int tid = threadIdx.x;
  const int h = tid >> 7, c = tid & 127;
  const _Float16* p = in + (size_t)n * 729 * 128 + c;

  float sum[9];
  #pragma unroll
  for (int j = 0; j < 9; ++j) sum[j] = 0.f;

  float prev[27], cur[27];
  const int r0 = h * 13;
  #pragma unroll
  for (int rr = 0; rr < 14; ++rr){
    const int r = r0 + rr;
    #pragma unroll
    for (int cc = 0; cc < 27; ++cc)
      cur[cc] = (float)p[(size_t)(r*27 + cc) * 128];
    if (rr > 0){
      const int pr = r - 1;
      const bool b0 = (pr < 9), b1 = (pr >= 8) && (pr < 18), b2 = (pr >= 17);
      #pragma unroll
      for (int cc = 0; cc < 26; ++cc){
        float v = fmaxf(fmaxf(prev[cc], prev[cc+1]), fmaxf(cur[cc], cur[cc+1]));
        if (b0){
          if (cc < 9)             sum[0] += v;
          if (cc >= 8 && cc < 18) sum[1] += v;
          if (cc >= 17)           sum[2] += v;
        }
        if (b1){
          if (cc < 9)             sum[3] += v;
          if (cc >= 8 && cc < 18) sum[4] += v;
          if (cc >= 17)           sum[5] += v;
        }
        if (b2){
          if (cc < 9)             sum[6] += v;
          if (cc >= 8 && cc < 18) sum[7] += v;
          if (cc >= 17)           sum[8] += v;
        }
      }
    }
    #pragma unroll
    for (int cc = 0; cc < 27; ++cc) prev[cc] = cur[cc];
  }

  #pragma unroll
  for (int j = 0; j < 9; ++j) red[h][c][j] = sum[j];
  __syncthreads();

  if (tid < 128){
    const float rcp[9] = {1.f/81, 1.f/90, 1.f/81, 1.f/90, 1.f/100, 1.f/90,
                          1.f/81, 1.f/90, 1.f/81};
    float* o = flat + (size_t)n * 1152 + tid * 9;
    #pragma unroll
    for (int j = 0; j < 9; ++j)
      o[j] = (red[0][tid][j] + red[1][tid][j]) * rcp[j];
  }
}

// ---------------- final gated combine ----------------
__global__ __launch_bounds__(256) void comb_k(const float* __restrict__ h3,
                                              const float* __restrict__ comb,
                                              float* __restrict__ out){
  int idx = blockIdx.x * 256 + threadIdx.x;
  if (idx >= BATCH * 512) return;
  int o = idx % 512, b = idx / 512;
  float s = 0.f;
  #pragma unroll
  for (int e = 0; e < 3; ++e)
    s += comb[b * 3 + e] * h3[((size_t)e * BATCH + b) * 512 + o];
  out[idx] = s;
}

// ============================================================================
extern "C" void kernel_launch(void* const* d_in, const int* in_sizes, int n_in,
                              void* d_out, int out_size, void* d_ws, size_t ws_size,
                              hipStream_t stream){
  const float* x    = (const float*)d_in[0];
  const float* tw1  = (const float*)d_in[1];  const float* tb1 = (const float*)d_in[2];
  const float* tw2  = (const float*)d_in[3];  const float* tb2 = (const float*)d_in[4];
  const float* tw3  = (const float*)d_in[5];  const float* tb3 = (const float*)d_in[6];
  const float* tw4  = (const float*)d_in[7];  const float* tb4 = (const float*)d_in[8];
  const float* sw1  = (const float*)d_in[9];  const float* sb1 = (const float*)d_in[10];
  const float* bn1g = (const float*)d_in[11]; const float* bn1b = (const float*)d_in[12];
  const float* bn1m = (const float*)d_in[13]; const float* bn1v = (const float*)d_in[14];
  const float* sw2  = (const float*)d_in[15]; const float* sb2 = (const float*)d_in[16];
  const float* bn2g = (const float*)d_in[17]; const float* bn2b = (const float*)d_in[18];
  const float* bn2m = (const float*)d_in[19]; const float* bn2v = (const float*)d_in[20];
  const float* cw   = (const float*)d_in[21]; const float* cb  = (const float*)d_in[22];
  const float* ew1  = (const float*)d_in[23]; const float* eb1 = (const float*)d_in[24];
  const float* ew2  = (const float*)d_in[25]; const float* eb2 = (const float*)d_in[26];
  const float* ew3  = (const float*)d_in[27]; const float* eb3 = (const float*)d_in[28];
  float* out = (float*)d_out;

  // ---- workspace layout (floats), ~157 MB ----
  float* ws = (float*)d_ws;
  size_t off = 0;
  float* comb   = ws + off; off += 768;
  float* flat   = ws + off; off += (size_t)BATCH * 1152;
  float* h3     = ws + off; off += (size_t)BATCH * 3 * 512;
  _Float16* wpk3 = (_Float16*)(ws + off); off += 9216;
  _Float16* wpk4 = (_Float16*)(ws + off); off += 36864;
  _Float16* wp2  = (_Float16*)(ws + off); off += 7680;
  _Float16* wps2 = (_Float16*)(ws + off); off += 3072;
  _Float16* wpf  = (_Float16*)(ws + off); off += 3072;
  off += 16;                                                      // guard pad
  float* bufA   = ws + off; off += 13778944;
  off += 16;                                                      // guard pad
  float* bufB   = ws + off; off += 23887872;
  off += 16;
  (void)ws_size; (void)in_sizes; (void)n_in; (void)out_size;

  // phase aliases (lifetimes disjoint, single-stream ordered)
  _Float16* s1h = (_Float16*)bufA;           // [B,56,56,16] fp16 NHWC
  _Float16* c1h = (_Float16*)bufB;           // [B,56,56,16] fp16 NHWC
  float* s2out  = bufB + 16000000;           // [B,28,28,32] fp32 NHWC (gate path)
  _Float16* p1h = (_Float16*)bufA;           // [B,55,55,16] fp16 NHWC
  _Float16* c2h = (_Float16*)bufB;           // [B,28,28,32] fp16 NHWC
  _Float16* P2 = (_Float16*)(bufB + 8000000);
  _Float16* C3 = (_Float16*)bufA;
  _Float16* c4h = (_Float16*)bufB;           // [B,27,27,128] fp16 NHWC

  // head-phase aliases in bufB (valid after papool2_k)
  unsigned short* ub = (unsigned short*)bufB;
  size_t uo = 0;
  unsigned short* ewp1h = ub + uo; uo += 3538944;
  unsigned short* ewp1l = ub + uo; uo += 3538944;
  unsigned short* ewp2h = ub + uo; uo += 1572864;
  unsigned short* ewp2l = ub + uo; uo += 1572864;
  unsigned short* ewp3h = ub + uo; uo += 786432;
  unsigned short* ewp3l = ub + uo; uo += 786432;
  unsigned short* fh    = ub + uo; uo += 294912;
  unsigned short* fl    = ub + uo; uo += 294912;
  unsigned short* h1h   = ub + uo; uo += 786432;
  unsigned short* h1l   = ub + uo; uo += 786432;
  unsigned short* h2h   = ub + uo; uo += 393216;
  unsigned short* h2l   = ub + uo; uo += 393216;

  dim3 blk(256);

  // ---- weight prep ----
  wpackM_k<32,64>  <<<dim3(72),  blk, 0, stream>>>(tw3, wpk3);
  wpackM_k<64,128> <<<dim3(288), blk, 0, stream>>>(tw4, wpk4);
  wpackS_k<32,5><<<dim3(60), blk, 0, stream>>>(tw2, wp2);
  wpackS_k<32,3><<<dim3(24), blk, 0, stream>>>(sw2, wps2);
  wpackF_k<<<dim3(24), blk, 0, stream>>>(sw1, tw1, wpf);

  // ---- fused scout1 + conv1 -> fp16 NHWC (4 rows/block) ----
  fusedM_k<<<dim3(BATCH*14), blk, 0, stream>>>(
      x, wpf, sb1, tb1, bn1g, bn1b, bn1m, bn1v, s1h, c1h);

  // ---- scout2 (fp32 out for gate) + gate ----
  convS_k<32,3,1,56,56,1,false><<<dim3(BATCH*28), blk, 0, stream>>>(
      s1h, wps2, sb2, bn2g, bn2b, bn2m, bn2v, s2out, nullptr);
  gate_k<<<dim3(256), blk, 0, stream>>>(s2out, cw, cb, comb);

  // ---- pool1 (fp16 NHWC) -> conv2 (fp16 out) ----
  poolh_k<<<dim3((BATCH*55*55*2 + 255)/256), blk, 0, stream>>>(c1h, p1h);
  convS_k<32,5,2,55,55,0,true><<<dim3(BATCH*28), blk, 0, stream>>>(
      p1h, wp2, tb2, nullptr, nullptr, nullptr, nullptr, nullptr, c2h);

  // ---- pool2 (fp16 in) -> padded NHWC fp16 ----
  hipMemsetAsync(P2, 0, (size_t)6889472 * 2, stream);
  pool2n_k<<<dim3((BATCH*27*27*32 + 255)/256), blk, 0, stream>>>(c2h, P2);

  // ---- conv3 (MFMA fp16) -> padded NHWC fp16 ----
  hipMemsetAsync(C3, 0, (size_t)13778944 * 2, stream);
  convM_k<32,64,0><<<dim3(BATCH*14), blk, 0, stream>>>(
      P2, wpk3, tb3, C3, nullptr);

  // ---- conv4 (MFMA fp16) -> fp16 NHWC [B,27,27,128] ----
  convM_k<64,128,1><<<dim3(BATCH*14), blk, 0, stream>>>(
      C3, wpk4, tb4, nullptr, c4h);

  papool2_k<<<dim3(BATCH), blk, 0, stream>>>(c4h, flat);

  // ---- MoE head: pack weights + split A, then 3 MFMA GEMMs (split-bf16) ----
  wpackG_k<1152><<<dim3(4608,3), blk, 0, stream>>>(ew1, 1024, ewp1h, ewp1l);
  wpackG_k<1024><<<dim3(2048,3), blk, 0, stream>>>(ew2,  512, ewp2h, ewp2l);
  wpackG_k< 512><<<dim3(1024,3), blk, 0, stream>>>(ew3,  512, ewp3h, ewp3l);
  asplit_k<<<dim3(1152), blk, 0, stream>>>(flat, fh, fl, BATCH*1152);

  gemmM_k<1152,1,0><<<dim3(8,16,3), blk, 0, stream>>>(
      fh, fl, 0L, ewp1h, ewp1l, eb1, 1024, h1h, h1l, nullptr);
  gemmM_k<1024,1,0><<<dim3(8,8,3), blk, 0, stream>>>(
      h1h, h1l, 256L*1024, ewp2h, ewp2l, eb2, 512, h2h, h2l, nullptr);
  gemmM_k< 512,0,1><<<dim3(8,8,3), blk, 0, stream>>>(
      h2h, h2l, 256L*512, ewp3h, ewp3l, eb3, 512, nullptr, nullptr, h3);

  comb_k<<<dim3(512), blk, 0, stream>>>(h3, comb, out);
}

// Round 15
// 308.588 us; speedup vs baseline: 2.1475x; 1.1147x over previous
//
#include <hip/hip_runtime.h>

#define DEV static __device__ __forceinline__

constexpr int BATCH = 256;

DEV float leakyf(float x){ return x > 0.f ? x : 0.2f * x; }

typedef _Float16 f16x8 __attribute__((ext_vector_type(8)));
typedef float f32x4 __attribute__((ext_vector_type(4)));

// ------- pack OIHW conv weights into MFMA B-fragment order, single fp16 -----
template<int IC,int OC>
__global__ __launch_bounds__(256) void wpackM_k(const float* __restrict__ w,
    _Float16* __restrict__ wp){
  constexpr int S = IC/32, F = OC/16;
  int i = blockIdx.x*256 + threadIdx.x;
  if (i >= 9*S*F*512) return;
  int j = i & 7, L = (i >> 3) & 63, rest = i >> 9;
  int f = rest % F; int q2 = rest / F; int s = q2 % S; int t = q2 / S;
  int oc = f*16 + (L & 15), ic = s*32 + (L >> 4)*8 + j;
  wp[i] = (_Float16)w[((size_t)oc*IC + ic)*9 + t];
}

// ------- pack strided-conv weights (IC=16), single fp16 ---------------------
template<int OC,int K>
__global__ __launch_bounds__(256) void wpackS_k(const float* __restrict__ w,
    _Float16* __restrict__ wp){
  constexpr int F = OC/16, KWP = (K+1)/2;
  int i = blockIdx.x*256 + threadIdx.x;
  if (i >= K*KWP*F*512) return;
  int j = i & 7, L = (i >> 3) & 63, rest = i >> 9;
  int f = rest % F, s = rest / F;
  int kh = s / KWP, kwp = s % KWP;
  int k = (L >> 4)*8 + j;
  int kw = 2*kwp + (k >> 4), ic = k & 15;
  int oc = f*16 + (L & 15);
  float v = (kw < K) ? w[((size_t)(oc*16 + ic)*K + kh)*K + kw] : 0.f;
  wp[i] = (_Float16)v;
}

// ------- pack scout1(k7) + conv1(k3) weights, space-to-depth, single fp16 ---
__global__ __launch_bounds__(256) void wpackF_k(const float* __restrict__ sw1,
    const float* __restrict__ tw1, _Float16* __restrict__ wp){
  int i = blockIdx.x*256 + threadIdx.x;
  if (i >= 6*2*512) return;
  int j = i & 7, L = (i >> 3) & 63, rest = i >> 9;
  int nf = rest & 1, s = rest >> 1;
  int k = s*32 + (L >> 4)*8 + j;
  int oc = L & 15;
  int t = k / 48, c = k % 48;
  int dr = (t >> 1) - 1, dc = (t & 1) - 1;
  int ic = c >> 4, pr = (c >> 2) & 3, pc = c & 3;
  float v = 0.f;
  if (nf == 0){
    int kh = 4*dr + pr + 3, kw = 4*dc + pc + 3;
    if (kh >= 0 && kh < 7 && kw >= 0 && kw < 7) v = sw1[((oc*3 + ic)*7 + kh)*7 + kw];
  } else {
    int kh = 4*dr + pr + 1, kw = 4*dc + pc + 1;
    if (kh >= 0 && kh < 3 && kw >= 0 && kw < 3) v = tw1[((oc*3 + ic)*3 + kh)*3 + kw];
  }
  wp[i] = (_Float16)v;
}

// ------- pack expert GEMM weights W[e][N][K] into frag order, single fp16 ---
template<int KTOT>
__global__ __launch_bounds__(256) void wpackGh_k(const float* __restrict__ w, int N,
    _Float16* __restrict__ wp){
  const int NF = N >> 4, KT = KTOT >> 5;
  const int total = NF * KT * 512;
  const int e = blockIdx.y;
  w  += (size_t)e * N * KTOT;
  wp += (size_t)e * total;
  int i = blockIdx.x*256 + threadIdx.x;
  if (i >= total) return;
  int j = i & 7, L = (i >> 3) & 63, rest = i >> 9;
  int nf = rest % NF, t = rest / NF;
  int n = nf*16 + (L & 15), k = t*32 + (L >> 4)*8 + j;
  wp[i] = (_Float16)w[(size_t)n*KTOT + k];
}

// ------- convert fp32 array to fp16 ----------------------------------------
__global__ __launch_bounds__(256) void acvt_k(const float* __restrict__ in,
    _Float16* __restrict__ o16, int nelem){
  int i = blockIdx.x*256 + threadIdx.x;
  if (i >= nelem) return;
  o16[i] = (_Float16)in[i];
}

// ---------- fused scout1+conv1, space-to-depth MFMA fp16 (2 rows/block) -----
__global__ __launch_bounds__(256) void fusedM_k(
    const float* __restrict__ x,
    const _Float16* __restrict__ W,
    const float* __restrict__ sb, const float* __restrict__ cb_,
    const float* __restrict__ g, const float* __restrict__ bt,
    const float* __restrict__ mn, const float* __restrict__ vr,
    _Float16* __restrict__ s1out, _Float16* __restrict__ c1out){
  __shared__ __align__(16) _Float16 Ah[3*58*64];
  const int tid = threadIdx.x;
  const int n = blockIdx.x / 28, oh0 = (blockIdx.x % 28) * 2;

  { // zero LDS tile
    int4* a = (int4*)Ah;
    for (int i = tid; i < 1392; i += 256) a[i] = (int4){0,0,0,0};
  }
  __syncthreads();

  for (int i = tid; i < 2016; i += 256){
    int m = i % 56; int rc = i / 56;
    int ic = rc % 3, ridx = rc / 3;
    int ih = 4*oh0 - 4 + ridx;
    if (ih < 0 || ih >= 224) continue;
    float4 v = *(const float4*)(x + ((size_t)(n*3 + ic)*224 + ih)*224 + 4*m);
    int rr = ridx >> 2, pr = ridx & 3, cc = m + 1;
    int boff = (((rr*58 + cc) << 7) + ic*32 + pr*8) ^ ((cc & 7) << 4);
    _Float16 h4[4] = {(_Float16)v.x, (_Float16)v.y, (_Float16)v.z, (_Float16)v.w};
    *(unsigned long long*)((char*)Ah + boff) = *(unsigned long long*)h4;
  }
  __syncthreads();

  const int wid = tid >> 6, lane = tid & 63;
  const int kg8 = (lane >> 4) * 8;
  f32x4 acc[2][2];
  #pragma unroll
  for (int mi = 0; mi < 2; ++mi)
    #pragma unroll
    for (int nf = 0; nf < 2; ++nf) acc[mi][nf] = (f32x4){0.f,0.f,0.f,0.f};

  #pragma unroll
  for (int s = 0; s < 6; ++s){
    const int kk = s*32 + kg8;
    const int t = kk / 48, c0 = kk - t*48;
    const int ra = t >> 1, ca = t & 1;
    f16x8 ah[2];
    #pragma unroll
    for (int mi = 0; mi < 2; ++mi){
      const int m = 2*wid + mi;
      const int rowsel = m >> 2;
      const int ow = (m & 3)*16 + (lane & 15);
      const int owc = ow > 55 ? 55 : ow;
      const int col = owc + ca;
      const int bidx = ((((rowsel + ra)*58 + col) << 7) + c0*2) ^ ((col & 7) << 4);
      ah[mi] = *(const f16x8*)((const char*)Ah + bidx);
    }
    #pragma unroll
    for (int nf = 0; nf < 2; ++nf){
      const f16x8 bw = *(const f16x8*)(W + (s*2 + nf)*512 + lane*8);
      #pragma unroll
      for (int mi = 0; mi < 2; ++mi)
        acc[mi][nf] = __builtin_amdgcn_mfma_f32_16x16x32_f16(ah[mi], bw, acc[mi][nf], 0,0,0);
    }
  }

  const int oc = lane & 15;
  const float sbv = sb[oc];
  const float scv = g[oc] * __frsqrt_rn(vr[oc] + 1e-5f);
  const float mnv = mn[oc], btv = bt[oc], cbv = cb_[oc];
  #pragma unroll
  for (int mi = 0; mi < 2; ++mi){
    const int m = 2*wid + mi;
    const int row = oh0 + (m >> 2);
    const int owb = (m & 3)*16 + (lane >> 4)*4;
    #pragma unroll
    for (int r = 0; r < 4; ++r){
      const int ow = owb + r;
      if (ow >= 56) continue;
      float vs = acc[mi][0][r] + sbv;
      vs = fmaxf((vs - mnv)*scv + btv, 0.f);
      const size_t o = (((size_t)n*56 + row)*56 + ow)*16 + oc;
      s1out[o] = (_Float16)vs;
      c1out[o] = (_Float16)leakyf(acc[mi][1][r] + cbv);
    }
  }
}

// ---------------- strided (S=2) MFMA conv, fp16 NHWC input [B,IH,IW,16] -----
template<int OC,int K,int P,int IH,int IW,int ACT,bool OUT16>
__global__ __launch_bounds__(256) void convS_k(
    const _Float16* __restrict__ in,
    const _Float16* __restrict__ W,
    const float* __restrict__ bias,
    const float* __restrict__ bng, const float* __restrict__ bnb,
    const float* __restrict__ bnm, const float* __restrict__ bnv,
    float* __restrict__ outF, _Float16* __restrict__ outH){
  constexpr int F = OC/16, KWP = (K+1)/2;
  __shared__ __align__(16) _Float16 A[K*60*16];

  const int tid = threadIdx.x;
  const int n = blockIdx.x / 28, oh = blockIdx.x % 28;

  for (int i = tid; i < K*60*2; i += 256){
    int half = i & 1; int p = i >> 1;
    int c = p % 60; int r = p / 60;
    int ih = 2*oh - P + r, iw = c - P;
    int4 v = {0,0,0,0};
    if (ih >= 0 && ih < IH && iw >= 0 && iw < IW)
      v = *(const int4*)(in + (((size_t)n*IH + ih)*IW + iw)*16 + half*8);
    int byte = ((r*60 + c)*32 + half*16) ^ (((c>>1)&7) << 4);
    *(int4*)((char*)A + byte) = v;
  }
  __syncthreads();

  const int wid = tid >> 6, lane = tid & 63;
  const int fsel = wid & 1, mb = wid >> 1;
  const int ow_l = min(mb*16 + (lane & 15), 27);
  const int ic0b = ((lane >> 4) & 1) * 16;
  const int kwo  = (lane >> 4) >> 1;

  f32x4 acc = {0.f,0.f,0.f,0.f};
  #pragma unroll
  for (int kh = 0; kh < K; ++kh){
    #pragma unroll
    for (int kwp = 0; kwp < KWP; ++kwp){
      const int kw = 2*kwp + kwo;
      const int c = 2*ow_l + kw;
      int byte = ((kh*60 + c)*32 + ic0b) ^ (((c>>1)&7) << 4);
      f16x8 a = *(const f16x8*)((const char*)A + byte);
      const int s = kh*KWP + kwp;
      const f16x8 b = *(const f16x8*)(W + (s*F + fsel)*512 + lane*8);
      acc = __builtin_amdgcn_mfma_f32_16x16x32_f16(a, b, acc, 0,0,0);
    }
  }

  const int oc = fsel*16 + (lane & 15);
  float bv = bias[oc], sc = 1.f, mm = 0.f, bb = 0.f;
  if (ACT == 1){
    sc = bng[oc] * __frsqrt_rn(bnv[oc] + 1e-5f);
    mm = bnm[oc]; bb = bnb[oc];
  }
  #pragma unroll
  for (int r = 0; r < 4; ++r){
    const int ow = mb*16 + (lane >> 4)*4 + r;
    if (ow >= 28) continue;
    float v = acc[r] + bv;
    if (ACT == 1) v = fmaxf((v - mm)*sc + bb, 0.f);
    else          v = leakyf(v);
    const size_t o = (((size_t)n*28 + oh)*28 + ow)*OC + oc;
    if (OUT16) outH[o] = (_Float16)v;
    else       outF[o] = v;
  }
}

// ---------------- MFMA single-fp16 3x3 s1 p1 conv on 27x27, padded NHWC -----
template<int IC,int OC,int OUTM>
__global__ __launch_bounds__(256) void convM_k(
    const _Float16* __restrict__ Ag,
    const _Float16* __restrict__ W,
    const float* __restrict__ bias,
    _Float16* __restrict__ OutPad, _Float16* __restrict__ OutNP)
{
  constexpr int S = IC/32, FTOT = OC/16, FW = FTOT/2;
  constexpr int ICB = IC*2, ICG = ICB/16;
  __shared__ __align__(16) char A[4*34*ICB];

  const int tid = threadIdx.x;
  const int bx = blockIdx.x;
  const int n = bx / 14, pr = bx % 14;
  const int oh0 = pr * 2;

  const size_t gbase = ((size_t)n*29) * 29 * IC;
  for (int g = tid; g < 4*34*ICG; g += 256){
    int r = g / (34*ICG);
    int rem = g - r*(34*ICG);
    int c = rem / ICG, q = rem - c*ICG;
    int rp = oh0 + r;
    int4 v = {0,0,0,0};
    if (rp <= 28 && c < 29){
      size_t e = gbase + ((size_t)rp*29 + c)*IC + q*8;
      v = *(const int4*)(Ag + e);
    }
    int off = (r*34 + c)*ICB + q*16;
    int swz = off ^ ((c & 7) << 4);
    *(int4*)(A + swz) = v;
  }
  __syncthreads();

  const int wid = tid >> 6, lane = tid & 63;
  const int rsel = wid & 1, ocq = wid >> 1;
  const int c0 = lane & 15, kg = (lane >> 4) * 16;
  const int colb0 = c0*ICB + kg, colb1 = (16 + c0)*ICB + kg;
  int msk[3];
  #pragma unroll
  for (int kw = 0; kw < 3; ++kw) msk[kw] = ((c0 + kw) & 7) << 4;

  f32x4 acc[2][FW];
  #pragma unroll
  for (int m = 0; m < 2; ++m)
    #pragma unroll
    for (int f = 0; f < FW; ++f) acc[m][f] = (f32x4){0.f,0.f,0.f,0.f};

  #pragma unroll
  for (int kh = 0; kh < 3; ++kh){
    #pragma unroll
    for (int kw = 0; kw < 3; ++kw){
      #pragma unroll
      for (int s = 0; s < S; ++s){
        const int fr0 = (((kh*3 + kw)*S + s)*FTOT + ocq*FW) * 512 + lane*8;
        f16x8 b[FW];
        #pragma unroll
        for (int f = 0; f < FW; ++f)
          b[f] = *(const f16x8*)(W + fr0 + f*512);
        const int base = ((rsel + kh)*34 + kw)*ICB + s*64;
        const int o0 = (base + colb0) ^ msk[kw];
        const int o1 = (base + colb1) ^ msk[kw];
        f16x8 a0 = *(const f16x8*)(A + o0);
        f16x8 a1 = *(const f16x8*)(A + o1);
        #pragma unroll
        for (int f = 0; f < FW; ++f){
          acc[0][f] = __builtin_amdgcn_mfma_f32_16x16x32_f16(a0, b[f], acc[0][f], 0,0,0);
          acc[1][f] = __builtin_amdgcn_mfma_f32_16x16x32_f16(a1, b[f], acc[1][f], 0,0,0);
        }
      }
    }
  }

  const int orow = oh0 + rsel;
  if (orow >= 27) return;
  #pragma unroll
  for (int f = 0; f < FW; ++f){
    const int oc = (ocq*FW + f)*16 + c0;
    const float bv = bias[oc];
    #pragma unroll
    for (int m = 0; m < 2; ++m){
      #pragma unroll
      for (int r = 0; r < 4; ++r){
        const int ow = m*16 + (lane >> 4)*4 + r;
        if (ow >= 27) continue;
        float v = leakyf(acc[m][f][r] + bv);
        if (OUTM == 0){
          OutPad[(((size_t)n*29 + orow+1)*29 + ow+1)*OC + oc] = (_Float16)v;
        } else {
          OutNP[(((size_t)n*27 + orow)*27 + ow)*OC + oc] = (_Float16)v;
        }
      }
    }
  }
}

// ---------------- single-fp16 MFMA GEMM for MoE head ------------------------
// C[e][256][N] = A[e][256][KTOT](fp16) * W[e](packed fp16)^T + bias
// OUTM 0: fp16 out ; OUTM 1: fp32 out
template<int KTOT,int ACT,int OUTM>
__global__ __launch_bounds__(256) void gemmH_k(
    const _Float16* __restrict__ A, long strideA,
    const _Float16* __restrict__ W,
    const float* __restrict__ bias, int N,
    _Float16* __restrict__ OutH, float* __restrict__ OutF){
  const int e = blockIdx.z;
  A += (size_t)e * strideA;
  const int NF = N >> 4, KT = KTOT >> 5;
  W += (size_t)e * NF * KT * 512;
  const float* bs = bias + (size_t)e * N;
  const size_t ob = (size_t)e * 256 * N;

  const int tid = threadIdx.x, wid = tid >> 6, lane = tid & 63;
  const int mblk = blockIdx.x * 32;
  const int nf = blockIdx.y * 4 + wid;
  const int r0 = mblk + (lane & 15);
  const int kof = (lane >> 4) * 8;

  f32x4 acc0 = {0,0,0,0}, acc1 = {0,0,0,0};
  for (int t = 0; t < KT; ++t){
    const int k = t*32 + kof;
    f16x8 a0 = *(const f16x8*)(A + (size_t)r0*KTOT + k);
    f16x8 a1 = *(const f16x8*)(A + (size_t)(r0+16)*KTOT + k);
    const f16x8 b = *(const f16x8*)(W + ((size_t)t*NF + nf)*512 + lane*8);
    acc0 = __builtin_amdgcn_mfma_f32_16x16x32_f16(a0, b, acc0, 0,0,0);
    acc1 = __builtin_amdgcn_mfma_f32_16x16x32_f16(a1, b, acc1, 0,0,0);
  }
  const int n = nf*16 + (lane & 15);
  const float bv = bs[n];
  #pragma unroll
  for (int mi = 0; mi < 2; ++mi){
    f32x4 a = mi ? acc1 : acc0;
    #pragma unroll
    for (int r = 0; r < 4; ++r){
      const int m = mblk + mi*16 + (lane >> 4)*4 + r;
      float v = a[r] + bv;
      if (ACT == 1) v = leakyf(v);
      const size_t o = ob + (size_t)m*N + n;
      if (OUTM == 0) OutH[o] = (_Float16)v;
      else           OutF[o] = v;
    }
  }
}

// ------ fp16 NHWC 2x2 s1 maxpool: [B,56,56,16] -> [B,55,55,16] --------------
__global__ __launch_bounds__(256) void poolh_k(const _Float16* __restrict__ in,
                                               _Float16* __restrict__ out){
  int idx = blockIdx.x * 256 + threadIdx.x;
  if (idx >= BATCH * 55 * 55 * 2) return;
  int half = idx & 1; int p = idx >> 1;
  int ow = p % 55; int t = p / 55; int oh = t % 55; int n = t / 55;
  const _Float16* q = in + (((size_t)n*56 + oh)*56 + ow)*16 + half*8;
  f16x8 a = *(const f16x8*)q;
  f16x8 b = *(const f16x8*)(q + 16);
  f16x8 c = *(const f16x8*)(q + 56*16);
  f16x8 d = *(const f16x8*)(q + 57*16);
  f16x8 r;
  #pragma unroll
  for (int j = 0; j < 8; ++j){
    float m = fmaxf(fmaxf((float)a[j], (float)b[j]), fmaxf((float)c[j], (float)d[j]));
    r[j] = (_Float16)m;
  }
  *(f16x8*)(out + (size_t)p*16 + half*8) = r;
}

// ------- pool2: fp16 NHWC [B,28,28,32] -> padded NHWC fp16 [B,29,29,32] -----
__global__ __launch_bounds__(256) void pool2n_k(const _Float16* __restrict__ in,
    _Float16* __restrict__ o16){
  int idx = blockIdx.x*256 + threadIdx.x;
  if (idx >= BATCH*27*27*32) return;
  int ic = idx & 31; int p = idx >> 5;
  int ow = p % 27; int t = p / 27; int oh = t % 27; int n = t / 27;
  const _Float16* b = in + (((size_t)n*28 + oh)*28 + ow)*32 + ic;
  float v = fmaxf(fmaxf((float)b[0], (float)b[32]),
                  fmaxf((float)b[28*32], (float)b[29*32]));
  o16[(((size_t)n*29 + oh+1)*29 + ow+1)*32 + ic] = (_Float16)v;
}

// ---------------- scout gate (fp32 NHWC input [B,28,28,32]) ----------------
__global__ __launch_bounds__(256) void gate_k(const float* __restrict__ s2,
                                              const float* __restrict__ cw,
                                              const float* __restrict__ cb,
                                              float* __restrict__ comb){
  int n = blockIdx.x;
  int tid = threadIdx.x;
  int c = tid & 31;
  int sub = tid >> 5;
  const float* p = s2 + (size_t)n * 784 * 32 + c;
  float s = 0.f;
  for (int i = sub * 98; i < sub * 98 + 98; ++i) s += p[(size_t)i * 32];
  __shared__ float red[32][8];
  red[c][sub] = s;
  __syncthreads();
  if (tid < 32){
    float tot = 0.f;
    #pragma unroll
    for (int k = 0; k < 8; ++k) tot += red[tid][k];
    red[tid][0] = tot / 784.f;
  }
  __syncthreads();
  if (tid == 0){
    float lg[3];
    for (int e = 0; e < 3; ++e){
      float a = cb[e];
      for (int c2 = 0; c2 < 32; ++c2) a += red[c2][0] * cw[e * 32 + c2];
      lg[e] = a;
    }
    float m = fmaxf(lg[0], fmaxf(lg[1], lg[2]));
    float ex[3], sum = 0.f;
    for (int e = 0; e < 3; ++e){ ex[e] = expf(lg[e] - m); sum += ex[e]; }
    float pr[3];
    for (int e = 0; e < 3; ++e) pr[e] = ex[e] / sum;
    int i1 = 0;
    if (pr[1] > pr[0]) i1 = 1;
    if (pr[2] > pr[i1]) i1 = 2;
    int i2 = -1;
    for (int e = 0; e < 3; ++e){
      if (e == i1) continue;
      if (i2 < 0 || pr[e] > pr[i2]) i2 = e;
    }
    float s12 = pr[i1] + pr[i2] + 1e-6f;
    float cmb[3] = {0.f, 0.f, 0.f};
    cmb[i1] = pr[i1] / s12;
    cmb[i2] = pr[i2] / s12;
    comb[n * 3 + 0] = cmb[0];
    comb[n * 3 + 1] = cmb[1];
    comb[n * 3 + 2] = cmb[2];
  }
}

// ------ channel-parallel fused maxpool2s1(27->26) + adaptive avg(26->3) -----
__global__ __launch_bounds__(256) void papool2_k(const _Float16* __restrict__ in,
                                                 float* __restrict__ flat){
  __shared__ float red[2][128][9];
  const int n = blockIdx.x;
  const int tid = threadIdx.x;
  const int h = tid >> 7, c = tid & 127;
  const _Float16* p = in + (size_t)n * 729 * 128 + c;

  float sum[9];
  #pragma unroll
  for (int j = 0; j < 9; ++j) sum[j] = 0.f;

  float prev[27], cur[27];
  const int r0 = h * 13;
  #pragma unroll
  for (int rr = 0; rr < 14; ++rr){
    const int r = r0 + rr;
    #pragma unroll
    for (int cc = 0; cc < 27; ++cc)
      cur[cc] = (float)p[(size_t)(r*27 + cc) * 128];
    if (rr > 0){
      const int pr = r - 1;
      const bool b0 = (pr < 9), b1 = (pr >= 8) && (pr < 18), b2 = (pr >= 17);
      #pragma unroll
      for (int cc = 0; cc < 26; ++cc){
        float v = fmaxf(fmaxf(prev[cc], prev[cc+1]), fmaxf(cur[cc], cur[cc+1]));
        if (b0){
          if (cc < 9)             sum[0] += v;
          if (cc >= 8 && cc < 18) sum[1] += v;
          if (cc >= 17)           sum[2] += v;
        }
        if (b1){
          if (cc < 9)             sum[3] += v;
          if (cc >= 8 && cc < 18) sum[4] += v;
          if (cc >= 17)           sum[5] += v;
        }
        if (b2){
          if (cc < 9)             sum[6] += v;
          if (cc >= 8 && cc < 18) sum[7] += v;
          if (cc >= 17)           sum[8] += v;
        }
      }
    }
    #pragma unroll
    for (int cc = 0; cc < 27; ++cc) prev[cc] = cur[cc];
  }

  #pragma unroll
  for (int j = 0; j < 9; ++j) red[h][c][j] = sum[j];
  __syncthreads();

  if (tid < 128){
    const float rcp[9] = {1.f/81, 1.f/90, 1.f/81, 1.f/90, 1.f/100, 1.f/90,
                          1.f/81, 1.f/90, 1.f/81};
    float* o = flat + (size_t)n * 1152 + tid * 9;
    #pragma unroll
    for (int j = 0; j < 9; ++j)
      o[j] = (red[0][tid][j] + red[1][tid][j]) * rcp[j];
  }
}

// ---------------- final gated combine ----------------
__global__ __launch_bounds__(256) void comb_k(const float* __restrict__ h3,
                                              const float* __restrict__ comb,
                                              float* __restrict__ out){
  int idx = blockIdx.x * 256 + threadIdx.x;
  if (idx >= BATCH * 512) return;
  int o = idx % 512, b = idx / 512;
  float s = 0.f;
  #pragma unroll
  for (int e = 0; e < 3; ++e)
    s += comb[b * 3 + e] * h3[((size_t)e * BATCH + b) * 512 + o];
  out[idx] = s;
}

// ============================================================================
extern "C" void kernel_launch(void* const* d_in, const int* in_sizes, int n_in,
                              void* d_out, int out_size, void* d_ws, size_t ws_size,
                              hipStream_t stream){
  const float* x    = (const float*)d_in[0];
  const float* tw1  = (const float*)d_in[1];  const float* tb1 = (const float*)d_in[2];
  const float* tw2  = (const float*)d_in[3];  const float* tb2 = (const float*)d_in[4];
  const float* tw3  = (const float*)d_in[5];  const float* tb3 = (const float*)d_in[6];
  const float* tw4  = (const float*)d_in[7];  const float* tb4 = (const float*)d_in[8];
  const float* sw1  = (const float*)d_in[9];  const float* sb1 = (const float*)d_in[10];
  const float* bn1g = (const float*)d_in[11]; const float* bn1b = (const float*)d_in[12];
  const float* bn1m = (const float*)d_in[13]; const float* bn1v = (const float*)d_in[14];
  const float* sw2  = (const float*)d_in[15]; const float* sb2 = (const float*)d_in[16];
  const float* bn2g = (const float*)d_in[17]; const float* bn2b = (const float*)d_in[18];
  const float* bn2m = (const float*)d_in[19]; const float* bn2v = (const float*)d_in[20];
  const float* cw   = (const float*)d_in[21]; const float* cb  = (const float*)d_in[22];
  const float* ew1  = (const float*)d_in[23]; const float* eb1 = (const float*)d_in[24];
  const float* ew2  = (const float*)d_in[25]; const float* eb2 = (const float*)d_in[26];
  const float* ew3  = (const float*)d_in[27]; const float* eb3 = (const float*)d_in[28];
  float* out = (float*)d_out;

  // ---- workspace layout (floats), ~157 MB ----
  float* ws = (float*)d_ws;
  size_t off = 0;
  float* comb   = ws + off; off += 768;
  float* flat   = ws + off; off += (size_t)BATCH * 1152;
  float* h3     = ws + off; off += (size_t)BATCH * 3 * 512;
  _Float16* wpk3 = (_Float16*)(ws + off); off += 9216;
  _Float16* wpk4 = (_Float16*)(ws + off); off += 36864;
  _Float16* wp2  = (_Float16*)(ws + off); off += 7680;
  _Float16* wps2 = (_Float16*)(ws + off); off += 3072;
  _Float16* wpf  = (_Float16*)(ws + off); off += 3072;
  off += 16;                                                      // guard pad
  float* bufA   = ws + off; off += 13778944;
  off += 16;                                                      // guard pad
  float* bufB   = ws + off; off += 23887872;
  off += 16;
  (void)ws_size; (void)in_sizes; (void)n_in; (void)out_size;

  // phase aliases (lifetimes disjoint, single-stream ordered)
  _Float16* s1h = (_Float16*)bufA;           // [B,56,56,16] fp16 NHWC
  _Float16* c1h = (_Float16*)bufB;           // [B,56,56,16] fp16 NHWC
  float* s2out  = bufB + 16000000;           // [B,28,28,32] fp32 NHWC (gate path)
  _Float16* p1h = (_Float16*)bufA;           // [B,55,55,16] fp16 NHWC
  _Float16* c2h = (_Float16*)bufB;           // [B,28,28,32] fp16 NHWC
  _Float16* P2 = (_Float16*)(bufB + 8000000);
  _Float16* C3 = (_Float16*)bufA;
  _Float16* c4h = (_Float16*)bufB;           // [B,27,27,128] fp16 NHWC

  // head-phase aliases in bufB (valid after papool2_k) — all fp16
  _Float16* hb = (_Float16*)bufB;
  size_t uo = 0;
  _Float16* ewp1 = hb + uo; uo += 3538944;
  _Float16* ewp2 = hb + uo; uo += 1572864;
  _Float16* ewp3 = hb + uo; uo += 786432;
  _Float16* f16a = hb + uo; uo += 294912;
  _Float16* h1   = hb + uo; uo += 786432;
  _Float16* h2   = hb + uo; uo += 393216;

  dim3 blk(256);

  // ---- weight prep ----
  wpackM_k<32,64>  <<<dim3(72),  blk, 0, stream>>>(tw3, wpk3);
  wpackM_k<64,128> <<<dim3(288), blk, 0, stream>>>(tw4, wpk4);
  wpackS_k<32,5><<<dim3(60), blk, 0, stream>>>(tw2, wp2);
  wpackS_k<32,3><<<dim3(24), blk, 0, stream>>>(sw2, wps2);
  wpackF_k<<<dim3(24), blk, 0, stream>>>(sw1, tw1, wpf);

  // ---- fused scout1 + conv1 -> fp16 NHWC (2 rows/block, proven) ----
  fusedM_k<<<dim3(BATCH*28), blk, 0, stream>>>(
      x, wpf, sb1, tb1, bn1g, bn1b, bn1m, bn1v, s1h, c1h);

  // ---- scout2 (fp32 out for gate) + gate ----
  convS_k<32,3,1,56,56,1,false><<<dim3(BATCH*28), blk, 0, stream>>>(
      s1h, wps2, sb2, bn2g, bn2b, bn2m, bn2v, s2out, nullptr);
  gate_k<<<dim3(256), blk, 0, stream>>>(s2out, cw, cb, comb);

  // ---- pool1 (fp16 NHWC) -> conv2 (fp16 out) ----
  poolh_k<<<dim3((BATCH*55*55*2 + 255)/256), blk, 0, stream>>>(c1h, p1h);
  convS_k<32,5,2,55,55,0,true><<<dim3(BATCH*28), blk, 0, stream>>>(
      p1h, wp2, tb2, nullptr, nullptr, nullptr, nullptr, nullptr, c2h);

  // ---- pool2 (fp16 in) -> padded NHWC fp16 ----
  hipMemsetAsync(P2, 0, (size_t)6889472 * 2, stream);
  pool2n_k<<<dim3((BATCH*27*27*32 + 255)/256), blk, 0, stream>>>(c2h, P2);

  // ---- conv3 (MFMA fp16) -> padded NHWC fp16 ----
  hipMemsetAsync(C3, 0, (size_t)13778944 * 2, stream);
  convM_k<32,64,0><<<dim3(BATCH*14), blk, 0, stream>>>(
      P2, wpk3, tb3, C3, nullptr);

  // ---- conv4 (MFMA fp16) -> fp16 NHWC [B,27,27,128] ----
  convM_k<64,128,1><<<dim3(BATCH*14), blk, 0, stream>>>(
      C3, wpk4, tb4, nullptr, c4h);

  papool2_k<<<dim3(BATCH), blk, 0, stream>>>(c4h, flat);

  // ---- MoE head: pack weights fp16 + convert A, then 3 fp16 MFMA GEMMs ----
  wpackGh_k<1152><<<dim3(4608,3), blk, 0, stream>>>(ew1, 1024, ewp1);
  wpackGh_k<1024><<<dim3(2048,3), blk, 0, stream>>>(ew2,  512, ewp2);
  wpackGh_k< 512><<<dim3(1024,3), blk, 0, stream>>>(ew3,  512, ewp3);
  acvt_k<<<dim3(1152), blk, 0, stream>>>(flat, f16a, BATCH*1152);

  gemmH_k<1152,1,0><<<dim3(8,16,3), blk, 0, stream>>>(
      f16a, 0L, ewp1, eb1, 1024, h1, nullptr);
  gemmH_k<1024,1,0><<<dim3(8,8,3), blk, 0, stream>>>(
      h1, 256L*1024, ewp2, eb2, 512, h2, nullptr);
  gemmH_k< 512,0,1><<<dim3(8,8,3), blk, 0, stream>>>(
      h2, 256L*512, ewp3, eb3, 512, nullptr, h3);

  comb_k<<<dim3(512), blk, 0, stream>>>(h3, comb, out);
}